// Round 7
// baseline (1990.838 us; speedup 1.0000x reference)
//
#include <hip/hip_runtime.h>
#include <math.h>

typedef short bf16x8 __attribute__((ext_vector_type(8)));
typedef float f32x4 __attribute__((ext_vector_type(4)));
typedef float f32x2 __attribute__((ext_vector_type(2)));
typedef unsigned short u16;
typedef unsigned int u32;
typedef unsigned short u16x4 __attribute__((ext_vector_type(4)));

#define B_    32
#define D_    384
#define DEPTH 12
#define NST   16
#define DI_   768
#define R_    24
#define L_    196
#define NC_   1000
#define M_    (B_*L_)   // 6272
#define SEG   28        // scan segment length (L_ = 7*28 exactly)
#define NSEG  7

__device__ __forceinline__ u16 f2bf(float f) {
  union { float f; unsigned u; } v; v.f = f;
  unsigned r = v.u + 0x7fffu + ((v.u >> 16) & 1u);
  return (u16)(r >> 16);
}
__device__ __forceinline__ float bf2f(u16 x) {
  union { unsigned u; float f; } v; v.u = ((unsigned)x) << 16;
  return v.f;
}
// sum across each quad of lanes via DPP (VALU pipe, no DS traffic)
__device__ __forceinline__ float quad_sum(float y) {
  y += __int_as_float(__builtin_amdgcn_update_dpp(0, __float_as_int(y), 0xB1, 0xf, 0xf, true)); // xor1
  y += __int_as_float(__builtin_amdgcn_update_dpp(0, __float_as_int(y), 0x4E, 0xf, 0xf, true)); // xor2
  return y;
}

// ---------------- weight prep ----------------
__global__ void k_transpose_bf16(const float* __restrict__ in, u16* __restrict__ out,
                                 int R, int C) {
  __shared__ float tile[32][33];
  const size_t zoff = (size_t)blockIdx.z * R * C;
  in  += zoff; out += zoff;
  int c0 = blockIdx.x * 32, r0 = blockIdx.y * 32;
  int tx = threadIdx.x, ty = threadIdx.y;
  for (int i = ty; i < 32; i += 8) {
    int r = r0 + i, c = c0 + tx;
    tile[i][tx] = (r < R && c < C) ? in[(size_t)r * C + c] : 0.f;
  }
  __syncthreads();
  for (int i = ty; i < 32; i += 8) {
    int c = c0 + i, r = r0 + tx;
    if (c < C && r < R) out[(size_t)c * R + r] = f2bf(tile[tx][i]);
  }
}

__global__ void k_convert_bf16(const float* __restrict__ in, u16* __restrict__ out, int n) {
  int i = blockIdx.x * 256 + threadIdx.x;
  if (i < n) out[i] = f2bf(in[i]);
}

// A = -exp(A_log), all layers at once
__global__ void k_prepA(const float* __restrict__ alog, float* __restrict__ A, int n) {
  int i = blockIdx.x * 256 + threadIdx.x;
  if (i < n) A[i] = -__expf(alog[i]);
}

// ---------------- im2col for patch embed ----------------
__global__ void k_im2col(const float* __restrict__ x, u16* __restrict__ xcol) {
  int idx = blockIdx.x * 256 + threadIdx.x;     // over M_*768
  if (idx >= M_ * 768) return;
  int k = idx % 768, m = idx / 768;
  int b = m / L_, l = m % L_;
  int li = l / 14, lj = l % 14;
  int c = k / 256, r = k % 256;
  int i = r / 16, j = r % 16;
  int hh = li * 16 + i, ww = lj * 16 + j;
  xcol[idx] = f2bf(x[(((size_t)b * 3 + c) * 224 + hh) * 224 + ww]);
}

// ---------------- GEMM: C(MxN) = A(MxK,bf16) * BT(NxK,bf16)^T ----------------
// EPI: 0 = store, 1 = add (residual), 2 = store + bias[col] + pos[(row%L)*N+col]
// OB:  1 = store bf16 (u16) instead of f32 (EPI==0 only)
template<int BM, int BN, int EPI, int OB>
__global__ __launch_bounds__(256)
void k_gemm(const u16* __restrict__ A, const u16* __restrict__ BT,
            float* __restrict__ Cout, int Nn, int Kk,
            const float* __restrict__ bias, const float* __restrict__ pos) {
  const int m0 = blockIdx.x * BM;
  const int n0 = blockIdx.y * BN;
  __shared__ u16 lA[BM * 72];
  __shared__ u16 lB[BN * 72];
  const int tid  = threadIdx.x;
  const int wave = tid >> 6, lane = tid & 63;
  const int wm = (wave >> 1) * (BM / 2), wn = (wave & 1) * (BN / 2);
  constexpr int MI = BM / 32, NJ = BN / 32;
  constexpr int NV = (BM + BN) / 32;
  f32x4 acc[MI][NJ] = {};
  const int fr = lane & 15, kg = (lane >> 4) * 8;

  for (int k0 = 0; k0 < Kk; k0 += 64) {
    bf16x8 v[NV];
    #pragma unroll
    for (int q = 0; q < NV; ++q) {
      int id = tid + q * 256;
      int row = id >> 3, vv = id & 7;
      bf16x8 t = {};
      if (row < BM) {
        t = *(const bf16x8*)(A + (size_t)(m0 + row) * Kk + k0 + vv * 8);
      } else {
        int br = n0 + row - BM;
        if (br < Nn) t = *(const bf16x8*)(BT + (size_t)br * Kk + k0 + vv * 8);
      }
      v[q] = t;
    }
    __syncthreads();
    #pragma unroll
    for (int q = 0; q < NV; ++q) {
      int id = tid + q * 256;
      int row = id >> 3, vv = id & 7;
      u16* dst = (row < BM) ? (lA + row * 72 + vv * 8) : (lB + (size_t)(row - BM) * 72 + vv * 8);
      *(bf16x8*)dst = v[q];
    }
    __syncthreads();
    #pragma unroll
    for (int kk = 0; kk < 64; kk += 32) {
      bf16x8 af[MI], bfr[NJ];
      #pragma unroll
      for (int i = 0; i < MI; ++i)
        af[i] = *(const bf16x8*)(lA + (wm + i * 16 + fr) * 72 + kk + kg);
      #pragma unroll
      for (int j = 0; j < NJ; ++j)
        bfr[j] = *(const bf16x8*)(lB + (wn + j * 16 + fr) * 72 + kk + kg);
      #pragma unroll
      for (int i = 0; i < MI; ++i)
        #pragma unroll
        for (int j = 0; j < NJ; ++j)
          acc[i][j] = __builtin_amdgcn_mfma_f32_16x16x32_bf16(af[i], bfr[j], acc[i][j], 0, 0, 0);
    }
  }

  const int rg = (lane >> 4) * 4;
  #pragma unroll
  for (int i = 0; i < MI; ++i) {
    int row = m0 + wm + i * 16 + rg;
    #pragma unroll
    for (int j = 0; j < NJ; ++j) {
      int col = n0 + wn + j * 16 + fr;
      if (col >= Nn) continue;
      #pragma unroll
      for (int r = 0; r < 4; ++r) {
        float v = acc[i][j][r];
        size_t idx = (size_t)(row + r) * Nn + col;
        if (EPI == 0) {
          if (OB) ((u16*)Cout)[idx] = f2bf(v);
          else    Cout[idx] = v;
        }
        else if (EPI == 1) Cout[idx] += v;
        else               Cout[idx] = v + bias[col] + pos[(size_t)((row + r) % L_) * Nn + col];
      }
    }
  }
}

// ---------------- LayerNorm (writes bf16 for GEMM A) ----------------
__global__ __launch_bounds__(384)
void k_ln(const float* __restrict__ x, const float* __restrict__ g,
          const float* __restrict__ bt, u16* __restrict__ h) {
  const int m = blockIdx.x, d = threadIdx.x;
  __shared__ float red[12];
  float v = x[(size_t)m * D_ + d];
  float s = v, s2 = v * v;
  #pragma unroll
  for (int o = 32; o > 0; o >>= 1) { s += __shfl_xor(s, o); s2 += __shfl_xor(s2, o); }
  int wid = d >> 6;
  if ((d & 63) == 0) { red[wid] = s; red[6 + wid] = s2; }
  __syncthreads();
  float ts = 0.f, ts2 = 0.f;
  #pragma unroll
  for (int w = 0; w < 6; ++w) { ts += red[w]; ts2 += red[6 + w]; }
  float mu = ts / (float)D_;
  float var = ts2 / (float)D_ - mu * mu;
  float rs = rsqrtf(var + 1e-5f);
  h[(size_t)m * D_ + d] = f2bf((v - mu) * rs * g[d] + bt[d]);
}

// ---------------- causal depthwise conv (K=4) + SiLU: bf16 in, bf16 out ----------------
__global__ __launch_bounds__(256)
void k_conv(const u16* __restrict__ xzb, const float* __restrict__ cw,
            const float* __restrict__ cb, u16* __restrict__ xcb) {
  int idx = blockIdx.x * 256 + threadIdx.x;   // over M_ * DI_/4
  if (idx >= M_ * (DI_ / 4)) return;
  int dq = idx % (DI_ / 4), m = idx / (DI_ / 4), l = m % L_;
  int di4 = dq * 4;
  const u16* base = xzb + (size_t)m * 1536 + di4;
  float xv[4][4];
  #pragma unroll
  for (int t = 0; t < 4; ++t) {
    int back = 3 - t;
    u16x4 v = {};
    if (l >= back) v = *(const u16x4*)(base - (size_t)back * 1536);
    #pragma unroll
    for (int c = 0; c < 4; ++c) xv[t][c] = bf2f(v[c]);
  }
  f32x4 bv = *(const f32x4*)(cb + di4);
  u16x4 outv;
  #pragma unroll
  for (int c = 0; c < 4; ++c) {
    f32x4 w = *(const f32x4*)(cw + (size_t)(di4 + c) * 4);
    float acc = bv[c] + w[0] * xv[0][c] + w[1] * xv[1][c] + w[2] * xv[2][c] + w[3] * xv[3][c];
    float s = acc / (1.f + __expf(-acc));
    outv[c] = f2bf(s);
  }
  *(u16x4*)(xcb + (size_t)m * DI_ + di4) = outv;
}

// ---------------- dt = softplus(dbc[:, :24] @ dtp_w + dtp_b) ----------------
__global__ __launch_bounds__(256)
void k_dt(const float* __restrict__ dbc, const float* __restrict__ dtw,
          const float* __restrict__ dtb, float* __restrict__ dt) {
  const int m0 = blockIdx.x * 16;
  const int di = blockIdx.y * 256 + threadIdx.x;
  __shared__ float sd[16][25];
  #pragma unroll
  for (int q = 0; q < 2; ++q) {
    int id = threadIdx.x + q * 256;
    if (id < 16 * 24) {
      int r = id / 24, c = id % 24;
      sd[r][c] = dbc[(size_t)(m0 + r) * 56 + c];
    }
  }
  __syncthreads();
  float w[24];
  #pragma unroll
  for (int r = 0; r < 24; ++r) w[r] = dtw[r * DI_ + di];
  const float bv = dtb[di];
  #pragma unroll 4
  for (int mi = 0; mi < 16; ++mi) {
    float acc = bv;
    #pragma unroll
    for (int r = 0; r < 24; ++r) acc += sd[mi][r] * w[r];
    float e  = __expf(-fabsf(acc));
    float sp = fmaxf(acc, 0.f) + __logf(1.f + e);
    dt[(size_t)(m0 + mi) * DI_ + di] = sp;
  }
}

// ---------------- pass A: local segment scan ----------------
// grid (B_, DI_/64, NSEG), 256 thr = 64 ch x 4 nq (quad = one channel's 4 state-quads)
// writes ys[m][ch] = {y_pre, scum}, hend (f32x4/lane), send (scalar/ch)
__global__ __launch_bounds__(256)
void k_scan_part(const float* __restrict__ dbc, const float* __restrict__ dt,
                 const u16* __restrict__ xcb, const float* __restrict__ Abuf,
                 const float* __restrict__ Dsk, float* __restrict__ ys,
                 float* __restrict__ hend, float* __restrict__ send) {
  const int b   = blockIdx.x;
  const int di0 = blockIdx.y * 64;
  const int s   = blockIdx.z;
  const int tid = threadIdx.x;
  const int dil = tid >> 2, nq = tid & 3;
  const int di  = di0 + dil;
  __shared__ float sDX[SEG][128];   // {dt,xc} interleaved per channel
  __shared__ float sYS[SEG][128];   // {y, scum} per channel

  const f32x4 Arow = *(const f32x4*)(Abuf + (size_t)di * NST + nq * 4);
  const float Dv = Dsk[di];
  const size_t mb = (size_t)b * L_ + (size_t)s * SEG;

  {
    int r = tid >> 4, cc = (tid & 15) * 4;
    #pragma unroll
    for (int j = 0; j < 2; ++j) {
      int row = r + j * 16;
      if (row < SEG) {
        f32x4 dtv = *(const f32x4*)(dt + (mb + row) * DI_ + di0 + cc);
        u16x4 xv  = *(const u16x4*)(xcb + (mb + row) * DI_ + di0 + cc);
        f32x4 w0 = {dtv[0], bf2f(xv[0]), dtv[1], bf2f(xv[1])};
        f32x4 w1 = {dtv[2], bf2f(xv[2]), dtv[3], bf2f(xv[3])};
        *(f32x4*)&sDX[row][cc * 2]     = w0;
        *(f32x4*)&sDX[row][cc * 2 + 4] = w1;
      }
    }
  }
  __syncthreads();

  const float* bc = dbc + mb * 56;
  float h[4] = {0.f, 0.f, 0.f, 0.f};
  float scum = 0.f;
  f32x2 dx = *(const f32x2*)&sDX[0][2 * dil];
  f32x4 Bv = *(const f32x4*)(bc + 24 + nq * 4);
  f32x4 Cv = *(const f32x4*)(bc + 40 + nq * 4);
  #pragma unroll 4
  for (int t = 0; t < SEG; ++t) {
    f32x2 dxn = {}; f32x4 Bn = {}, Cn = {};
    if (t + 1 < SEG) {      // prefetch next step (regs; B/C from global via L1)
      dxn = *(const f32x2*)&sDX[t + 1][2 * dil];
      Bn = *(const f32x4*)(bc + (t + 1) * 56 + 24 + nq * 4);
      Cn = *(const f32x4*)(bc + (t + 1) * 56 + 40 + nq * 4);
    }
    float dtc = dx.x, xcc = dx.y;
    scum += dtc;
    float dxv = dtc * xcc;
    float y = (nq == 0) ? Dv * xcc : 0.f;
    #pragma unroll
    for (int n = 0; n < 4; ++n) {
      float e = __expf(dtc * Arow[n]);
      h[n] = e * h[n] + dxv * Bv[n];
      y += h[n] * Cv[n];
    }
    y = quad_sum(y);        // DPP, no DS traffic
    if (nq == 0) *(f32x2*)&sYS[t][2 * dil] = f32x2{y, scum};
    dx = dxn; Bv = Bn; Cv = Cn;
  }

  size_t sb = ((size_t)s * B_ + b) * DI_ + di;
  *(f32x4*)(hend + sb * 16 + nq * 4) = f32x4{h[0], h[1], h[2], h[3]};
  if (nq == 0) send[sb] = scum;
  __syncthreads();
  #pragma unroll
  for (int j = 0; j < 4; ++j) {
    int id = tid + j * 256;
    if (id < SEG * 32) {
      int row = id >> 5, c4 = (id & 31) * 4;
      *(f32x4*)(ys + (mb + row) * (DI_ * 2) + di0 * 2 + c4) = *(const f32x4*)&sYS[row][c4];
    }
  }
}

// ---------------- pass B1: combine carry states across segments ----------------
// thread = (b, di, nq); hin(s) = exp(A*send[s-1])*hin(s-1) + hend[s-1]
__global__ __launch_bounds__(256)
void k_seg_combine(const float* __restrict__ hend, const float* __restrict__ send,
                   const float* __restrict__ Abuf, float* __restrict__ hinbuf) {
  int idx = blockIdx.x * 256 + threadIdx.x;   // < B_*DI_*4
  int nq = idx & 3, di = (idx >> 2) % DI_, b = (idx >> 2) / DI_;
  f32x4 A4 = *(const f32x4*)(Abuf + (size_t)di * NST + nq * 4);
  f32x4 hin = {0.f, 0.f, 0.f, 0.f};
  *(f32x4*)(hinbuf + (((size_t)0 * B_ + b) * DI_ + di) * 16 + nq * 4) = hin;
  for (int r = 0; r < NSEG - 1; ++r) {
    size_t sb = ((size_t)r * B_ + b) * DI_ + di;
    f32x4 he = *(const f32x4*)(hend + sb * 16 + nq * 4);
    float se = send[sb];
    #pragma unroll
    for (int q = 0; q < 4; ++q) hin[q] = __expf(A4[q] * se) * hin[q] + he[q];
    *(f32x4*)(hinbuf + (((size_t)(r + 1) * B_ + b) * DI_ + di) * 16 + nq * 4) = hin;
  }
}

// ---------------- pass B2: fully parallel correction + gate ----------------
// thread = (m, ch): y = (ypre + sum_n C[n]*exp(A[n]*scum)*hin[n]) * silu(z)
__global__ __launch_bounds__(256)
void k_scan_apply(const float* __restrict__ dbc, const float* __restrict__ ys,
                  const u16* __restrict__ xzb, const float* __restrict__ Abuf,
                  const float* __restrict__ hinbuf, u16* __restrict__ yb) {
  int idx = blockIdx.x * 256 + threadIdx.x;   // over M_*DI_
  int ch = idx % DI_, m = idx / DI_;
  int b = m / L_, l = m % L_, s = l / SEG;
  f32x2 yp = *(const f32x2*)(ys + (size_t)idx * 2);
  float y = yp.x;
  if (s > 0) {
    const float scum = yp.y;
    const float* Cp = dbc + (size_t)m * 56 + 40;
    const float* Ap = Abuf + (size_t)ch * NST;
    const float* hp = hinbuf + (((size_t)s * B_ + b) * DI_ + ch) * 16;
    float corr = 0.f;
    #pragma unroll
    for (int q = 0; q < 4; ++q) {
      f32x4 C4 = *(const f32x4*)(Cp + q * 4);
      f32x4 A4 = *(const f32x4*)(Ap + q * 4);
      f32x4 H4 = *(const f32x4*)(hp + q * 4);
      #pragma unroll
      for (int n = 0; n < 4; ++n) corr += C4[n] * __expf(A4[n] * scum) * H4[n];
    }
    y += corr;
  }
  float z = bf2f(xzb[(size_t)m * 1536 + DI_ + ch]);
  yb[idx] = f2bf(y * z / (1.f + __expf(-z)));
}

// ---------------- final LN partial sums: grid (B_, 7), 28 rows each ----------------
__global__ __launch_bounds__(384)
void k_feat_part(const float* __restrict__ x, float* __restrict__ partial) {
  const int b = blockIdx.x, j = blockIdx.y, d = threadIdx.x;
  __shared__ float red[12];
  const int l0 = j * 28;
  float acc = 0.f;
  float v = x[((size_t)b * L_ + l0) * D_ + d];
  for (int l = l0; l < l0 + 28; ++l) {
    float vn = (l + 1 < l0 + 28) ? x[((size_t)b * L_ + l + 1) * D_ + d] : 0.f;
    float s = v, s2 = v * v;
    #pragma unroll
    for (int o = 32; o > 0; o >>= 1) { s += __shfl_xor(s, o); s2 += __shfl_xor(s2, o); }
    int wid = d >> 6;
    if ((d & 63) == 0) { red[wid] = s; red[6 + wid] = s2; }
    __syncthreads();
    float ts = 0.f, ts2 = 0.f;
    #pragma unroll
    for (int w = 0; w < 6; ++w) { ts += red[w]; ts2 += red[6 + w]; }
    float mu = ts * (1.f / (float)D_);
    float var = ts2 * (1.f / (float)D_) - mu * mu;
    acc += (v - mu) * rsqrtf(var + 1e-5f);
    __syncthreads();
    v = vn;
  }
  partial[((size_t)(b * 7 + j)) * D_ + d] = acc;
}

// ---------------- head (folds final-LN gamma/beta + mean) ----------------
__global__ __launch_bounds__(256)
void k_head(const float* __restrict__ partial, const float* __restrict__ g,
            const float* __restrict__ bt, const float* __restrict__ hw,
            const float* __restrict__ hb, float* __restrict__ out) {
  const int b = blockIdx.y;
  const int c = blockIdx.x * 256 + threadIdx.x;
  __shared__ float sf[D_];
  for (int i = threadIdx.x; i < D_; i += 256) {
    float s = 0.f;
    #pragma unroll
    for (int j = 0; j < 7; ++j) s += partial[((size_t)(b * 7 + j)) * D_ + i];
    sf[i] = g[i] * (s * (1.f / (float)L_)) + bt[i];
  }
  __syncthreads();
  if (c >= NC_) return;
  float acc = hb[c];
  for (int d = 0; d < D_; ++d) acc += sf[d] * hw[(size_t)d * NC_ + c];
  out[(size_t)b * NC_ + c] = acc;
}

// =====================================================================
extern "C" void kernel_launch(void* const* d_in, const int* in_sizes, int n_in,
                              void* d_out, int out_size, void* d_ws, size_t ws_size,
                              hipStream_t stream) {
  const float* x_in    = (const float*)d_in[0];
  const float* patch_w = (const float*)d_in[1];
  const float* patch_b = (const float*)d_in[2];
  const float* pos     = (const float*)d_in[3];
  const float* bn_g    = (const float*)d_in[4];
  const float* bn_b    = (const float*)d_in[5];
  const float* in_w    = (const float*)d_in[6];
  const float* conv_w  = (const float*)d_in[7];
  const float* conv_b  = (const float*)d_in[8];
  const float* xp_w    = (const float*)d_in[9];
  const float* dtp_w   = (const float*)d_in[10];
  const float* dtp_b   = (const float*)d_in[11];
  const float* A_log   = (const float*)d_in[12];
  const float* D_skip  = (const float*)d_in[13];
  const float* out_w   = (const float*)d_in[14];
  const float* norm_g  = (const float*)d_in[15];
  const float* norm_b  = (const float*)d_in[16];
  const float* head_w  = (const float*)d_in[17];
  const float* head_b  = (const float*)d_in[18];
  float* out = (float*)d_out;

  char* ws = (char*)d_ws;
  size_t off = 0;
  auto alloc = [&](size_t bytes) { size_t o = off; off += (bytes + 255) & ~(size_t)255; return o; };

  float* xbuf   = (float*)(ws + alloc((size_t)M_ * D_ * 4));
  u16*   hbuf   = (u16*)  (ws + alloc((size_t)M_ * D_ * 2));
  u16*   xzb    = (u16*)  (ws + alloc((size_t)M_ * 1536 * 2));
  u16*   xcbb   = (u16*)  (ws + alloc((size_t)M_ * DI_ * 2));
  float* dbcbuf = (float*)(ws + alloc((size_t)M_ * 56 * 4));
  float* dtbuf  = (float*)(ws + alloc((size_t)M_ * DI_ * 4));   // aliased as im2col before loop
  u16*   ybuf   = (u16*)  (ws + alloc((size_t)M_ * DI_ * 2));
  float* ysbuf  = (float*)(ws + alloc((size_t)M_ * DI_ * 2 * 4));
  float* hend   = (float*)(ws + alloc((size_t)NSEG * B_ * DI_ * NST * 4));
  float* send   = (float*)(ws + alloc((size_t)NSEG * B_ * DI_ * 4));
  float* hinbuf = (float*)(ws + alloc((size_t)NSEG * B_ * DI_ * NST * 4));
  float* Abuf   = (float*)(ws + alloc((size_t)DEPTH * DI_ * NST * 4));
  float* partial= (float*)(ws + alloc((size_t)B_ * 7 * D_ * 4));
  u16*   in_wT  = (u16*)  (ws + alloc((size_t)DEPTH * 1536 * D_ * 2));
  u16*   xp_wT  = (u16*)  (ws + alloc((size_t)DEPTH * 56 * DI_ * 2));
  u16*   out_wT = (u16*)  (ws + alloc((size_t)DEPTH * D_ * DI_ * 2));
  u16*   pw_b   = (u16*)  (ws + alloc((size_t)D_ * 768 * 2));
  u16*   im2col = (u16*)dtbuf;

  dim3 tb(32, 8);
  k_transpose_bf16<<<dim3(48, 12, DEPTH), tb, 0, stream>>>(in_w,  in_wT,  D_, 1536);
  k_transpose_bf16<<<dim3(2, 24, DEPTH),  tb, 0, stream>>>(xp_w,  xp_wT,  DI_, 56);
  k_transpose_bf16<<<dim3(12, 24, DEPTH), tb, 0, stream>>>(out_w, out_wT, DI_, D_);
  k_convert_bf16<<<(D_ * 768 + 255) / 256, 256, 0, stream>>>(patch_w, pw_b, D_ * 768);
  k_prepA<<<(DEPTH * DI_ * NST + 255) / 256, 256, 0, stream>>>(A_log, Abuf, DEPTH * DI_ * NST);

  k_im2col<<<(M_ * 768 + 255) / 256, 256, 0, stream>>>(x_in, im2col);
  k_gemm<64,128,2,0><<<dim3(M_ / 64, 3), 256, 0, stream>>>(im2col, pw_b, xbuf, D_, 768, patch_b, pos);

  for (int dp = 0; dp < DEPTH; ++dp) {
    const u16* iwt = in_wT  + (size_t)dp * 1536 * D_;
    const u16* xwt = xp_wT  + (size_t)dp * 56 * DI_;
    const u16* owt = out_wT + (size_t)dp * D_ * DI_;
    const float* Al = Abuf + (size_t)dp * DI_ * NST;
    k_ln<<<M_, 384, 0, stream>>>(xbuf, bn_g + dp * D_, bn_b + dp * D_, hbuf);
    k_gemm<128,128,0,1><<<dim3(M_ / 128, 12), 256, 0, stream>>>(hbuf, iwt, (float*)xzb, 1536, D_, nullptr, nullptr);
    k_conv<<<(M_ * (DI_ / 4) + 255) / 256, 256, 0, stream>>>(xzb, conv_w + (size_t)dp * DI_ * 4,
                                                             conv_b + dp * DI_, xcbb);
    k_gemm<32,64,0,0><<<dim3(M_ / 32, 1), 256, 0, stream>>>(xcbb, xwt, dbcbuf, 56, DI_, nullptr, nullptr);
    k_dt<<<dim3(M_ / 16, DI_ / 256), 256, 0, stream>>>(dbcbuf, dtp_w + (size_t)dp * R_ * DI_,
                                                       dtp_b + dp * DI_, dtbuf);
    k_scan_part<<<dim3(B_, DI_ / 64, NSEG), 256, 0, stream>>>(dbcbuf, dtbuf, xcbb, Al,
                                                              D_skip + dp * DI_, ysbuf, hend, send);
    k_seg_combine<<<(B_ * DI_ * 4) / 256, 256, 0, stream>>>(hend, send, Al, hinbuf);
    k_scan_apply<<<(M_ * DI_) / 256, 256, 0, stream>>>(dbcbuf, ysbuf, xzb, Al, hinbuf, ybuf);
    k_gemm<64,128,1,0><<<dim3(M_ / 64, 3), 256, 0, stream>>>(ybuf, owt, xbuf, D_, DI_, nullptr, nullptr);
  }

  k_feat_part<<<dim3(B_, 7), 384, 0, stream>>>(xbuf, partial);
  k_head<<<dim3((NC_ + 255) / 256, B_), 256, 0, stream>>>(partial, norm_g, norm_b, head_w, head_b, out);
}

// Round 8
// 1870.930 us; speedup vs baseline: 1.0641x; 1.0641x over previous
//
#include <hip/hip_runtime.h>
#include <math.h>

typedef short bf16x8 __attribute__((ext_vector_type(8)));
typedef float f32x4 __attribute__((ext_vector_type(4)));
typedef float f32x2 __attribute__((ext_vector_type(2)));
typedef unsigned short u16;
typedef unsigned int u32;
typedef unsigned short u16x4 __attribute__((ext_vector_type(4)));

#define B_    32
#define D_    384
#define DEPTH 12
#define NST   16
#define DI_   768
#define R_    24
#define L_    196
#define NC_   1000
#define M_    (B_*L_)   // 6272
#define SEG   28        // scan segment length (L_ = 7*28 exactly)
#define NSEG  7

__device__ __forceinline__ u16 f2bf(float f) {
  union { float f; unsigned u; } v; v.f = f;
  unsigned r = v.u + 0x7fffu + ((v.u >> 16) & 1u);
  return (u16)(r >> 16);
}
__device__ __forceinline__ float bf2f(u16 x) {
  union { unsigned u; float f; } v; v.u = ((unsigned)x) << 16;
  return v.f;
}
// sum across each quad of lanes via DPP (VALU pipe, no DS traffic)
__device__ __forceinline__ float quad_sum(float y) {
  y += __int_as_float(__builtin_amdgcn_update_dpp(0, __float_as_int(y), 0xB1, 0xf, 0xf, true)); // xor1
  y += __int_as_float(__builtin_amdgcn_update_dpp(0, __float_as_int(y), 0x4E, 0xf, 0xf, true)); // xor2
  return y;
}

// ---------------- weight prep ----------------
__global__ void k_transpose_bf16(const float* __restrict__ in, u16* __restrict__ out,
                                 int R, int C) {
  __shared__ float tile[32][33];
  const size_t zoff = (size_t)blockIdx.z * R * C;
  in  += zoff; out += zoff;
  int c0 = blockIdx.x * 32, r0 = blockIdx.y * 32;
  int tx = threadIdx.x, ty = threadIdx.y;
  for (int i = ty; i < 32; i += 8) {
    int r = r0 + i, c = c0 + tx;
    tile[i][tx] = (r < R && c < C) ? in[(size_t)r * C + c] : 0.f;
  }
  __syncthreads();
  for (int i = ty; i < 32; i += 8) {
    int c = c0 + i, r = r0 + tx;
    if (c < C && r < R) out[(size_t)c * R + r] = f2bf(tile[tx][i]);
  }
}

__global__ void k_convert_bf16(const float* __restrict__ in, u16* __restrict__ out, int n) {
  int i = blockIdx.x * 256 + threadIdx.x;
  if (i < n) out[i] = f2bf(in[i]);
}

// A = -exp(A_log), all layers at once
__global__ void k_prepA(const float* __restrict__ alog, float* __restrict__ A, int n) {
  int i = blockIdx.x * 256 + threadIdx.x;
  if (i < n) A[i] = -__expf(alog[i]);
}

// ---------------- im2col for patch embed ----------------
__global__ void k_im2col(const float* __restrict__ x, u16* __restrict__ xcol) {
  int idx = blockIdx.x * 256 + threadIdx.x;     // over M_*768
  if (idx >= M_ * 768) return;
  int k = idx % 768, m = idx / 768;
  int b = m / L_, l = m % L_;
  int li = l / 14, lj = l % 14;
  int c = k / 256, r = k % 256;
  int i = r / 16, j = r % 16;
  int hh = li * 16 + i, ww = lj * 16 + j;
  xcol[idx] = f2bf(x[(((size_t)b * 3 + c) * 224 + hh) * 224 + ww]);
}

// ---------------- GEMM: C(MxN) = A(MxK,bf16) * BT(NxK,bf16)^T ----------------
// EPI: 0 = store, 1 = add (residual), 2 = store + bias[col] + pos[(row%L)*N+col]
// OB:  1 = store bf16 (u16) instead of f32 (EPI==0 only)
template<int BM, int BN, int EPI, int OB>
__global__ __launch_bounds__(256)
void k_gemm(const u16* __restrict__ A, const u16* __restrict__ BT,
            float* __restrict__ Cout, int Nn, int Kk,
            const float* __restrict__ bias, const float* __restrict__ pos) {
  const int m0 = blockIdx.x * BM;
  const int n0 = blockIdx.y * BN;
  __shared__ u16 lA[BM * 72];
  __shared__ u16 lB[BN * 72];
  const int tid  = threadIdx.x;
  const int wave = tid >> 6, lane = tid & 63;
  const int wm = (wave >> 1) * (BM / 2), wn = (wave & 1) * (BN / 2);
  constexpr int MI = BM / 32, NJ = BN / 32;
  constexpr int NV = (BM + BN) / 32;
  f32x4 acc[MI][NJ] = {};
  const int fr = lane & 15, kg = (lane >> 4) * 8;

  for (int k0 = 0; k0 < Kk; k0 += 64) {
    bf16x8 v[NV];
    #pragma unroll
    for (int q = 0; q < NV; ++q) {
      int id = tid + q * 256;
      int row = id >> 3, vv = id & 7;
      bf16x8 t = {};
      if (row < BM) {
        t = *(const bf16x8*)(A + (size_t)(m0 + row) * Kk + k0 + vv * 8);
      } else {
        int br = n0 + row - BM;
        if (br < Nn) t = *(const bf16x8*)(BT + (size_t)br * Kk + k0 + vv * 8);
      }
      v[q] = t;
    }
    __syncthreads();
    #pragma unroll
    for (int q = 0; q < NV; ++q) {
      int id = tid + q * 256;
      int row = id >> 3, vv = id & 7;
      u16* dst = (row < BM) ? (lA + row * 72 + vv * 8) : (lB + (size_t)(row - BM) * 72 + vv * 8);
      *(bf16x8*)dst = v[q];
    }
    __syncthreads();
    #pragma unroll
    for (int kk = 0; kk < 64; kk += 32) {
      bf16x8 af[MI], bfr[NJ];
      #pragma unroll
      for (int i = 0; i < MI; ++i)
        af[i] = *(const bf16x8*)(lA + (wm + i * 16 + fr) * 72 + kk + kg);
      #pragma unroll
      for (int j = 0; j < NJ; ++j)
        bfr[j] = *(const bf16x8*)(lB + (wn + j * 16 + fr) * 72 + kk + kg);
      #pragma unroll
      for (int i = 0; i < MI; ++i)
        #pragma unroll
        for (int j = 0; j < NJ; ++j)
          acc[i][j] = __builtin_amdgcn_mfma_f32_16x16x32_bf16(af[i], bfr[j], acc[i][j], 0, 0, 0);
    }
  }

  const int rg = (lane >> 4) * 4;
  #pragma unroll
  for (int i = 0; i < MI; ++i) {
    int row = m0 + wm + i * 16 + rg;
    #pragma unroll
    for (int j = 0; j < NJ; ++j) {
      int col = n0 + wn + j * 16 + fr;
      if (col >= Nn) continue;
      #pragma unroll
      for (int r = 0; r < 4; ++r) {
        float v = acc[i][j][r];
        size_t idx = (size_t)(row + r) * Nn + col;
        if (EPI == 0) {
          if (OB) ((u16*)Cout)[idx] = f2bf(v);
          else    Cout[idx] = v;
        }
        else if (EPI == 1) Cout[idx] += v;
        else               Cout[idx] = v + bias[col] + pos[(size_t)((row + r) % L_) * Nn + col];
      }
    }
  }
}

// ---------------- LayerNorm (writes bf16 for GEMM A) ----------------
__global__ __launch_bounds__(384)
void k_ln(const float* __restrict__ x, const float* __restrict__ g,
          const float* __restrict__ bt, u16* __restrict__ h) {
  const int m = blockIdx.x, d = threadIdx.x;
  __shared__ float red[12];
  float v = x[(size_t)m * D_ + d];
  float s = v, s2 = v * v;
  #pragma unroll
  for (int o = 32; o > 0; o >>= 1) { s += __shfl_xor(s, o); s2 += __shfl_xor(s2, o); }
  int wid = d >> 6;
  if ((d & 63) == 0) { red[wid] = s; red[6 + wid] = s2; }
  __syncthreads();
  float ts = 0.f, ts2 = 0.f;
  #pragma unroll
  for (int w = 0; w < 6; ++w) { ts += red[w]; ts2 += red[6 + w]; }
  float mu = ts / (float)D_;
  float var = ts2 / (float)D_ - mu * mu;
  float rs = rsqrtf(var + 1e-5f);
  h[(size_t)m * D_ + d] = f2bf((v - mu) * rs * g[d] + bt[d]);
}

// ---------------- causal depthwise conv (K=4) + SiLU: bf16 in, bf16 out ----------------
__global__ __launch_bounds__(256)
void k_conv(const u16* __restrict__ xzb, const float* __restrict__ cw,
            const float* __restrict__ cb, u16* __restrict__ xcb) {
  int idx = blockIdx.x * 256 + threadIdx.x;   // over M_ * DI_/4
  if (idx >= M_ * (DI_ / 4)) return;
  int dq = idx % (DI_ / 4), m = idx / (DI_ / 4), l = m % L_;
  int di4 = dq * 4;
  const u16* base = xzb + (size_t)m * 1536 + di4;
  float xv[4][4];
  #pragma unroll
  for (int t = 0; t < 4; ++t) {
    int back = 3 - t;
    u16x4 v = {};
    if (l >= back) v = *(const u16x4*)(base - (size_t)back * 1536);
    #pragma unroll
    for (int c = 0; c < 4; ++c) xv[t][c] = bf2f(v[c]);
  }
  f32x4 bv = *(const f32x4*)(cb + di4);
  u16x4 outv;
  #pragma unroll
  for (int c = 0; c < 4; ++c) {
    f32x4 w = *(const f32x4*)(cw + (size_t)(di4 + c) * 4);
    float acc = bv[c] + w[0] * xv[0][c] + w[1] * xv[1][c] + w[2] * xv[2][c] + w[3] * xv[3][c];
    float s = acc / (1.f + __expf(-acc));
    outv[c] = f2bf(s);
  }
  *(u16x4*)(xcb + (size_t)m * DI_ + di4) = outv;
}

// ---------------- dt = softplus(dbc[:, :24] @ dtp_w + dtp_b) ----------------
__global__ __launch_bounds__(256)
void k_dt(const float* __restrict__ dbc, const float* __restrict__ dtw,
          const float* __restrict__ dtb, float* __restrict__ dt) {
  const int m0 = blockIdx.x * 16;
  const int di = blockIdx.y * 256 + threadIdx.x;
  __shared__ float sd[16][25];
  #pragma unroll
  for (int q = 0; q < 2; ++q) {
    int id = threadIdx.x + q * 256;
    if (id < 16 * 24) {
      int r = id / 24, c = id % 24;
      sd[r][c] = dbc[(size_t)(m0 + r) * 56 + c];
    }
  }
  __syncthreads();
  float w[24];
  #pragma unroll
  for (int r = 0; r < 24; ++r) w[r] = dtw[r * DI_ + di];
  const float bv = dtb[di];
  #pragma unroll 4
  for (int mi = 0; mi < 16; ++mi) {
    float acc = bv;
    #pragma unroll
    for (int r = 0; r < 24; ++r) acc += sd[mi][r] * w[r];
    float e  = __expf(-fabsf(acc));
    float sp = fmaxf(acc, 0.f) + __logf(1.f + e);
    dt[(size_t)(m0 + mi) * DI_ + di] = sp;
  }
}

// ---------------- pass A: local segment scan ----------------
// grid (B_, DI_/64, NSEG), 256 thr = 64 ch x 4 nq (quad = one channel's 4 state-quads)
// writes ys[m][ch] = {y_pre, scum}, hend (f32x4/lane), send (scalar/ch)
__global__ __launch_bounds__(256)
void k_scan_part(const float* __restrict__ dbc, const float* __restrict__ dt,
                 const u16* __restrict__ xcb, const float* __restrict__ Abuf,
                 const float* __restrict__ Dsk, float* __restrict__ ys,
                 float* __restrict__ hend, float* __restrict__ send) {
  const int b   = blockIdx.x;
  const int di0 = blockIdx.y * 64;
  const int s   = blockIdx.z;
  const int tid = threadIdx.x;
  const int dil = tid >> 2, nq = tid & 3;
  const int di  = di0 + dil;
  __shared__ float sDX[SEG][128];   // {dt,xc} interleaved per channel
  __shared__ float sYS[SEG][128];   // {y, scum} per channel

  const f32x4 Arow = *(const f32x4*)(Abuf + (size_t)di * NST + nq * 4);
  const float Dv = Dsk[di];
  const size_t mb = (size_t)b * L_ + (size_t)s * SEG;

  {
    int r = tid >> 4, cc = (tid & 15) * 4;
    #pragma unroll
    for (int j = 0; j < 2; ++j) {
      int row = r + j * 16;
      if (row < SEG) {
        f32x4 dtv = *(const f32x4*)(dt + (mb + row) * DI_ + di0 + cc);
        u16x4 xv  = *(const u16x4*)(xcb + (mb + row) * DI_ + di0 + cc);
        f32x4 w0 = {dtv[0], bf2f(xv[0]), dtv[1], bf2f(xv[1])};
        f32x4 w1 = {dtv[2], bf2f(xv[2]), dtv[3], bf2f(xv[3])};
        *(f32x4*)&sDX[row][cc * 2]     = w0;
        *(f32x4*)&sDX[row][cc * 2 + 4] = w1;
      }
    }
  }
  __syncthreads();

  const float* bc = dbc + mb * 56;
  float h[4] = {0.f, 0.f, 0.f, 0.f};
  float scum = 0.f;
  f32x2 dx = *(const f32x2*)&sDX[0][2 * dil];
  f32x4 Bv = *(const f32x4*)(bc + 24 + nq * 4);
  f32x4 Cv = *(const f32x4*)(bc + 40 + nq * 4);
  #pragma unroll 4
  for (int t = 0; t < SEG; ++t) {
    f32x2 dxn = {}; f32x4 Bn = {}, Cn = {};
    if (t + 1 < SEG) {      // prefetch next step (regs; B/C from global via L1)
      dxn = *(const f32x2*)&sDX[t + 1][2 * dil];
      Bn = *(const f32x4*)(bc + (t + 1) * 56 + 24 + nq * 4);
      Cn = *(const f32x4*)(bc + (t + 1) * 56 + 40 + nq * 4);
    }
    float dtc = dx.x, xcc = dx.y;
    scum += dtc;
    float dxv = dtc * xcc;
    float y = (nq == 0) ? Dv * xcc : 0.f;
    #pragma unroll
    for (int n = 0; n < 4; ++n) {
      float e = __expf(dtc * Arow[n]);
      h[n] = e * h[n] + dxv * Bv[n];
      y += h[n] * Cv[n];
    }
    y = quad_sum(y);        // DPP, no DS traffic
    if (nq == 0) *(f32x2*)&sYS[t][2 * dil] = f32x2{y, scum};
    dx = dxn; Bv = Bn; Cv = Cn;
  }

  size_t sb = ((size_t)s * B_ + b) * DI_ + di;
  *(f32x4*)(hend + sb * 16 + nq * 4) = f32x4{h[0], h[1], h[2], h[3]};
  if (nq == 0) send[sb] = scum;
  __syncthreads();
  #pragma unroll
  for (int j = 0; j < 4; ++j) {
    int id = tid + j * 256;
    if (id < SEG * 32) {
      int row = id >> 5, c4 = (id & 31) * 4;
      *(f32x4*)(ys + (mb + row) * (DI_ * 2) + di0 * 2 + c4) = *(const f32x4*)&sYS[row][c4];
    }
  }
}

// ---------------- pass B1: combine carry states across segments ----------------
// thread = (b, di, nq); hin(s) = exp(A*send[s-1])*hin(s-1) + hend[s-1]
__global__ __launch_bounds__(256)
void k_seg_combine(const float* __restrict__ hend, const float* __restrict__ send,
                   const float* __restrict__ Abuf, float* __restrict__ hinbuf) {
  int idx = blockIdx.x * 256 + threadIdx.x;   // < B_*DI_*4
  int nq = idx & 3, di = (idx >> 2) % DI_, b = (idx >> 2) / DI_;
  f32x4 A4 = *(const f32x4*)(Abuf + (size_t)di * NST + nq * 4);
  f32x4 hin = {0.f, 0.f, 0.f, 0.f};
  *(f32x4*)(hinbuf + (((size_t)0 * B_ + b) * DI_ + di) * 16 + nq * 4) = hin;
  for (int r = 0; r < NSEG - 1; ++r) {
    size_t sb = ((size_t)r * B_ + b) * DI_ + di;
    f32x4 he = *(const f32x4*)(hend + sb * 16 + nq * 4);
    float se = send[sb];
    #pragma unroll
    for (int q = 0; q < 4; ++q) hin[q] = __expf(A4[q] * se) * hin[q] + he[q];
    *(f32x4*)(hinbuf + (((size_t)(r + 1) * B_ + b) * DI_ + di) * 16 + nq * 4) = hin;
  }
}

// ---------------- pass B2: block-structured correction + gate ----------------
// grid (B_, DI_/64, NSEG), 256 thr = 64 ch x 4 nq. All loads coalesced / LDS-staged.
// y = (ypre + sum_n C_l[n]*exp(A[n]*scum_l)*hin[n]) * silu(z), bf16 out
__global__ __launch_bounds__(256)
void k_scan_apply(const float* __restrict__ dbc, const float* __restrict__ ys,
                  const u16* __restrict__ xzb, const float* __restrict__ Abuf,
                  const float* __restrict__ hinbuf, u16* __restrict__ yb) {
  const int b   = blockIdx.x;
  const int di0 = blockIdx.y * 64;
  const int s   = blockIdx.z;
  const int tid = threadIdx.x;
  const size_t mb = (size_t)b * L_ + (size_t)s * SEG;
  __shared__ float sC[SEG][16];    // C_l (shared by all channels)
  __shared__ float sA[64][16];
  __shared__ float sH[64][16];
  __shared__ float sYO[SEG][64];   // pre-gate y

  if (s > 0) {
    {
      int ch = tid >> 2, q = tid & 3;
      *(f32x4*)&sA[ch][q * 4] = *(const f32x4*)(Abuf + (size_t)(di0 + ch) * NST + q * 4);
      *(f32x4*)&sH[ch][q * 4] =
          *(const f32x4*)(hinbuf + (((size_t)s * B_ + b) * DI_ + di0 + ch) * 16 + q * 4);
      if (tid < SEG * 4) {
        int row = tid >> 2, qq = tid & 3;
        *(f32x4*)&sC[row][qq * 4] = *(const f32x4*)(dbc + (mb + row) * 56 + 40 + qq * 4);
      }
    }
    __syncthreads();
    const int dil = tid >> 2, nq = tid & 3;
    const f32x4 A4 = *(const f32x4*)&sA[dil][nq * 4];
    const f32x4 H4 = *(const f32x4*)&sH[dil][nq * 4];
    #pragma unroll 4
    for (int l = 0; l < SEG; ++l) {
      f32x2 yp = *(const f32x2*)(ys + (mb + l) * (DI_ * 2) + (size_t)(di0 + dil) * 2);
      f32x4 C4 = *(const f32x4*)&sC[l][nq * 4];
      float scum = yp.y;
      float corr = 0.f;
      #pragma unroll
      for (int n = 0; n < 4; ++n) corr += C4[n] * __expf(A4[n] * scum) * H4[n];
      corr = quad_sum(corr);
      if (nq == 0) sYO[l][dil] = yp.x + corr;
    }
  } else {
    #pragma unroll
    for (int j = 0; j < 7; ++j) {            // 28*64/256
      int id = tid + j * 256;
      int row = id >> 6, ch = id & 63;
      sYO[row][ch] = ys[(mb + row) * (DI_ * 2) + (size_t)(di0 + ch) * 2];
    }
  }
  __syncthreads();
  // gate + pack (coalesced u32 writes)
  #pragma unroll
  for (int j = 0; j < 4; ++j) {
    int id = tid + j * 256;
    if (id < SEG * 32) {
      int row = id >> 5, c2 = id & 31;
      int ch0 = c2 * 2;
      float y0 = sYO[row][ch0], y1 = sYO[row][ch0 + 1];
      u32 zz = *(const u32*)(xzb + (mb + row) * 1536 + DI_ + di0 + ch0);
      float z0 = bf2f((u16)(zz & 0xffff)), z1 = bf2f((u16)(zz >> 16));
      u32 o = (u32)f2bf(y0 * z0 / (1.f + __expf(-z0)))
            | ((u32)f2bf(y1 * z1 / (1.f + __expf(-z1))) << 16);
      *((u32*)yb + ((mb + row) * DI_ + di0) / 2 + c2) = o;
    }
  }
}

// ---------------- final LN partial sums: grid (B_, 7), 28 rows each ----------------
__global__ __launch_bounds__(384)
void k_feat_part(const float* __restrict__ x, float* __restrict__ partial) {
  const int b = blockIdx.x, j = blockIdx.y, d = threadIdx.x;
  __shared__ float red[12];
  const int l0 = j * 28;
  float acc = 0.f;
  float v = x[((size_t)b * L_ + l0) * D_ + d];
  for (int l = l0; l < l0 + 28; ++l) {
    float vn = (l + 1 < l0 + 28) ? x[((size_t)b * L_ + l + 1) * D_ + d] : 0.f;
    float s = v, s2 = v * v;
    #pragma unroll
    for (int o = 32; o > 0; o >>= 1) { s += __shfl_xor(s, o); s2 += __shfl_xor(s2, o); }
    int wid = d >> 6;
    if ((d & 63) == 0) { red[wid] = s; red[6 + wid] = s2; }
    __syncthreads();
    float ts = 0.f, ts2 = 0.f;
    #pragma unroll
    for (int w = 0; w < 6; ++w) { ts += red[w]; ts2 += red[6 + w]; }
    float mu = ts * (1.f / (float)D_);
    float var = ts2 * (1.f / (float)D_) - mu * mu;
    acc += (v - mu) * rsqrtf(var + 1e-5f);
    __syncthreads();
    v = vn;
  }
  partial[((size_t)(b * 7 + j)) * D_ + d] = acc;
}

// ---------------- head (folds final-LN gamma/beta + mean) ----------------
__global__ __launch_bounds__(256)
void k_head(const float* __restrict__ partial, const float* __restrict__ g,
            const float* __restrict__ bt, const float* __restrict__ hw,
            const float* __restrict__ hb, float* __restrict__ out) {
  const int b = blockIdx.y;
  const int c = blockIdx.x * 256 + threadIdx.x;
  __shared__ float sf[D_];
  for (int i = threadIdx.x; i < D_; i += 256) {
    float s = 0.f;
    #pragma unroll
    for (int j = 0; j < 7; ++j) s += partial[((size_t)(b * 7 + j)) * D_ + i];
    sf[i] = g[i] * (s * (1.f / (float)L_)) + bt[i];
  }
  __syncthreads();
  if (c >= NC_) return;
  float acc = hb[c];
  for (int d = 0; d < D_; ++d) acc += sf[d] * hw[(size_t)d * NC_ + c];
  out[(size_t)b * NC_ + c] = acc;
}

// =====================================================================
extern "C" void kernel_launch(void* const* d_in, const int* in_sizes, int n_in,
                              void* d_out, int out_size, void* d_ws, size_t ws_size,
                              hipStream_t stream) {
  const float* x_in    = (const float*)d_in[0];
  const float* patch_w = (const float*)d_in[1];
  const float* patch_b = (const float*)d_in[2];
  const float* pos     = (const float*)d_in[3];
  const float* bn_g    = (const float*)d_in[4];
  const float* bn_b    = (const float*)d_in[5];
  const float* in_w    = (const float*)d_in[6];
  const float* conv_w  = (const float*)d_in[7];
  const float* conv_b  = (const float*)d_in[8];
  const float* xp_w    = (const float*)d_in[9];
  const float* dtp_w   = (const float*)d_in[10];
  const float* dtp_b   = (const float*)d_in[11];
  const float* A_log   = (const float*)d_in[12];
  const float* D_skip  = (const float*)d_in[13];
  const float* out_w   = (const float*)d_in[14];
  const float* norm_g  = (const float*)d_in[15];
  const float* norm_b  = (const float*)d_in[16];
  const float* head_w  = (const float*)d_in[17];
  const float* head_b  = (const float*)d_in[18];
  float* out = (float*)d_out;

  char* ws = (char*)d_ws;
  size_t off = 0;
  auto alloc = [&](size_t bytes) { size_t o = off; off += (bytes + 255) & ~(size_t)255; return o; };

  float* xbuf   = (float*)(ws + alloc((size_t)M_ * D_ * 4));
  u16*   hbuf   = (u16*)  (ws + alloc((size_t)M_ * D_ * 2));
  u16*   xzb    = (u16*)  (ws + alloc((size_t)M_ * 1536 * 2));
  u16*   xcbb   = (u16*)  (ws + alloc((size_t)M_ * DI_ * 2));
  float* dbcbuf = (float*)(ws + alloc((size_t)M_ * 56 * 4));
  float* dtbuf  = (float*)(ws + alloc((size_t)M_ * DI_ * 4));   // aliased as im2col before loop
  u16*   ybuf   = (u16*)  (ws + alloc((size_t)M_ * DI_ * 2));
  float* ysbuf  = (float*)(ws + alloc((size_t)M_ * DI_ * 2 * 4));
  float* hend   = (float*)(ws + alloc((size_t)NSEG * B_ * DI_ * NST * 4));
  float* send   = (float*)(ws + alloc((size_t)NSEG * B_ * DI_ * 4));
  float* hinbuf = (float*)(ws + alloc((size_t)NSEG * B_ * DI_ * NST * 4));
  float* Abuf   = (float*)(ws + alloc((size_t)DEPTH * DI_ * NST * 4));
  float* partial= (float*)(ws + alloc((size_t)B_ * 7 * D_ * 4));
  u16*   in_wT  = (u16*)  (ws + alloc((size_t)DEPTH * 1536 * D_ * 2));
  u16*   xp_wT  = (u16*)  (ws + alloc((size_t)DEPTH * 56 * DI_ * 2));
  u16*   out_wT = (u16*)  (ws + alloc((size_t)DEPTH * D_ * DI_ * 2));
  u16*   pw_b   = (u16*)  (ws + alloc((size_t)D_ * 768 * 2));
  u16*   im2col = (u16*)dtbuf;

  dim3 tb(32, 8);
  k_transpose_bf16<<<dim3(48, 12, DEPTH), tb, 0, stream>>>(in_w,  in_wT,  D_, 1536);
  k_transpose_bf16<<<dim3(2, 24, DEPTH),  tb, 0, stream>>>(xp_w,  xp_wT,  DI_, 56);
  k_transpose_bf16<<<dim3(12, 24, DEPTH), tb, 0, stream>>>(out_w, out_wT, DI_, D_);
  k_convert_bf16<<<(D_ * 768 + 255) / 256, 256, 0, stream>>>(patch_w, pw_b, D_ * 768);
  k_prepA<<<(DEPTH * DI_ * NST + 255) / 256, 256, 0, stream>>>(A_log, Abuf, DEPTH * DI_ * NST);

  k_im2col<<<(M_ * 768 + 255) / 256, 256, 0, stream>>>(x_in, im2col);
  k_gemm<64,128,2,0><<<dim3(M_ / 64, 3), 256, 0, stream>>>(im2col, pw_b, xbuf, D_, 768, patch_b, pos);

  for (int dp = 0; dp < DEPTH; ++dp) {
    const u16* iwt = in_wT  + (size_t)dp * 1536 * D_;
    const u16* xwt = xp_wT  + (size_t)dp * 56 * DI_;
    const u16* owt = out_wT + (size_t)dp * D_ * DI_;
    const float* Al = Abuf + (size_t)dp * DI_ * NST;
    k_ln<<<M_, 384, 0, stream>>>(xbuf, bn_g + dp * D_, bn_b + dp * D_, hbuf);
    k_gemm<128,128,0,1><<<dim3(M_ / 128, 12), 256, 0, stream>>>(hbuf, iwt, (float*)xzb, 1536, D_, nullptr, nullptr);
    k_conv<<<(M_ * (DI_ / 4) + 255) / 256, 256, 0, stream>>>(xzb, conv_w + (size_t)dp * DI_ * 4,
                                                             conv_b + dp * DI_, xcbb);
    k_gemm<32,64,0,0><<<dim3(M_ / 32, 1), 256, 0, stream>>>(xcbb, xwt, dbcbuf, 56, DI_, nullptr, nullptr);
    k_dt<<<dim3(M_ / 16, DI_ / 256), 256, 0, stream>>>(dbcbuf, dtp_w + (size_t)dp * R_ * DI_,
                                                       dtp_b + dp * DI_, dtbuf);
    k_scan_part<<<dim3(B_, DI_ / 64, NSEG), 256, 0, stream>>>(dbcbuf, dtbuf, xcbb, Al,
                                                              D_skip + dp * DI_, ysbuf, hend, send);
    k_seg_combine<<<(B_ * DI_ * 4) / 256, 256, 0, stream>>>(hend, send, Al, hinbuf);
    k_scan_apply<<<dim3(B_, DI_ / 64, NSEG), 256, 0, stream>>>(dbcbuf, ysbuf, xzb, Al, hinbuf, ybuf);
    k_gemm<64,128,1,0><<<dim3(M_ / 64, 3), 256, 0, stream>>>(ybuf, owt, xbuf, D_, DI_, nullptr, nullptr);
  }

  k_feat_part<<<dim3(B_, 7), 384, 0, stream>>>(xbuf, partial);
  k_head<<<dim3((NC_ + 255) / 256, B_), 256, 0, stream>>>(partial, norm_g, norm_b, head_w, head_b, out);
}

// Round 9
// 1686.648 us; speedup vs baseline: 1.1804x; 1.1093x over previous
//
#include <hip/hip_runtime.h>
#include <math.h>

typedef short bf16x8 __attribute__((ext_vector_type(8)));
typedef float f32x4 __attribute__((ext_vector_type(4)));
typedef float f32x2 __attribute__((ext_vector_type(2)));
typedef unsigned short u16;
typedef unsigned int u32;
typedef unsigned short u16x4 __attribute__((ext_vector_type(4)));

#define B_    32
#define D_    384
#define DEPTH 12
#define NST   16
#define DI_   768
#define R_    24
#define L_    196
#define NC_   1000
#define M_    (B_*L_)   // 6272
#define SEG   28
#define NSEG  7

__device__ __forceinline__ u16 f2bf(float f) {
  union { float f; unsigned u; } v; v.f = f;
  unsigned r = v.u + 0x7fffu + ((v.u >> 16) & 1u);
  return (u16)(r >> 16);
}
__device__ __forceinline__ float bf2f(u16 x) {
  union { unsigned u; float f; } v; v.u = ((unsigned)x) << 16;
  return v.f;
}
__device__ __forceinline__ float quad_sum(float y) {
  y += __int_as_float(__builtin_amdgcn_update_dpp(0, __float_as_int(y), 0xB1, 0xf, 0xf, true));
  y += __int_as_float(__builtin_amdgcn_update_dpp(0, __float_as_int(y), 0x4E, 0xf, 0xf, true));
  return y;
}

// ---------------- weight prep ----------------
__global__ void k_transpose_bf16(const float* __restrict__ in, u16* __restrict__ out,
                                 int R, int C) {
  __shared__ float tile[32][33];
  const size_t zoff = (size_t)blockIdx.z * R * C;
  in  += zoff; out += zoff;
  int c0 = blockIdx.x * 32, r0 = blockIdx.y * 32;
  int tx = threadIdx.x, ty = threadIdx.y;
  for (int i = ty; i < 32; i += 8) {
    int r = r0 + i, c = c0 + tx;
    tile[i][tx] = (r < R && c < C) ? in[(size_t)r * C + c] : 0.f;
  }
  __syncthreads();
  for (int i = ty; i < 32; i += 8) {
    int c = c0 + i, r = r0 + tx;
    if (c < C && r < R) out[(size_t)c * R + r] = f2bf(tile[tx][i]);
  }
}

__global__ void k_convert_bf16(const float* __restrict__ in, u16* __restrict__ out, int n) {
  int i = blockIdx.x * 256 + threadIdx.x;
  if (i < n) out[i] = f2bf(in[i]);
}

__global__ void k_prepA(const float* __restrict__ alog, float* __restrict__ A, int n) {
  int i = blockIdx.x * 256 + threadIdx.x;
  if (i < n) A[i] = -__expf(alog[i]);
}

// dtp_w (DEPTH,24,768) -> dtwT (DEPTH,768,32) bf16, K-padded with zeros
__global__ void k_prep_dtw(const float* __restrict__ in, u16* __restrict__ out) {
  int idx = blockIdx.x * 256 + threadIdx.x;
  if (idx >= DEPTH * DI_ * 32) return;
  int r = idx & 31, c = (idx >> 5) % DI_, dp = idx / (DI_ * 32);
  out[idx] = (r < R_) ? f2bf(in[((size_t)dp * R_ + r) * DI_ + c]) : (u16)0;
}

// ---------------- im2col ----------------
__global__ void k_im2col(const float* __restrict__ x, u16* __restrict__ xcol) {
  int idx = blockIdx.x * 256 + threadIdx.x;
  if (idx >= M_ * 768) return;
  int k = idx % 768, m = idx / 768;
  int b = m / L_, l = m % L_;
  int li = l / 14, lj = l % 14;
  int c = k / 256, r = k % 256;
  int i = r / 16, j = r % 16;
  int hh = li * 16 + i, ww = lj * 16 + j;
  xcol[idx] = f2bf(x[(((size_t)b * 3 + c) * 224 + hh) * 224 + ww]);
}

// ---------------- GEMM (software-pipelined) ----------------
template<int BM, int BN, int EPI, int OB>
__global__ __launch_bounds__(256)
void k_gemm(const u16* __restrict__ A, const u16* __restrict__ BT,
            float* __restrict__ Cout, int Nn, int Kk,
            const float* __restrict__ bias, const float* __restrict__ pos) {
  const int m0 = blockIdx.x * BM;
  const int n0 = blockIdx.y * BN;
  __shared__ u16 lA[BM * 72];
  __shared__ u16 lB[BN * 72];
  const int tid  = threadIdx.x;
  const int wave = tid >> 6, lane = tid & 63;
  const int wm = (wave >> 1) * (BM / 2), wn = (wave & 1) * (BN / 2);
  constexpr int MI = BM / 32, NJ = BN / 32;
  constexpr int NV = (BM + BN) / 32;
  f32x4 acc[MI][NJ] = {};
  const int fr = lane & 15, kg = (lane >> 4) * 8;

  bf16x8 v[NV];
  auto load = [&](int k0) {
    #pragma unroll
    for (int q = 0; q < NV; ++q) {
      int id = tid + q * 256;
      int row = id >> 3, vv = id & 7;
      bf16x8 t = {};
      if (row < BM) {
        t = *(const bf16x8*)(A + (size_t)(m0 + row) * Kk + k0 + vv * 8);
      } else {
        int br = n0 + row - BM;
        if (br < Nn) t = *(const bf16x8*)(BT + (size_t)br * Kk + k0 + vv * 8);
      }
      v[q] = t;
    }
  };
  load(0);
  for (int k0 = 0; k0 < Kk; k0 += 64) {
    __syncthreads();
    #pragma unroll
    for (int q = 0; q < NV; ++q) {
      int id = tid + q * 256;
      int row = id >> 3, vv = id & 7;
      u16* dst = (row < BM) ? (lA + row * 72 + vv * 8) : (lB + (size_t)(row - BM) * 72 + vv * 8);
      *(bf16x8*)dst = v[q];
    }
    __syncthreads();
    if (k0 + 64 < Kk) load(k0 + 64);     // overlaps MFMA below
    #pragma unroll
    for (int kk = 0; kk < 64; kk += 32) {
      bf16x8 af[MI], bfr[NJ];
      #pragma unroll
      for (int i = 0; i < MI; ++i)
        af[i] = *(const bf16x8*)(lA + (wm + i * 16 + fr) * 72 + kk + kg);
      #pragma unroll
      for (int j = 0; j < NJ; ++j)
        bfr[j] = *(const bf16x8*)(lB + (wn + j * 16 + fr) * 72 + kk + kg);
      #pragma unroll
      for (int i = 0; i < MI; ++i)
        #pragma unroll
        for (int j = 0; j < NJ; ++j)
          acc[i][j] = __builtin_amdgcn_mfma_f32_16x16x32_bf16(af[i], bfr[j], acc[i][j], 0, 0, 0);
    }
  }

  const int rg = (lane >> 4) * 4;
  #pragma unroll
  for (int i = 0; i < MI; ++i) {
    int row = m0 + wm + i * 16 + rg;
    #pragma unroll
    for (int j = 0; j < NJ; ++j) {
      int col = n0 + wn + j * 16 + fr;
      if (col >= Nn) continue;
      #pragma unroll
      for (int r = 0; r < 4; ++r) {
        float vv = acc[i][j][r];
        size_t idx = (size_t)(row + r) * Nn + col;
        if (EPI == 0) {
          if (OB) ((u16*)Cout)[idx] = f2bf(vv);
          else    Cout[idx] = vv;
        }
        else if (EPI == 1) Cout[idx] += vv;
        else               Cout[idx] = vv + bias[col] + pos[(size_t)((row + r) % L_) * Nn + col];
      }
    }
  }
}

// ---------------- LayerNorm ----------------
__global__ __launch_bounds__(384)
void k_ln(const float* __restrict__ x, const float* __restrict__ g,
          const float* __restrict__ bt, u16* __restrict__ h) {
  const int m = blockIdx.x, d = threadIdx.x;
  __shared__ float red[12];
  float v = x[(size_t)m * D_ + d];
  float s = v, s2 = v * v;
  #pragma unroll
  for (int o = 32; o > 0; o >>= 1) { s += __shfl_xor(s, o); s2 += __shfl_xor(s2, o); }
  int wid = d >> 6;
  if ((d & 63) == 0) { red[wid] = s; red[6 + wid] = s2; }
  __syncthreads();
  float ts = 0.f, ts2 = 0.f;
  #pragma unroll
  for (int w = 0; w < 6; ++w) { ts += red[w]; ts2 += red[6 + w]; }
  float mu = ts / (float)D_;
  float var = ts2 / (float)D_ - mu * mu;
  float rs = rsqrtf(var + 1e-5f);
  h[(size_t)m * D_ + d] = f2bf((v - mu) * rs * g[d] + bt[d]);
}

// ---------------- conv + SiLU ----------------
__global__ __launch_bounds__(256)
void k_conv(const u16* __restrict__ xzb, const float* __restrict__ cw,
            const float* __restrict__ cb, u16* __restrict__ xcb) {
  int idx = blockIdx.x * 256 + threadIdx.x;
  if (idx >= M_ * (DI_ / 4)) return;
  int dq = idx % (DI_ / 4), m = idx / (DI_ / 4), l = m % L_;
  int di4 = dq * 4;
  const u16* base = xzb + (size_t)m * 1536 + di4;
  float xv[4][4];
  #pragma unroll
  for (int t = 0; t < 4; ++t) {
    int back = 3 - t;
    u16x4 v = {};
    if (l >= back) v = *(const u16x4*)(base - (size_t)back * 1536);
    #pragma unroll
    for (int c = 0; c < 4; ++c) xv[t][c] = bf2f(v[c]);
  }
  f32x4 bv = *(const f32x4*)(cb + di4);
  u16x4 outv;
  #pragma unroll
  for (int c = 0; c < 4; ++c) {
    f32x4 w = *(const f32x4*)(cw + (size_t)(di4 + c) * 4);
    float acc = bv[c] + w[0] * xv[0][c] + w[1] * xv[1][c] + w[2] * xv[2][c] + w[3] * xv[3][c];
    float s = acc / (1.f + __expf(-acc));
    outv[c] = f2bf(s);
  }
  *(u16x4*)(xcb + (size_t)m * DI_ + di4) = outv;
}

// ---------------- fused xp-GEMM + dt ----------------
// grid M_/32 blocks. Stage1: dbc(32x56) = xc(32x768) @ xp_wT^T.
//   cols 24..55 -> bcbuf[M][32] (f32); cols 0..23 -> LDS bf16 (K-pad 32).
// Stage2: dt(32x768) = softplus(dbcA(32x32) @ dtwT(768x32)^T + dtp_b)
__global__ __launch_bounds__(256)
void k_xp_dt(const u16* __restrict__ A, const u16* __restrict__ BT,
             const u16* __restrict__ dtwT, const float* __restrict__ dtb,
             float* __restrict__ bcbuf, float* __restrict__ dt) {
  const int m0 = blockIdx.x * 32;
  __shared__ u16 lA[32 * 72];
  __shared__ u16 lB[64 * 72];
  __shared__ u16 sA2[32 * 40];
  const int tid  = threadIdx.x;
  const int wave = tid >> 6, lane = tid & 63;
  const int wm = (wave >> 1) * 16, wn = (wave & 1) * 32;
  const int fr = lane & 15, kg = (lane >> 4) * 8;
  const int rg = (lane >> 4) * 4;
  f32x4 acc[1][2] = {};

  // zero K-pad cols 24..31 of sA2
  sA2[(tid >> 3) * 40 + 24 + (tid & 7)] = 0;

  bf16x8 v[3];
  auto load = [&](int k0) {
    #pragma unroll
    for (int q = 0; q < 3; ++q) {
      int id = tid + q * 256;
      int row = id >> 3, vv = id & 7;
      bf16x8 t = {};
      if (row < 32) {
        t = *(const bf16x8*)(A + (size_t)(m0 + row) * DI_ + k0 + vv * 8);
      } else {
        int br = row - 32;
        if (br < 56) t = *(const bf16x8*)(BT + (size_t)br * DI_ + k0 + vv * 8);
      }
      v[q] = t;
    }
  };
  load(0);
  for (int k0 = 0; k0 < DI_; k0 += 64) {
    __syncthreads();
    #pragma unroll
    for (int q = 0; q < 3; ++q) {
      int id = tid + q * 256;
      int row = id >> 3, vv = id & 7;
      u16* dst = (row < 32) ? (lA + row * 72 + vv * 8) : (lB + (size_t)(row - 32) * 72 + vv * 8);
      *(bf16x8*)dst = v[q];
    }
    __syncthreads();
    if (k0 + 64 < DI_) load(k0 + 64);
    #pragma unroll
    for (int kk = 0; kk < 64; kk += 32) {
      bf16x8 af = *(const bf16x8*)(lA + (wm + fr) * 72 + kk + kg);
      bf16x8 b0 = *(const bf16x8*)(lB + (wn + fr) * 72 + kk + kg);
      bf16x8 b1 = *(const bf16x8*)(lB + (wn + 16 + fr) * 72 + kk + kg);
      acc[0][0] = __builtin_amdgcn_mfma_f32_16x16x32_bf16(af, b0, acc[0][0], 0, 0, 0);
      acc[0][1] = __builtin_amdgcn_mfma_f32_16x16x32_bf16(af, b1, acc[0][1], 0, 0, 0);
    }
  }
  // stage-1 epilogue: scatter to sA2 (cols<24) and bcbuf (24..55)
  #pragma unroll
  for (int j = 0; j < 2; ++j) {
    int col = wn + j * 16 + fr;
    #pragma unroll
    for (int r = 0; r < 4; ++r) {
      int row = wm + rg + r;
      float vv = acc[0][j][r];
      if (col < 24)       sA2[row * 40 + col] = f2bf(vv);
      else if (col < 56)  bcbuf[(size_t)(m0 + row) * 32 + (col - 24)] = vv;
    }
  }
  __syncthreads();

  // stage 2: per wave 192 cols x 32 rows
  const int wn2 = wave * 192;
  f32x4 acc2[2][12] = {};
  bf16x8 a2[2];
  #pragma unroll
  for (int i = 0; i < 2; ++i)
    a2[i] = *(const bf16x8*)(sA2 + (i * 16 + fr) * 40 + kg);
  #pragma unroll
  for (int j = 0; j < 12; ++j) {
    bf16x8 b2 = *(const bf16x8*)(dtwT + (size_t)(wn2 + j * 16 + fr) * 32 + kg);
    #pragma unroll
    for (int i = 0; i < 2; ++i)
      acc2[i][j] = __builtin_amdgcn_mfma_f32_16x16x32_bf16(a2[i], b2, acc2[i][j], 0, 0, 0);
  }
  #pragma unroll
  for (int j = 0; j < 12; ++j) {
    int col = wn2 + j * 16 + fr;
    float bvv = dtb[col];
    #pragma unroll
    for (int i = 0; i < 2; ++i) {
      #pragma unroll
      for (int r = 0; r < 4; ++r) {
        int row = i * 16 + rg + r;
        float pre = acc2[i][j][r] + bvv;
        float e  = __expf(-fabsf(pre));
        float sp = fmaxf(pre, 0.f) + __logf(1.f + e);
        dt[(size_t)(m0 + row) * DI_ + col] = sp;
      }
    }
  }
}

// ---------------- pass A: local segment scan ----------------
__global__ __launch_bounds__(256)
void k_scan_part(const float* __restrict__ bcbuf, const float* __restrict__ dt,
                 const u16* __restrict__ xcb, const float* __restrict__ Abuf,
                 const float* __restrict__ Dsk, float* __restrict__ ys,
                 float* __restrict__ hend, float* __restrict__ send) {
  const int b   = blockIdx.x;
  const int di0 = blockIdx.y * 64;
  const int s   = blockIdx.z;
  const int tid = threadIdx.x;
  const int dil = tid >> 2, nq = tid & 3;
  const int di  = di0 + dil;
  __shared__ float sDX[SEG][128];
  __shared__ float sYS[SEG][128];

  const f32x4 Arow = *(const f32x4*)(Abuf + (size_t)di * NST + nq * 4);
  const float Dv = Dsk[di];
  const size_t mb = (size_t)b * L_ + (size_t)s * SEG;

  {
    int r = tid >> 4, cc = (tid & 15) * 4;
    #pragma unroll
    for (int j = 0; j < 2; ++j) {
      int row = r + j * 16;
      if (row < SEG) {
        f32x4 dtv = *(const f32x4*)(dt + (mb + row) * DI_ + di0 + cc);
        u16x4 xv  = *(const u16x4*)(xcb + (mb + row) * DI_ + di0 + cc);
        f32x4 w0 = {dtv[0], bf2f(xv[0]), dtv[1], bf2f(xv[1])};
        f32x4 w1 = {dtv[2], bf2f(xv[2]), dtv[3], bf2f(xv[3])};
        *(f32x4*)&sDX[row][cc * 2]     = w0;
        *(f32x4*)&sDX[row][cc * 2 + 4] = w1;
      }
    }
  }
  __syncthreads();

  const float* bc = bcbuf + mb * 32;
  float h[4] = {0.f, 0.f, 0.f, 0.f};
  float scum = 0.f;
  f32x2 dx = *(const f32x2*)&sDX[0][2 * dil];
  f32x4 Bv = *(const f32x4*)(bc + nq * 4);
  f32x4 Cv = *(const f32x4*)(bc + 16 + nq * 4);
  #pragma unroll 4
  for (int t = 0; t < SEG; ++t) {
    f32x2 dxn = {}; f32x4 Bn = {}, Cn = {};
    if (t + 1 < SEG) {
      dxn = *(const f32x2*)&sDX[t + 1][2 * dil];
      Bn = *(const f32x4*)(bc + (t + 1) * 32 + nq * 4);
      Cn = *(const f32x4*)(bc + (t + 1) * 32 + 16 + nq * 4);
    }
    float dtc = dx.x, xcc = dx.y;
    scum += dtc;
    float dxv = dtc * xcc;
    float y = (nq == 0) ? Dv * xcc : 0.f;
    #pragma unroll
    for (int n = 0; n < 4; ++n) {
      float e = __expf(dtc * Arow[n]);
      h[n] = e * h[n] + dxv * Bv[n];
      y += h[n] * Cv[n];
    }
    y = quad_sum(y);
    if (nq == 0) *(f32x2*)&sYS[t][2 * dil] = f32x2{y, scum};
    dx = dxn; Bv = Bn; Cv = Cn;
  }

  size_t sb = ((size_t)s * B_ + b) * DI_ + di;
  *(f32x4*)(hend + sb * 16 + nq * 4) = f32x4{h[0], h[1], h[2], h[3]};
  if (nq == 0) send[sb] = scum;
  __syncthreads();
  #pragma unroll
  for (int j = 0; j < 4; ++j) {
    int id = tid + j * 256;
    if (id < SEG * 32) {
      int row = id >> 5, c4 = (id & 31) * 4;
      *(f32x4*)(ys + (mb + row) * (DI_ * 2) + di0 * 2 + c4) = *(const f32x4*)&sYS[row][c4];
    }
  }
}

// ---------------- pass B: carry combine + correction + gate (fused) ----------------
__global__ __launch_bounds__(256)
void k_scan_apply(const float* __restrict__ bcbuf, const float* __restrict__ ys,
                  const u16* __restrict__ xzb, const float* __restrict__ Abuf,
                  const float* __restrict__ hend, const float* __restrict__ send,
                  u16* __restrict__ yb) {
  const int b   = blockIdx.x;
  const int di0 = blockIdx.y * 64;
  const int s   = blockIdx.z;
  const int tid = threadIdx.x;
  const size_t mb = (size_t)b * L_ + (size_t)s * SEG;
  __shared__ float sC[SEG][16];
  __shared__ float sYO[SEG][64];

  if (s > 0) {
    const int dil = tid >> 2, nq = tid & 3;
    const f32x4 A4 = *(const f32x4*)(Abuf + (size_t)(di0 + dil) * NST + nq * 4);
    // combine carry-in over previous segments
    f32x4 H4 = {0.f, 0.f, 0.f, 0.f};
    for (int r = 0; r < s; ++r) {
      size_t sb = ((size_t)r * B_ + b) * DI_ + di0 + dil;
      f32x4 he = *(const f32x4*)(hend + sb * 16 + nq * 4);
      float se = send[sb];
      #pragma unroll
      for (int q = 0; q < 4; ++q) H4[q] = __expf(A4[q] * se) * H4[q] + he[q];
    }
    if (tid < SEG * 4) {
      int row = tid >> 2, qq = tid & 3;
      *(f32x4*)&sC[row][qq * 4] = *(const f32x4*)(bcbuf + (mb + row) * 32 + 16 + qq * 4);
    }
    __syncthreads();
    #pragma unroll 4
    for (int l = 0; l < SEG; ++l) {
      f32x2 yp = *(const f32x2*)(ys + (mb + l) * (DI_ * 2) + (size_t)(di0 + dil) * 2);
      f32x4 C4 = *(const f32x4*)&sC[l][nq * 4];
      float scum = yp.y;
      float corr = 0.f;
      #pragma unroll
      for (int n = 0; n < 4; ++n) corr += C4[n] * __expf(A4[n] * scum) * H4[n];
      corr = quad_sum(corr);
      if (nq == 0) sYO[l][dil] = yp.x + corr;
    }
  } else {
    #pragma unroll
    for (int j = 0; j < 7; ++j) {
      int id = tid + j * 256;
      int row = id >> 6, ch = id & 63;
      sYO[row][ch] = ys[(mb + row) * (DI_ * 2) + (size_t)(di0 + ch) * 2];
    }
  }
  __syncthreads();
  #pragma unroll
  for (int j = 0; j < 4; ++j) {
    int id = tid + j * 256;
    if (id < SEG * 32) {
      int row = id >> 5, c2 = id & 31;
      int ch0 = c2 * 2;
      float y0 = sYO[row][ch0], y1 = sYO[row][ch0 + 1];
      u32 zz = *(const u32*)(xzb + (mb + row) * 1536 + DI_ + di0 + ch0);
      float z0 = bf2f((u16)(zz & 0xffff)), z1 = bf2f((u16)(zz >> 16));
      u32 o = (u32)f2bf(y0 * z0 / (1.f + __expf(-z0)))
            | ((u32)f2bf(y1 * z1 / (1.f + __expf(-z1))) << 16);
      *((u32*)yb + ((mb + row) * DI_ + di0) / 2 + c2) = o;
    }
  }
}

// ---------------- final LN partial sums ----------------
__global__ __launch_bounds__(384)
void k_feat_part(const float* __restrict__ x, float* __restrict__ partial) {
  const int b = blockIdx.x, j = blockIdx.y, d = threadIdx.x;
  __shared__ float red[12];
  const int l0 = j * 28;
  float acc = 0.f;
  float v = x[((size_t)b * L_ + l0) * D_ + d];
  for (int l = l0; l < l0 + 28; ++l) {
    float vn = (l + 1 < l0 + 28) ? x[((size_t)b * L_ + l + 1) * D_ + d] : 0.f;
    float s = v, s2 = v * v;
    #pragma unroll
    for (int o = 32; o > 0; o >>= 1) { s += __shfl_xor(s, o); s2 += __shfl_xor(s2, o); }
    int wid = d >> 6;
    if ((d & 63) == 0) { red[wid] = s; red[6 + wid] = s2; }
    __syncthreads();
    float ts = 0.f, ts2 = 0.f;
    #pragma unroll
    for (int w = 0; w < 6; ++w) { ts += red[w]; ts2 += red[6 + w]; }
    float mu = ts * (1.f / (float)D_);
    float var = ts2 * (1.f / (float)D_) - mu * mu;
    acc += (v - mu) * rsqrtf(var + 1e-5f);
    __syncthreads();
    v = vn;
  }
  partial[((size_t)(b * 7 + j)) * D_ + d] = acc;
}

// ---------------- head ----------------
__global__ __launch_bounds__(256)
void k_head(const float* __restrict__ partial, const float* __restrict__ g,
            const float* __restrict__ bt, const float* __restrict__ hw,
            const float* __restrict__ hb, float* __restrict__ out) {
  const int b = blockIdx.y;
  const int c = blockIdx.x * 256 + threadIdx.x;
  __shared__ float sf[D_];
  for (int i = threadIdx.x; i < D_; i += 256) {
    float s = 0.f;
    #pragma unroll
    for (int j = 0; j < 7; ++j) s += partial[((size_t)(b * 7 + j)) * D_ + i];
    sf[i] = g[i] * (s * (1.f / (float)L_)) + bt[i];
  }
  __syncthreads();
  if (c >= NC_) return;
  float acc = hb[c];
  for (int d = 0; d < D_; ++d) acc += sf[d] * hw[(size_t)d * NC_ + c];
  out[(size_t)b * NC_ + c] = acc;
}

// =====================================================================
extern "C" void kernel_launch(void* const* d_in, const int* in_sizes, int n_in,
                              void* d_out, int out_size, void* d_ws, size_t ws_size,
                              hipStream_t stream) {
  const float* x_in    = (const float*)d_in[0];
  const float* patch_w = (const float*)d_in[1];
  const float* patch_b = (const float*)d_in[2];
  const float* pos     = (const float*)d_in[3];
  const float* bn_g    = (const float*)d_in[4];
  const float* bn_b    = (const float*)d_in[5];
  const float* in_w    = (const float*)d_in[6];
  const float* conv_w  = (const float*)d_in[7];
  const float* conv_b  = (const float*)d_in[8];
  const float* xp_w    = (const float*)d_in[9];
  const float* dtp_w   = (const float*)d_in[10];
  const float* dtp_b   = (const float*)d_in[11];
  const float* A_log   = (const float*)d_in[12];
  const float* D_skip  = (const float*)d_in[13];
  const float* out_w   = (const float*)d_in[14];
  const float* norm_g  = (const float*)d_in[15];
  const float* norm_b  = (const float*)d_in[16];
  const float* head_w  = (const float*)d_in[17];
  const float* head_b  = (const float*)d_in[18];
  float* out = (float*)d_out;

  char* ws = (char*)d_ws;
  size_t off = 0;
  auto alloc = [&](size_t bytes) { size_t o = off; off += (bytes + 255) & ~(size_t)255; return o; };

  float* xbuf   = (float*)(ws + alloc((size_t)M_ * D_ * 4));
  u16*   hbuf   = (u16*)  (ws + alloc((size_t)M_ * D_ * 2));
  u16*   xzb    = (u16*)  (ws + alloc((size_t)M_ * 1536 * 2));
  u16*   xcbb   = (u16*)  (ws + alloc((size_t)M_ * DI_ * 2));
  float* bcbuf  = (float*)(ws + alloc((size_t)M_ * 32 * 4));
  float* dtbuf  = (float*)(ws + alloc((size_t)M_ * DI_ * 4));   // aliased as im2col before loop
  u16*   ybuf   = (u16*)  (ws + alloc((size_t)M_ * DI_ * 2));
  float* ysbuf  = (float*)(ws + alloc((size_t)M_ * DI_ * 2 * 4));
  float* hend   = (float*)(ws + alloc((size_t)NSEG * B_ * DI_ * NST * 4));
  float* send   = (float*)(ws + alloc((size_t)NSEG * B_ * DI_ * 4));
  float* Abuf   = (float*)(ws + alloc((size_t)DEPTH * DI_ * NST * 4));
  float* partial= (float*)(ws + alloc((size_t)B_ * 7 * D_ * 4));
  u16*   in_wT  = (u16*)  (ws + alloc((size_t)DEPTH * 1536 * D_ * 2));
  u16*   xp_wT  = (u16*)  (ws + alloc((size_t)DEPTH * 56 * DI_ * 2));
  u16*   out_wT = (u16*)  (ws + alloc((size_t)DEPTH * D_ * DI_ * 2));
  u16*   dtwT   = (u16*)  (ws + alloc((size_t)DEPTH * DI_ * 32 * 2));
  u16*   pw_b   = (u16*)  (ws + alloc((size_t)D_ * 768 * 2));
  u16*   im2col = (u16*)dtbuf;

  dim3 tb(32, 8);
  k_transpose_bf16<<<dim3(48, 12, DEPTH), tb, 0, stream>>>(in_w,  in_wT,  D_, 1536);
  k_transpose_bf16<<<dim3(2, 24, DEPTH),  tb, 0, stream>>>(xp_w,  xp_wT,  DI_, 56);
  k_transpose_bf16<<<dim3(12, 24, DEPTH), tb, 0, stream>>>(out_w, out_wT, DI_, D_);
  k_convert_bf16<<<(D_ * 768 + 255) / 256, 256, 0, stream>>>(patch_w, pw_b, D_ * 768);
  k_prepA<<<(DEPTH * DI_ * NST + 255) / 256, 256, 0, stream>>>(A_log, Abuf, DEPTH * DI_ * NST);
  k_prep_dtw<<<(DEPTH * DI_ * 32 + 255) / 256, 256, 0, stream>>>(dtp_w, dtwT);

  k_im2col<<<(M_ * 768 + 255) / 256, 256, 0, stream>>>(x_in, im2col);
  k_gemm<64,128,2,0><<<dim3(M_ / 64, 3), 256, 0, stream>>>(im2col, pw_b, xbuf, D_, 768, patch_b, pos);

  for (int dp = 0; dp < DEPTH; ++dp) {
    const u16* iwt = in_wT  + (size_t)dp * 1536 * D_;
    const u16* xwt = xp_wT  + (size_t)dp * 56 * DI_;
    const u16* owt = out_wT + (size_t)dp * D_ * DI_;
    const u16* dwt = dtwT   + (size_t)dp * DI_ * 32;
    const float* Al = Abuf + (size_t)dp * DI_ * NST;
    k_ln<<<M_, 384, 0, stream>>>(xbuf, bn_g + dp * D_, bn_b + dp * D_, hbuf);
    k_gemm<64,128,0,1><<<dim3(M_ / 64, 12), 256, 0, stream>>>(hbuf, iwt, (float*)xzb, 1536, D_, nullptr, nullptr);
    k_conv<<<(M_ * (DI_ / 4) + 255) / 256, 256, 0, stream>>>(xzb, conv_w + (size_t)dp * DI_ * 4,
                                                             conv_b + dp * DI_, xcbb);
    k_xp_dt<<<M_ / 32, 256, 0, stream>>>(xcbb, xwt, dwt, dtp_b + dp * DI_, bcbuf, dtbuf);
    k_scan_part<<<dim3(B_, DI_ / 64, NSEG), 256, 0, stream>>>(bcbuf, dtbuf, xcbb, Al,
                                                              D_skip + dp * DI_, ysbuf, hend, send);
    k_scan_apply<<<dim3(B_, DI_ / 64, NSEG), 256, 0, stream>>>(bcbuf, ysbuf, xzb, Al,
                                                               hend, send, ybuf);
    k_gemm<64,128,1,0><<<dim3(M_ / 64, 3), 256, 0, stream>>>(ybuf, owt, xbuf, D_, DI_, nullptr, nullptr);
  }

  k_feat_part<<<dim3(B_, 7), 384, 0, stream>>>(xbuf, partial);
  k_head<<<dim3((NC_ + 255) / 256, B_), 256, 0, stream>>>(partial, norm_g, norm_b, head_w, head_b, out);
}

// Round 10
// 1661.989 us; speedup vs baseline: 1.1979x; 1.0148x over previous
//
#include <hip/hip_runtime.h>
#include <math.h>

typedef short bf16x8 __attribute__((ext_vector_type(8)));
typedef float f32x4 __attribute__((ext_vector_type(4)));
typedef float f32x2 __attribute__((ext_vector_type(2)));
typedef unsigned short u16;
typedef unsigned int u32;
typedef unsigned short u16x4 __attribute__((ext_vector_type(4)));

#define B_    32
#define D_    384
#define DEPTH 12
#define NST   16
#define DI_   768
#define R_    24
#define L_    196
#define NC_   1000
#define M_    (B_*L_)   // 6272
#define SEG   28
#define NSEG  7

__device__ __forceinline__ u16 f2bf(float f) {
  union { float f; unsigned u; } v; v.f = f;
  unsigned r = v.u + 0x7fffu + ((v.u >> 16) & 1u);
  return (u16)(r >> 16);
}
__device__ __forceinline__ float bf2f(u16 x) {
  union { unsigned u; float f; } v; v.u = ((unsigned)x) << 16;
  return v.f;
}
__device__ __forceinline__ float quad_sum(float y) {
  y += __int_as_float(__builtin_amdgcn_update_dpp(0, __float_as_int(y), 0xB1, 0xf, 0xf, true));
  y += __int_as_float(__builtin_amdgcn_update_dpp(0, __float_as_int(y), 0x4E, 0xf, 0xf, true));
  return y;
}

// ---------------- weight prep ----------------
__global__ void k_transpose_bf16(const float* __restrict__ in, u16* __restrict__ out,
                                 int R, int C) {
  __shared__ float tile[32][33];
  const size_t zoff = (size_t)blockIdx.z * R * C;
  in  += zoff; out += zoff;
  int c0 = blockIdx.x * 32, r0 = blockIdx.y * 32;
  int tx = threadIdx.x, ty = threadIdx.y;
  for (int i = ty; i < 32; i += 8) {
    int r = r0 + i, c = c0 + tx;
    tile[i][tx] = (r < R && c < C) ? in[(size_t)r * C + c] : 0.f;
  }
  __syncthreads();
  for (int i = ty; i < 32; i += 8) {
    int c = c0 + i, r = r0 + tx;
    if (c < C && r < R) out[(size_t)c * R + r] = f2bf(tile[tx][i]);
  }
}

__global__ void k_convert_bf16(const float* __restrict__ in, u16* __restrict__ out, int n) {
  int i = blockIdx.x * 256 + threadIdx.x;
  if (i < n) out[i] = f2bf(in[i]);
}

__global__ void k_prepA(const float* __restrict__ alog, float* __restrict__ A, int n) {
  int i = blockIdx.x * 256 + threadIdx.x;
  if (i < n) A[i] = -__expf(alog[i]);
}

// ---------------- im2col ----------------
__global__ void k_im2col(const float* __restrict__ x, u16* __restrict__ xcol) {
  int idx = blockIdx.x * 256 + threadIdx.x;
  if (idx >= M_ * 768) return;
  int k = idx % 768, m = idx / 768;
  int b = m / L_, l = m % L_;
  int li = l / 14, lj = l % 14;
  int c = k / 256, r = k % 256;
  int i = r / 16, j = r % 16;
  int hh = li * 16 + i, ww = lj * 16 + j;
  xcol[idx] = f2bf(x[(((size_t)b * 3 + c) * 224 + hh) * 224 + ww]);
}

// ---------------- GEMM (software-pipelined) ----------------
template<int BM, int BN, int EPI, int OB>
__global__ __launch_bounds__(256)
void k_gemm(const u16* __restrict__ A, const u16* __restrict__ BT,
            float* __restrict__ Cout, int Nn, int Kk,
            const float* __restrict__ bias, const float* __restrict__ pos) {
  const int m0 = blockIdx.x * BM;
  const int n0 = blockIdx.y * BN;
  __shared__ u16 lA[BM * 72];
  __shared__ u16 lB[BN * 72];
  const int tid  = threadIdx.x;
  const int wave = tid >> 6, lane = tid & 63;
  const int wm = (wave >> 1) * (BM / 2), wn = (wave & 1) * (BN / 2);
  constexpr int MI = BM / 32, NJ = BN / 32;
  constexpr int NV = (BM + BN) / 32;
  f32x4 acc[MI][NJ] = {};
  const int fr = lane & 15, kg = (lane >> 4) * 8;

  bf16x8 v[NV];
  auto load = [&](int k0) {
    #pragma unroll
    for (int q = 0; q < NV; ++q) {
      int id = tid + q * 256;
      int row = id >> 3, vv = id & 7;
      bf16x8 t = {};
      if (row < BM) {
        t = *(const bf16x8*)(A + (size_t)(m0 + row) * Kk + k0 + vv * 8);
      } else {
        int br = n0 + row - BM;
        if (br < Nn) t = *(const bf16x8*)(BT + (size_t)br * Kk + k0 + vv * 8);
      }
      v[q] = t;
    }
  };
  load(0);
  for (int k0 = 0; k0 < Kk; k0 += 64) {
    __syncthreads();
    #pragma unroll
    for (int q = 0; q < NV; ++q) {
      int id = tid + q * 256;
      int row = id >> 3, vv = id & 7;
      u16* dst = (row < BM) ? (lA + row * 72 + vv * 8) : (lB + (size_t)(row - BM) * 72 + vv * 8);
      *(bf16x8*)dst = v[q];
    }
    __syncthreads();
    if (k0 + 64 < Kk) load(k0 + 64);     // overlaps MFMA below
    #pragma unroll
    for (int kk = 0; kk < 64; kk += 32) {
      bf16x8 af[MI], bfr[NJ];
      #pragma unroll
      for (int i = 0; i < MI; ++i)
        af[i] = *(const bf16x8*)(lA + (wm + i * 16 + fr) * 72 + kk + kg);
      #pragma unroll
      for (int j = 0; j < NJ; ++j)
        bfr[j] = *(const bf16x8*)(lB + (wn + j * 16 + fr) * 72 + kk + kg);
      #pragma unroll
      for (int i = 0; i < MI; ++i)
        #pragma unroll
        for (int j = 0; j < NJ; ++j)
          acc[i][j] = __builtin_amdgcn_mfma_f32_16x16x32_bf16(af[i], bfr[j], acc[i][j], 0, 0, 0);
    }
  }

  const int rg = (lane >> 4) * 4;
  #pragma unroll
  for (int i = 0; i < MI; ++i) {
    int row = m0 + wm + i * 16 + rg;
    #pragma unroll
    for (int j = 0; j < NJ; ++j) {
      int col = n0 + wn + j * 16 + fr;
      if (col >= Nn) continue;
      #pragma unroll
      for (int r = 0; r < 4; ++r) {
        float vv = acc[i][j][r];
        size_t idx = (size_t)(row + r) * Nn + col;
        if (EPI == 0) {
          if (OB) ((u16*)Cout)[idx] = f2bf(vv);
          else    Cout[idx] = vv;
        }
        else if (EPI == 1) Cout[idx] += vv;
        else               Cout[idx] = vv + bias[col] + pos[(size_t)((row + r) % L_) * Nn + col];
      }
    }
  }
}

// ---------------- xp skinny GEMM, K-split x4 ----------------
// grid (M_/32, 4): block computes 32x56 partial over K slice [ks*192,(ks+1)*192)
__global__ __launch_bounds__(256)
void k_xp_split(const u16* __restrict__ A, const u16* __restrict__ BT,
                float* __restrict__ pbuf) {
  const int m0 = blockIdx.x * 32;
  const int ks = blockIdx.y;
  __shared__ u16 lA[32 * 72];
  __shared__ u16 lB[64 * 72];
  const int tid  = threadIdx.x;
  const int wave = tid >> 6, lane = tid & 63;
  const int wm = (wave >> 1) * 16, wn = (wave & 1) * 32;
  const int fr = lane & 15, kg = (lane >> 4) * 8;
  f32x4 acc[2] = {};

  bf16x8 v[3];
  auto load = [&](int k0) {
    #pragma unroll
    for (int q = 0; q < 3; ++q) {
      int id = tid + q * 256;
      int row = id >> 3, vv = id & 7;
      bf16x8 t = {};
      if (row < 32) {
        t = *(const bf16x8*)(A + (size_t)(m0 + row) * DI_ + k0 + vv * 8);
      } else {
        int br = row - 32;
        if (br < 56) t = *(const bf16x8*)(BT + (size_t)br * DI_ + k0 + vv * 8);
      }
      v[q] = t;
    }
  };
  const int kbase = ks * 192;
  load(kbase);
  for (int k0 = kbase; k0 < kbase + 192; k0 += 64) {
    __syncthreads();
    #pragma unroll
    for (int q = 0; q < 3; ++q) {
      int id = tid + q * 256;
      int row = id >> 3, vv = id & 7;
      u16* dst = (row < 32) ? (lA + row * 72 + vv * 8) : (lB + (size_t)(row - 32) * 72 + vv * 8);
      *(bf16x8*)dst = v[q];
    }
    __syncthreads();
    if (k0 + 64 < kbase + 192) load(k0 + 64);
    #pragma unroll
    for (int kk = 0; kk < 64; kk += 32) {
      bf16x8 af = *(const bf16x8*)(lA + (wm + fr) * 72 + kk + kg);
      bf16x8 b0 = *(const bf16x8*)(lB + (wn + fr) * 72 + kk + kg);
      bf16x8 b1 = *(const bf16x8*)(lB + (wn + 16 + fr) * 72 + kk + kg);
      acc[0] = __builtin_amdgcn_mfma_f32_16x16x32_bf16(af, b0, acc[0], 0, 0, 0);
      acc[1] = __builtin_amdgcn_mfma_f32_16x16x32_bf16(af, b1, acc[1], 0, 0, 0);
    }
  }
  const int rg = (lane >> 4) * 4;
  #pragma unroll
  for (int j = 0; j < 2; ++j) {
    int col = wn + j * 16 + fr;
    if (col >= 56) continue;
    #pragma unroll
    for (int r = 0; r < 4; ++r) {
      int row = wm + rg + r;
      pbuf[((size_t)ks * M_ + m0 + row) * 56 + col] = acc[j][r];
    }
  }
}

// sum 4 K-split partials -> dbc[M][56]
__global__ __launch_bounds__(256)
void k_xp_reduce(const float* __restrict__ pbuf, float* __restrict__ dbc) {
  int i = blockIdx.x * 256 + threadIdx.x;     // f32x4 units over M_*56/4
  const int off = M_ * 56 / 4;
  const f32x4* p = (const f32x4*)pbuf;
  f32x4 s = p[i] + p[i + off] + p[i + 2 * off] + p[i + 3 * off];
  ((f32x4*)dbc)[i] = s;
}

// ---------------- LayerNorm ----------------
__global__ __launch_bounds__(384)
void k_ln(const float* __restrict__ x, const float* __restrict__ g,
          const float* __restrict__ bt, u16* __restrict__ h) {
  const int m = blockIdx.x, d = threadIdx.x;
  __shared__ float red[12];
  float v = x[(size_t)m * D_ + d];
  float s = v, s2 = v * v;
  #pragma unroll
  for (int o = 32; o > 0; o >>= 1) { s += __shfl_xor(s, o); s2 += __shfl_xor(s2, o); }
  int wid = d >> 6;
  if ((d & 63) == 0) { red[wid] = s; red[6 + wid] = s2; }
  __syncthreads();
  float ts = 0.f, ts2 = 0.f;
  #pragma unroll
  for (int w = 0; w < 6; ++w) { ts += red[w]; ts2 += red[6 + w]; }
  float mu = ts / (float)D_;
  float var = ts2 / (float)D_ - mu * mu;
  float rs = rsqrtf(var + 1e-5f);
  h[(size_t)m * D_ + d] = f2bf((v - mu) * rs * g[d] + bt[d]);
}

// ---------------- conv + SiLU ----------------
__global__ __launch_bounds__(256)
void k_conv(const u16* __restrict__ xzb, const float* __restrict__ cw,
            const float* __restrict__ cb, u16* __restrict__ xcb) {
  int idx = blockIdx.x * 256 + threadIdx.x;
  if (idx >= M_ * (DI_ / 4)) return;
  int dq = idx % (DI_ / 4), m = idx / (DI_ / 4), l = m % L_;
  int di4 = dq * 4;
  const u16* base = xzb + (size_t)m * 1536 + di4;
  float xv[4][4];
  #pragma unroll
  for (int t = 0; t < 4; ++t) {
    int back = 3 - t;
    u16x4 v = {};
    if (l >= back) v = *(const u16x4*)(base - (size_t)back * 1536);
    #pragma unroll
    for (int c = 0; c < 4; ++c) xv[t][c] = bf2f(v[c]);
  }
  f32x4 bv = *(const f32x4*)(cb + di4);
  u16x4 outv;
  #pragma unroll
  for (int c = 0; c < 4; ++c) {
    f32x4 w = *(const f32x4*)(cw + (size_t)(di4 + c) * 4);
    float acc = bv[c] + w[0] * xv[0][c] + w[1] * xv[1][c] + w[2] * xv[2][c] + w[3] * xv[3][c];
    float s = acc / (1.f + __expf(-acc));
    outv[c] = f2bf(s);
  }
  *(u16x4*)(xcb + (size_t)m * DI_ + di4) = outv;
}

// ---------------- dt = softplus(dbc[:, :24] @ dtp_w + dtp_b) ----------------
__global__ __launch_bounds__(256)
void k_dt(const float* __restrict__ dbc, const float* __restrict__ dtw,
          const float* __restrict__ dtb, float* __restrict__ dt) {
  const int m0 = blockIdx.x * 16;
  const int di = blockIdx.y * 256 + threadIdx.x;
  __shared__ float sd[16][25];
  #pragma unroll
  for (int q = 0; q < 2; ++q) {
    int id = threadIdx.x + q * 256;
    if (id < 16 * 24) {
      int r = id / 24, c = id % 24;
      sd[r][c] = dbc[(size_t)(m0 + r) * 56 + c];
    }
  }
  __syncthreads();
  float w[24];
  #pragma unroll
  for (int r = 0; r < 24; ++r) w[r] = dtw[r * DI_ + di];
  const float bv = dtb[di];
  #pragma unroll 4
  for (int mi = 0; mi < 16; ++mi) {
    float acc = bv;
    #pragma unroll
    for (int r = 0; r < 24; ++r) acc += sd[mi][r] * w[r];
    float e  = __expf(-fabsf(acc));
    float sp = fmaxf(acc, 0.f) + __logf(1.f + e);
    dt[(size_t)(m0 + mi) * DI_ + di] = sp;
  }
}

// ---------------- pass A: local segment scan ----------------
__global__ __launch_bounds__(256)
void k_scan_part(const float* __restrict__ dbc, const float* __restrict__ dt,
                 const u16* __restrict__ xcb, const float* __restrict__ Abuf,
                 const float* __restrict__ Dsk, float* __restrict__ ys,
                 float* __restrict__ hend, float* __restrict__ send) {
  const int b   = blockIdx.x;
  const int di0 = blockIdx.y * 64;
  const int s   = blockIdx.z;
  const int tid = threadIdx.x;
  const int dil = tid >> 2, nq = tid & 3;
  const int di  = di0 + dil;
  __shared__ float sDX[SEG][128];
  __shared__ float sYS[SEG][128];

  const f32x4 Arow = *(const f32x4*)(Abuf + (size_t)di * NST + nq * 4);
  const float Dv = Dsk[di];
  const size_t mb = (size_t)b * L_ + (size_t)s * SEG;

  {
    int r = tid >> 4, cc = (tid & 15) * 4;
    #pragma unroll
    for (int j = 0; j < 2; ++j) {
      int row = r + j * 16;
      if (row < SEG) {
        f32x4 dtv = *(const f32x4*)(dt + (mb + row) * DI_ + di0 + cc);
        u16x4 xv  = *(const u16x4*)(xcb + (mb + row) * DI_ + di0 + cc);
        f32x4 w0 = {dtv[0], bf2f(xv[0]), dtv[1], bf2f(xv[1])};
        f32x4 w1 = {dtv[2], bf2f(xv[2]), dtv[3], bf2f(xv[3])};
        *(f32x4*)&sDX[row][cc * 2]     = w0;
        *(f32x4*)&sDX[row][cc * 2 + 4] = w1;
      }
    }
  }
  __syncthreads();

  const float* bc = dbc + mb * 56 + 24;
  float h[4] = {0.f, 0.f, 0.f, 0.f};
  float scum = 0.f;
  f32x2 dx = *(const f32x2*)&sDX[0][2 * dil];
  f32x4 Bv = *(const f32x4*)(bc + nq * 4);
  f32x4 Cv = *(const f32x4*)(bc + 16 + nq * 4);
  #pragma unroll 4
  for (int t = 0; t < SEG; ++t) {
    f32x2 dxn = {}; f32x4 Bn = {}, Cn = {};
    if (t + 1 < SEG) {
      dxn = *(const f32x2*)&sDX[t + 1][2 * dil];
      Bn = *(const f32x4*)(bc + (t + 1) * 56 + nq * 4);
      Cn = *(const f32x4*)(bc + (t + 1) * 56 + 16 + nq * 4);
    }
    float dtc = dx.x, xcc = dx.y;
    scum += dtc;
    float dxv = dtc * xcc;
    float y = (nq == 0) ? Dv * xcc : 0.f;
    #pragma unroll
    for (int n = 0; n < 4; ++n) {
      float e = __expf(dtc * Arow[n]);
      h[n] = e * h[n] + dxv * Bv[n];
      y += h[n] * Cv[n];
    }
    y = quad_sum(y);
    if (nq == 0) *(f32x2*)&sYS[t][2 * dil] = f32x2{y, scum};
    dx = dxn; Bv = Bn; Cv = Cn;
  }

  size_t sb = ((size_t)s * B_ + b) * DI_ + di;
  *(f32x4*)(hend + sb * 16 + nq * 4) = f32x4{h[0], h[1], h[2], h[3]};
  if (nq == 0) send[sb] = scum;
  __syncthreads();
  #pragma unroll
  for (int j = 0; j < 4; ++j) {
    int id = tid + j * 256;
    if (id < SEG * 32) {
      int row = id >> 5, c4 = (id & 31) * 4;
      *(f32x4*)(ys + (mb + row) * (DI_ * 2) + di0 * 2 + c4) = *(const f32x4*)&sYS[row][c4];
    }
  }
}

// ---------------- pass B: carry combine + correction + gate (fused) ----------------
__global__ __launch_bounds__(256)
void k_scan_apply(const float* __restrict__ dbc, const float* __restrict__ ys,
                  const u16* __restrict__ xzb, const float* __restrict__ Abuf,
                  const float* __restrict__ hend, const float* __restrict__ send,
                  u16* __restrict__ yb) {
  const int b   = blockIdx.x;
  const int di0 = blockIdx.y * 64;
  const int s   = blockIdx.z;
  const int tid = threadIdx.x;
  const size_t mb = (size_t)b * L_ + (size_t)s * SEG;
  __shared__ float sC[SEG][16];
  __shared__ float sYO[SEG][64];

  if (s > 0) {
    const int dil = tid >> 2, nq = tid & 3;
    const f32x4 A4 = *(const f32x4*)(Abuf + (size_t)(di0 + dil) * NST + nq * 4);
    f32x4 H4 = {0.f, 0.f, 0.f, 0.f};
    for (int r = 0; r < s; ++r) {
      size_t sb = ((size_t)r * B_ + b) * DI_ + di0 + dil;
      f32x4 he = *(const f32x4*)(hend + sb * 16 + nq * 4);
      float se = send[sb];
      #pragma unroll
      for (int q = 0; q < 4; ++q) H4[q] = __expf(A4[q] * se) * H4[q] + he[q];
    }
    if (tid < SEG * 4) {
      int row = tid >> 2, qq = tid & 3;
      *(f32x4*)&sC[row][qq * 4] = *(const f32x4*)(dbc + (mb + row) * 56 + 40 + qq * 4);
    }
    __syncthreads();
    #pragma unroll 4
    for (int l = 0; l < SEG; ++l) {
      f32x2 yp = *(const f32x2*)(ys + (mb + l) * (DI_ * 2) + (size_t)(di0 + dil) * 2);
      f32x4 C4 = *(const f32x4*)&sC[l][nq * 4];
      float scum = yp.y;
      float corr = 0.f;
      #pragma unroll
      for (int n = 0; n < 4; ++n) corr += C4[n] * __expf(A4[n] * scum) * H4[n];
      corr = quad_sum(corr);
      if (nq == 0) sYO[l][dil] = yp.x + corr;
    }
  } else {
    #pragma unroll
    for (int j = 0; j < 7; ++j) {
      int id = tid + j * 256;
      int row = id >> 6, ch = id & 63;
      sYO[row][ch] = ys[(mb + row) * (DI_ * 2) + (size_t)(di0 + ch) * 2];
    }
  }
  __syncthreads();
  #pragma unroll
  for (int j = 0; j < 4; ++j) {
    int id = tid + j * 256;
    if (id < SEG * 32) {
      int row = id >> 5, c2 = id & 31;
      int ch0 = c2 * 2;
      float y0 = sYO[row][ch0], y1 = sYO[row][ch0 + 1];
      u32 zz = *(const u32*)(xzb + (mb + row) * 1536 + DI_ + di0 + ch0);
      float z0 = bf2f((u16)(zz & 0xffff)), z1 = bf2f((u16)(zz >> 16));
      u32 o = (u32)f2bf(y0 * z0 / (1.f + __expf(-z0)))
            | ((u32)f2bf(y1 * z1 / (1.f + __expf(-z1))) << 16);
      *((u32*)yb + ((mb + row) * DI_ + di0) / 2 + c2) = o;
    }
  }
}

// ---------------- final LN partial sums ----------------
__global__ __launch_bounds__(384)
void k_feat_part(const float* __restrict__ x, float* __restrict__ partial) {
  const int b = blockIdx.x, j = blockIdx.y, d = threadIdx.x;
  __shared__ float red[12];
  const int l0 = j * 28;
  float acc = 0.f;
  float v = x[((size_t)b * L_ + l0) * D_ + d];
  for (int l = l0; l < l0 + 28; ++l) {
    float vn = (l + 1 < l0 + 28) ? x[((size_t)b * L_ + l + 1) * D_ + d] : 0.f;
    float s = v, s2 = v * v;
    #pragma unroll
    for (int o = 32; o > 0; o >>= 1) { s += __shfl_xor(s, o); s2 += __shfl_xor(s2, o); }
    int wid = d >> 6;
    if ((d & 63) == 0) { red[wid] = s; red[6 + wid] = s2; }
    __syncthreads();
    float ts = 0.f, ts2 = 0.f;
    #pragma unroll
    for (int w = 0; w < 6; ++w) { ts += red[w]; ts2 += red[6 + w]; }
    float mu = ts * (1.f / (float)D_);
    float var = ts2 * (1.f / (float)D_) - mu * mu;
    acc += (v - mu) * rsqrtf(var + 1e-5f);
    __syncthreads();
    v = vn;
  }
  partial[((size_t)(b * 7 + j)) * D_ + d] = acc;
}

// ---------------- head ----------------
__global__ __launch_bounds__(256)
void k_head(const float* __restrict__ partial, const float* __restrict__ g,
            const float* __restrict__ bt, const float* __restrict__ hw,
            const float* __restrict__ hb, float* __restrict__ out) {
  const int b = blockIdx.y;
  const int c = blockIdx.x * 256 + threadIdx.x;
  __shared__ float sf[D_];
  for (int i = threadIdx.x; i < D_; i += 256) {
    float s = 0.f;
    #pragma unroll
    for (int j = 0; j < 7; ++j) s += partial[((size_t)(b * 7 + j)) * D_ + i];
    sf[i] = g[i] * (s * (1.f / (float)L_)) + bt[i];
  }
  __syncthreads();
  if (c >= NC_) return;
  float acc = hb[c];
  for (int d = 0; d < D_; ++d) acc += sf[d] * hw[(size_t)d * NC_ + c];
  out[(size_t)b * NC_ + c] = acc;
}

// =====================================================================
extern "C" void kernel_launch(void* const* d_in, const int* in_sizes, int n_in,
                              void* d_out, int out_size, void* d_ws, size_t ws_size,
                              hipStream_t stream) {
  const float* x_in    = (const float*)d_in[0];
  const float* patch_w = (const float*)d_in[1];
  const float* patch_b = (const float*)d_in[2];
  const float* pos     = (const float*)d_in[3];
  const float* bn_g    = (const float*)d_in[4];
  const float* bn_b    = (const float*)d_in[5];
  const float* in_w    = (const float*)d_in[6];
  const float* conv_w  = (const float*)d_in[7];
  const float* conv_b  = (const float*)d_in[8];
  const float* xp_w    = (const float*)d_in[9];
  const float* dtp_w   = (const float*)d_in[10];
  const float* dtp_b   = (const float*)d_in[11];
  const float* A_log   = (const float*)d_in[12];
  const float* D_skip  = (const float*)d_in[13];
  const float* out_w   = (const float*)d_in[14];
  const float* norm_g  = (const float*)d_in[15];
  const float* norm_b  = (const float*)d_in[16];
  const float* head_w  = (const float*)d_in[17];
  const float* head_b  = (const float*)d_in[18];
  float* out = (float*)d_out;

  char* ws = (char*)d_ws;
  size_t off = 0;
  auto alloc = [&](size_t bytes) { size_t o = off; off += (bytes + 255) & ~(size_t)255; return o; };

  float* xbuf   = (float*)(ws + alloc((size_t)M_ * D_ * 4));
  u16*   hbuf   = (u16*)  (ws + alloc((size_t)M_ * D_ * 2));
  u16*   xzb    = (u16*)  (ws + alloc((size_t)M_ * 1536 * 2));
  u16*   xcbb   = (u16*)  (ws + alloc((size_t)M_ * DI_ * 2));
  float* pbuf   = (float*)(ws + alloc((size_t)4 * M_ * 56 * 4));
  float* dbcbuf = (float*)(ws + alloc((size_t)M_ * 56 * 4));
  float* dtbuf  = (float*)(ws + alloc((size_t)M_ * DI_ * 4));   // aliased as im2col before loop
  u16*   ybuf   = (u16*)  (ws + alloc((size_t)M_ * DI_ * 2));
  float* ysbuf  = (float*)(ws + alloc((size_t)M_ * DI_ * 2 * 4));
  float* hend   = (float*)(ws + alloc((size_t)NSEG * B_ * DI_ * NST * 4));
  float* send   = (float*)(ws + alloc((size_t)NSEG * B_ * DI_ * 4));
  float* Abuf   = (float*)(ws + alloc((size_t)DEPTH * DI_ * NST * 4));
  float* partial= (float*)(ws + alloc((size_t)B_ * 7 * D_ * 4));
  u16*   in_wT  = (u16*)  (ws + alloc((size_t)DEPTH * 1536 * D_ * 2));
  u16*   xp_wT  = (u16*)  (ws + alloc((size_t)DEPTH * 56 * DI_ * 2));
  u16*   out_wT = (u16*)  (ws + alloc((size_t)DEPTH * D_ * DI_ * 2));
  u16*   pw_b   = (u16*)  (ws + alloc((size_t)D_ * 768 * 2));
  u16*   im2col = (u16*)dtbuf;

  dim3 tb(32, 8);
  k_transpose_bf16<<<dim3(48, 12, DEPTH), tb, 0, stream>>>(in_w,  in_wT,  D_, 1536);
  k_transpose_bf16<<<dim3(2, 24, DEPTH),  tb, 0, stream>>>(xp_w,  xp_wT,  DI_, 56);
  k_transpose_bf16<<<dim3(12, 24, DEPTH), tb, 0, stream>>>(out_w, out_wT, DI_, D_);
  k_convert_bf16<<<(D_ * 768 + 255) / 256, 256, 0, stream>>>(patch_w, pw_b, D_ * 768);
  k_prepA<<<(DEPTH * DI_ * NST + 255) / 256, 256, 0, stream>>>(A_log, Abuf, DEPTH * DI_ * NST);

  k_im2col<<<(M_ * 768 + 255) / 256, 256, 0, stream>>>(x_in, im2col);
  k_gemm<64,64,2,0><<<dim3(M_ / 64, 6), 256, 0, stream>>>(im2col, pw_b, xbuf, D_, 768, patch_b, pos);

  for (int dp = 0; dp < DEPTH; ++dp) {
    const u16* iwt = in_wT  + (size_t)dp * 1536 * D_;
    const u16* xwt = xp_wT  + (size_t)dp * 56 * DI_;
    const u16* owt = out_wT + (size_t)dp * D_ * DI_;
    const float* Al = Abuf + (size_t)dp * DI_ * NST;
    k_ln<<<M_, 384, 0, stream>>>(xbuf, bn_g + dp * D_, bn_b + dp * D_, hbuf);
    k_gemm<64,128,0,1><<<dim3(M_ / 64, 12), 256, 0, stream>>>(hbuf, iwt, (float*)xzb, 1536, D_, nullptr, nullptr);
    k_conv<<<(M_ * (DI_ / 4) + 255) / 256, 256, 0, stream>>>(xzb, conv_w + (size_t)dp * DI_ * 4,
                                                             conv_b + dp * DI_, xcbb);
    k_xp_split<<<dim3(M_ / 32, 4), 256, 0, stream>>>(xcbb, xwt, pbuf);
    k_xp_reduce<<<M_ * 56 / 1024, 256, 0, stream>>>(pbuf, dbcbuf);
    k_dt<<<dim3(M_ / 16, DI_ / 256), 256, 0, stream>>>(dbcbuf, dtp_w + (size_t)dp * R_ * DI_,
                                                       dtp_b + dp * DI_, dtbuf);
    k_scan_part<<<dim3(B_, DI_ / 64, NSEG), 256, 0, stream>>>(dbcbuf, dtbuf, xcbb, Al,
                                                              D_skip + dp * DI_, ysbuf, hend, send);
    k_scan_apply<<<dim3(B_, DI_ / 64, NSEG), 256, 0, stream>>>(dbcbuf, ysbuf, xzb, Al,
                                                               hend, send, ybuf);
    k_gemm<64,64,1,0><<<dim3(M_ / 64, 6), 256, 0, stream>>>(ybuf, owt, xbuf, D_, DI_, nullptr, nullptr);
  }

  k_feat_part<<<dim3(B_, 7), 384, 0, stream>>>(xbuf, partial);
  k_head<<<dim3((NC_ + 255) / 256, B_), 256, 0, stream>>>(partial, norm_g, norm_b, head_w, head_b, out);
}

// Round 11
// 1471.482 us; speedup vs baseline: 1.3529x; 1.1295x over previous
//
#include <hip/hip_runtime.h>
#include <math.h>

typedef short bf16x8 __attribute__((ext_vector_type(8)));
typedef float f32x4 __attribute__((ext_vector_type(4)));
typedef float f32x2 __attribute__((ext_vector_type(2)));
typedef unsigned short u16;
typedef unsigned int u32;
typedef unsigned short u16x4 __attribute__((ext_vector_type(4)));

#define B_    32
#define D_    384
#define DEPTH 12
#define NST   16
#define DI_   768
#define R_    24
#define L_    196
#define NC_   1000
#define M_    (B_*L_)   // 6272
#define SEG   28
#define NSEG  7

__device__ __forceinline__ u16 f2bf(float f) {
  union { float f; unsigned u; } v; v.f = f;
  unsigned r = v.u + 0x7fffu + ((v.u >> 16) & 1u);
  return (u16)(r >> 16);
}
__device__ __forceinline__ float bf2f(u16 x) {
  union { unsigned u; float f; } v; v.u = ((unsigned)x) << 16;
  return v.f;
}
__device__ __forceinline__ float quad_sum(float y) {
  y += __int_as_float(__builtin_amdgcn_update_dpp(0, __float_as_int(y), 0xB1, 0xf, 0xf, true));
  y += __int_as_float(__builtin_amdgcn_update_dpp(0, __float_as_int(y), 0x4E, 0xf, 0xf, true));
  return y;
}

// ---------------- weight prep ----------------
__global__ void k_transpose_bf16(const float* __restrict__ in, u16* __restrict__ out,
                                 int R, int C) {
  __shared__ float tile[32][33];
  const size_t zoff = (size_t)blockIdx.z * R * C;
  in  += zoff; out += zoff;
  int c0 = blockIdx.x * 32, r0 = blockIdx.y * 32;
  int tx = threadIdx.x, ty = threadIdx.y;
  for (int i = ty; i < 32; i += 8) {
    int r = r0 + i, c = c0 + tx;
    tile[i][tx] = (r < R && c < C) ? in[(size_t)r * C + c] : 0.f;
  }
  __syncthreads();
  for (int i = ty; i < 32; i += 8) {
    int c = c0 + i, r = r0 + tx;
    if (c < C && r < R) out[(size_t)c * R + r] = f2bf(tile[tx][i]);
  }
}

__global__ void k_convert_bf16(const float* __restrict__ in, u16* __restrict__ out, int n) {
  int i = blockIdx.x * 256 + threadIdx.x;
  if (i < n) out[i] = f2bf(in[i]);
}

__global__ void k_prepA(const float* __restrict__ alog, float* __restrict__ A, int n) {
  int i = blockIdx.x * 256 + threadIdx.x;
  if (i < n) A[i] = -__expf(alog[i]);
}

// ---------------- im2col ----------------
__global__ void k_im2col(const float* __restrict__ x, u16* __restrict__ xcol) {
  int idx = blockIdx.x * 256 + threadIdx.x;
  if (idx >= M_ * 768) return;
  int k = idx % 768, m = idx / 768;
  int b = m / L_, l = m % L_;
  int li = l / 14, lj = l % 14;
  int c = k / 256, r = k % 256;
  int i = r / 16, j = r % 16;
  int hh = li * 16 + i, ww = lj * 16 + j;
  xcol[idx] = f2bf(x[(((size_t)b * 3 + c) * 224 + hh) * 224 + ww]);
}

// ---------------- GEMM (software-pipelined) ----------------
template<int BM, int BN, int EPI, int OB>
__global__ __launch_bounds__(256)
void k_gemm(const u16* __restrict__ A, const u16* __restrict__ BT,
            float* __restrict__ Cout, int Nn, int Kk,
            const float* __restrict__ bias, const float* __restrict__ pos) {
  const int m0 = blockIdx.x * BM;
  const int n0 = blockIdx.y * BN;
  __shared__ u16 lA[BM * 72];
  __shared__ u16 lB[BN * 72];
  const int tid  = threadIdx.x;
  const int wave = tid >> 6, lane = tid & 63;
  const int wm = (wave >> 1) * (BM / 2), wn = (wave & 1) * (BN / 2);
  constexpr int MI = BM / 32, NJ = BN / 32;
  constexpr int NV = (BM + BN) / 32;
  f32x4 acc[MI][NJ] = {};
  const int fr = lane & 15, kg = (lane >> 4) * 8;

  bf16x8 v[NV];
  auto load = [&](int k0) {
    #pragma unroll
    for (int q = 0; q < NV; ++q) {
      int id = tid + q * 256;
      int row = id >> 3, vv = id & 7;
      bf16x8 t = {};
      if (row < BM) {
        t = *(const bf16x8*)(A + (size_t)(m0 + row) * Kk + k0 + vv * 8);
      } else {
        int br = n0 + row - BM;
        if (br < Nn) t = *(const bf16x8*)(BT + (size_t)br * Kk + k0 + vv * 8);
      }
      v[q] = t;
    }
  };
  load(0);
  for (int k0 = 0; k0 < Kk; k0 += 64) {
    __syncthreads();
    #pragma unroll
    for (int q = 0; q < NV; ++q) {
      int id = tid + q * 256;
      int row = id >> 3, vv = id & 7;
      u16* dst = (row < BM) ? (lA + row * 72 + vv * 8) : (lB + (size_t)(row - BM) * 72 + vv * 8);
      *(bf16x8*)dst = v[q];
    }
    __syncthreads();
    if (k0 + 64 < Kk) load(k0 + 64);
    #pragma unroll
    for (int kk = 0; kk < 64; kk += 32) {
      bf16x8 af[MI], bfr[NJ];
      #pragma unroll
      for (int i = 0; i < MI; ++i)
        af[i] = *(const bf16x8*)(lA + (wm + i * 16 + fr) * 72 + kk + kg);
      #pragma unroll
      for (int j = 0; j < NJ; ++j)
        bfr[j] = *(const bf16x8*)(lB + (wn + j * 16 + fr) * 72 + kk + kg);
      #pragma unroll
      for (int i = 0; i < MI; ++i)
        #pragma unroll
        for (int j = 0; j < NJ; ++j)
          acc[i][j] = __builtin_amdgcn_mfma_f32_16x16x32_bf16(af[i], bfr[j], acc[i][j], 0, 0, 0);
    }
  }

  const int rg = (lane >> 4) * 4;
  #pragma unroll
  for (int i = 0; i < MI; ++i) {
    int row = m0 + wm + i * 16 + rg;
    #pragma unroll
    for (int j = 0; j < NJ; ++j) {
      int col = n0 + wn + j * 16 + fr;
      if (col >= Nn) continue;
      #pragma unroll
      for (int r = 0; r < 4; ++r) {
        float vv = acc[i][j][r];
        size_t idx = (size_t)(row + r) * Nn + col;
        if (EPI == 0) {
          if (OB) ((u16*)Cout)[idx] = f2bf(vv);
          else    Cout[idx] = vv;
        }
        else if (EPI == 1) Cout[idx] += vv;
        else               Cout[idx] = vv + bias[col] + pos[(size_t)((row + r) % L_) * Nn + col];
      }
    }
  }
}

// ---------------- xp skinny GEMM, K-split x4 ----------------
__global__ __launch_bounds__(256)
void k_xp_split(const u16* __restrict__ A, const u16* __restrict__ BT,
                float* __restrict__ pbuf) {
  const int m0 = blockIdx.x * 32;
  const int ks = blockIdx.y;
  __shared__ u16 lA[32 * 72];
  __shared__ u16 lB[64 * 72];
  const int tid  = threadIdx.x;
  const int wave = tid >> 6, lane = tid & 63;
  const int wm = (wave >> 1) * 16, wn = (wave & 1) * 32;
  const int fr = lane & 15, kg = (lane >> 4) * 8;
  f32x4 acc[2] = {};

  bf16x8 v[3];
  auto load = [&](int k0) {
    #pragma unroll
    for (int q = 0; q < 3; ++q) {
      int id = tid + q * 256;
      int row = id >> 3, vv = id & 7;
      bf16x8 t = {};
      if (row < 32) {
        t = *(const bf16x8*)(A + (size_t)(m0 + row) * DI_ + k0 + vv * 8);
      } else {
        int br = row - 32;
        if (br < 56) t = *(const bf16x8*)(BT + (size_t)br * DI_ + k0 + vv * 8);
      }
      v[q] = t;
    }
  };
  const int kbase = ks * 192;
  load(kbase);
  for (int k0 = kbase; k0 < kbase + 192; k0 += 64) {
    __syncthreads();
    #pragma unroll
    for (int q = 0; q < 3; ++q) {
      int id = tid + q * 256;
      int row = id >> 3, vv = id & 7;
      u16* dst = (row < 32) ? (lA + row * 72 + vv * 8) : (lB + (size_t)(row - 32) * 72 + vv * 8);
      *(bf16x8*)dst = v[q];
    }
    __syncthreads();
    if (k0 + 64 < kbase + 192) load(k0 + 64);
    #pragma unroll
    for (int kk = 0; kk < 64; kk += 32) {
      bf16x8 af = *(const bf16x8*)(lA + (wm + fr) * 72 + kk + kg);
      bf16x8 b0 = *(const bf16x8*)(lB + (wn + fr) * 72 + kk + kg);
      bf16x8 b1 = *(const bf16x8*)(lB + (wn + 16 + fr) * 72 + kk + kg);
      acc[0] = __builtin_amdgcn_mfma_f32_16x16x32_bf16(af, b0, acc[0], 0, 0, 0);
      acc[1] = __builtin_amdgcn_mfma_f32_16x16x32_bf16(af, b1, acc[1], 0, 0, 0);
    }
  }
  const int rg = (lane >> 4) * 4;
  #pragma unroll
  for (int j = 0; j < 2; ++j) {
    int col = wn + j * 16 + fr;
    if (col >= 56) continue;
    #pragma unroll
    for (int r = 0; r < 4; ++r) {
      int row = wm + rg + r;
      pbuf[((size_t)ks * M_ + m0 + row) * 56 + col] = acc[j][r];
    }
  }
}

// ---------------- LayerNorm ----------------
__global__ __launch_bounds__(384)
void k_ln(const float* __restrict__ x, const float* __restrict__ g,
          const float* __restrict__ bt, u16* __restrict__ h) {
  const int m = blockIdx.x, d = threadIdx.x;
  __shared__ float red[12];
  float v = x[(size_t)m * D_ + d];
  float s = v, s2 = v * v;
  #pragma unroll
  for (int o = 32; o > 0; o >>= 1) { s += __shfl_xor(s, o); s2 += __shfl_xor(s2, o); }
  int wid = d >> 6;
  if ((d & 63) == 0) { red[wid] = s; red[6 + wid] = s2; }
  __syncthreads();
  float ts = 0.f, ts2 = 0.f;
  #pragma unroll
  for (int w = 0; w < 6; ++w) { ts += red[w]; ts2 += red[6 + w]; }
  float mu = ts / (float)D_;
  float var = ts2 / (float)D_ - mu * mu;
  float rs = rsqrtf(var + 1e-5f);
  h[(size_t)m * D_ + d] = f2bf((v - mu) * rs * g[d] + bt[d]);
}

// ---------------- conv + SiLU ----------------
__global__ __launch_bounds__(256)
void k_conv(const u16* __restrict__ xzb, const float* __restrict__ cw,
            const float* __restrict__ cb, u16* __restrict__ xcb) {
  int idx = blockIdx.x * 256 + threadIdx.x;
  if (idx >= M_ * (DI_ / 4)) return;
  int dq = idx % (DI_ / 4), m = idx / (DI_ / 4), l = m % L_;
  int di4 = dq * 4;
  const u16* base = xzb + (size_t)m * 1536 + di4;
  float xv[4][4];
  #pragma unroll
  for (int t = 0; t < 4; ++t) {
    int back = 3 - t;
    u16x4 v = {};
    if (l >= back) v = *(const u16x4*)(base - (size_t)back * 1536);
    #pragma unroll
    for (int c = 0; c < 4; ++c) xv[t][c] = bf2f(v[c]);
  }
  f32x4 bv = *(const f32x4*)(cb + di4);
  u16x4 outv;
  #pragma unroll
  for (int c = 0; c < 4; ++c) {
    f32x4 w = *(const f32x4*)(cw + (size_t)(di4 + c) * 4);
    float acc = bv[c] + w[0] * xv[0][c] + w[1] * xv[1][c] + w[2] * xv[2][c] + w[3] * xv[3][c];
    float s = acc / (1.f + __expf(-acc));
    outv[c] = f2bf(s);
  }
  *(u16x4*)(xcb + (size_t)m * DI_ + di4) = outv;
}

// ---------------- pass A: fused dt + local segment scan ----------------
// grid (B_, DI_/64, NSEG). Sums 4 pbuf K-split slices inline (= dbc), computes
// dt = softplus(dbc[:, :24] @ dtw + dtb) in-kernel, then runs the 28-step scan.
__global__ __launch_bounds__(256)
void k_scan_part(const float* __restrict__ pbuf, const u16* __restrict__ xcb,
                 const float* __restrict__ dtw, const float* __restrict__ dtb,
                 const float* __restrict__ Abuf, const float* __restrict__ Dsk,
                 float* __restrict__ ys, float* __restrict__ hend,
                 float* __restrict__ send) {
  const int b   = blockIdx.x;
  const int di0 = blockIdx.y * 64;
  const int s   = blockIdx.z;
  const int tid = threadIdx.x;
  const int dil = tid >> 2, nq = tid & 3;
  const int di  = di0 + dil;
  __shared__ float sDT[SEG][64];
  __shared__ float sXC[SEG][64];
  __shared__ float sBC[SEG][32];
  __shared__ float sdb[SEG][28];   // dbc cols 0..23 (stride 28 keeps 16B align)

  const f32x4 Arow = *(const f32x4*)(Abuf + (size_t)di * NST + nq * 4);
  const float Dv = Dsk[di];
  const size_t mb = (size_t)b * L_ + (size_t)s * SEG;
  const int chd = tid & 63;        // dt-compute channel

  // ---- staging (concurrent, disjoint LDS) ----
  {
    int r = tid >> 4, cc = (tid & 15) * 4;
    #pragma unroll
    for (int j = 0; j < 2; ++j) {
      int row = r + j * 16;
      if (row < SEG) {
        u16x4 xv = *(const u16x4*)(xcb + (mb + row) * DI_ + di0 + cc);
        f32x4 xf;
        #pragma unroll
        for (int q = 0; q < 4; ++q) xf[q] = bf2f(xv[q]);
        *(f32x4*)&sXC[row][cc] = xf;
      }
    }
    if (tid < SEG * 6) {           // dbc cols 0..23, 4-slice sum
      int row = tid / 6, c4 = (tid % 6) * 4;
      f32x4 ssum = {};
      #pragma unroll
      for (int ks = 0; ks < 4; ++ks)
        ssum += *(const f32x4*)(pbuf + ((size_t)ks * M_ + mb + row) * 56 + c4);
      *(f32x4*)&sdb[row][c4] = ssum;
    }
    if (tid < SEG * 8) {           // dbc cols 24..55 (B,C), 4-slice sum
      int row = tid >> 3, c4 = (tid & 7) * 4;
      f32x4 ssum = {};
      #pragma unroll
      for (int ks = 0; ks < 4; ++ks)
        ssum += *(const f32x4*)(pbuf + ((size_t)ks * M_ + mb + row) * 56 + 24 + c4);
      *(f32x4*)&sBC[row][c4] = ssum;
    }
  }
  float w[24];
  #pragma unroll
  for (int r = 0; r < 24; ++r) w[r] = dtw[r * DI_ + di0 + chd];
  const float bvd = dtb[di0 + chd];
  __syncthreads();

  // ---- dt compute: thread (chd, rg) does 7 rows ----
  {
    const int rg = tid >> 6;
    #pragma unroll
    for (int rr = 0; rr < 7; ++rr) {
      int row = rg * 7 + rr;
      float acc = bvd;
      #pragma unroll
      for (int r4 = 0; r4 < 6; ++r4) {
        f32x4 sv = *(const f32x4*)&sdb[row][r4 * 4];
        acc += sv[0] * w[r4 * 4] + sv[1] * w[r4 * 4 + 1]
             + sv[2] * w[r4 * 4 + 2] + sv[3] * w[r4 * 4 + 3];
      }
      float e  = __expf(-fabsf(acc));
      sDT[row][chd] = fmaxf(acc, 0.f) + __logf(1.f + e);
    }
  }
  __syncthreads();

  // ---- 28-step scan ----
  float h[4] = {0.f, 0.f, 0.f, 0.f};
  float scum = 0.f;
  float dtc = sDT[0][dil], xcc = sXC[0][dil];
  f32x4 Bv = *(const f32x4*)&sBC[0][nq * 4];
  f32x4 Cv = *(const f32x4*)&sBC[0][16 + nq * 4];
  #pragma unroll 4
  for (int t = 0; t < SEG; ++t) {
    float dtn = 0.f, xcn = 0.f; f32x4 Bn = {}, Cn = {};
    if (t + 1 < SEG) {
      dtn = sDT[t + 1][dil]; xcn = sXC[t + 1][dil];
      Bn = *(const f32x4*)&sBC[t + 1][nq * 4];
      Cn = *(const f32x4*)&sBC[t + 1][16 + nq * 4];
    }
    scum += dtc;
    float dxv = dtc * xcc;
    float y = (nq == 0) ? Dv * xcc : 0.f;
    #pragma unroll
    for (int n = 0; n < 4; ++n) {
      float e = __expf(dtc * Arow[n]);
      h[n] = e * h[n] + dxv * Bv[n];
      y += h[n] * Cv[n];
    }
    y = quad_sum(y);
    if (nq == 0)
      *(f32x2*)(ys + (mb + t) * (DI_ * 2) + (size_t)(di0 + dil) * 2) = f32x2{y, scum};
    dtc = dtn; xcc = xcn; Bv = Bn; Cv = Cn;
  }

  size_t sb = ((size_t)s * B_ + b) * DI_ + di;
  *(f32x4*)(hend + sb * 16 + nq * 4) = f32x4{h[0], h[1], h[2], h[3]};
  if (nq == 0) send[sb] = scum;
}

// ---------------- pass B: carry combine + correction + gate ----------------
__global__ __launch_bounds__(256)
void k_scan_apply(const float* __restrict__ pbuf, const float* __restrict__ ys,
                  const u16* __restrict__ xzb, const float* __restrict__ Abuf,
                  const float* __restrict__ hend, const float* __restrict__ send,
                  u16* __restrict__ yb) {
  const int b   = blockIdx.x;
  const int di0 = blockIdx.y * 64;
  const int s   = blockIdx.z;
  const int tid = threadIdx.x;
  const size_t mb = (size_t)b * L_ + (size_t)s * SEG;
  __shared__ float sC[SEG][16];
  __shared__ float sYO[SEG][64];

  if (s > 0) {
    const int dil = tid >> 2, nq = tid & 3;
    const f32x4 A4 = *(const f32x4*)(Abuf + (size_t)(di0 + dil) * NST + nq * 4);
    f32x4 H4 = {0.f, 0.f, 0.f, 0.f};
    for (int r = 0; r < s; ++r) {
      size_t sb = ((size_t)r * B_ + b) * DI_ + di0 + dil;
      f32x4 he = *(const f32x4*)(hend + sb * 16 + nq * 4);
      float se = send[sb];
      #pragma unroll
      for (int q = 0; q < 4; ++q) H4[q] = __expf(A4[q] * se) * H4[q] + he[q];
    }
    if (tid < SEG * 4) {
      int row = tid >> 2, qq = tid & 3;
      f32x4 ssum = {};
      #pragma unroll
      for (int ks = 0; ks < 4; ++ks)
        ssum += *(const f32x4*)(pbuf + ((size_t)ks * M_ + mb + row) * 56 + 40 + qq * 4);
      *(f32x4*)&sC[row][qq * 4] = ssum;
    }
    __syncthreads();
    #pragma unroll 4
    for (int l = 0; l < SEG; ++l) {
      f32x2 yp = *(const f32x2*)(ys + (mb + l) * (DI_ * 2) + (size_t)(di0 + dil) * 2);
      f32x4 C4 = *(const f32x4*)&sC[l][nq * 4];
      float scum = yp.y;
      float corr = 0.f;
      #pragma unroll
      for (int n = 0; n < 4; ++n) corr += C4[n] * __expf(A4[n] * scum) * H4[n];
      corr = quad_sum(corr);
      if (nq == 0) sYO[l][dil] = yp.x + corr;
    }
  } else {
    #pragma unroll
    for (int j = 0; j < 7; ++j) {
      int id = tid + j * 256;
      int row = id >> 6, ch = id & 63;
      sYO[row][ch] = ys[(mb + row) * (DI_ * 2) + (size_t)(di0 + ch) * 2];
    }
  }
  __syncthreads();
  #pragma unroll
  for (int j = 0; j < 4; ++j) {
    int id = tid + j * 256;
    if (id < SEG * 32) {
      int row = id >> 5, c2 = id & 31;
      int ch0 = c2 * 2;
      float y0 = sYO[row][ch0], y1 = sYO[row][ch0 + 1];
      u32 zz = *(const u32*)(xzb + (mb + row) * 1536 + DI_ + di0 + ch0);
      float z0 = bf2f((u16)(zz & 0xffff)), z1 = bf2f((u16)(zz >> 16));
      u32 o = (u32)f2bf(y0 * z0 / (1.f + __expf(-z0)))
            | ((u32)f2bf(y1 * z1 / (1.f + __expf(-z1))) << 16);
      *((u32*)yb + ((mb + row) * DI_ + di0) / 2 + c2) = o;
    }
  }
}

// ---------------- final LN partial sums ----------------
__global__ __launch_bounds__(384)
void k_feat_part(const float* __restrict__ x, float* __restrict__ partial) {
  const int b = blockIdx.x, j = blockIdx.y, d = threadIdx.x;
  __shared__ float red[12];
  const int l0 = j * 28;
  float acc = 0.f;
  float v = x[((size_t)b * L_ + l0) * D_ + d];
  for (int l = l0; l < l0 + 28; ++l) {
    float vn = (l + 1 < l0 + 28) ? x[((size_t)b * L_ + l + 1) * D_ + d] : 0.f;
    float s = v, s2 = v * v;
    #pragma unroll
    for (int o = 32; o > 0; o >>= 1) { s += __shfl_xor(s, o); s2 += __shfl_xor(s2, o); }
    int wid = d >> 6;
    if ((d & 63) == 0) { red[wid] = s; red[6 + wid] = s2; }
    __syncthreads();
    float ts = 0.f, ts2 = 0.f;
    #pragma unroll
    for (int w = 0; w < 6; ++w) { ts += red[w]; ts2 += red[6 + w]; }
    float mu = ts * (1.f / (float)D_);
    float var = ts2 * (1.f / (float)D_) - mu * mu;
    acc += (v - mu) * rsqrtf(var + 1e-5f);
    __syncthreads();
    v = vn;
  }
  partial[((size_t)(b * 7 + j)) * D_ + d] = acc;
}

// ---------------- head ----------------
__global__ __launch_bounds__(256)
void k_head(const float* __restrict__ partial, const float* __restrict__ g,
            const float* __restrict__ bt, const float* __restrict__ hw,
            const float* __restrict__ hb, float* __restrict__ out) {
  const int b = blockIdx.y;
  const int c = blockIdx.x * 256 + threadIdx.x;
  __shared__ float sf[D_];
  for (int i = threadIdx.x; i < D_; i += 256) {
    float s = 0.f;
    #pragma unroll
    for (int j = 0; j < 7; ++j) s += partial[((size_t)(b * 7 + j)) * D_ + i];
    sf[i] = g[i] * (s * (1.f / (float)L_)) + bt[i];
  }
  __syncthreads();
  if (c >= NC_) return;
  float acc = hb[c];
  for (int d = 0; d < D_; ++d) acc += sf[d] * hw[(size_t)d * NC_ + c];
  out[(size_t)b * NC_ + c] = acc;
}

// =====================================================================
extern "C" void kernel_launch(void* const* d_in, const int* in_sizes, int n_in,
                              void* d_out, int out_size, void* d_ws, size_t ws_size,
                              hipStream_t stream) {
  const float* x_in    = (const float*)d_in[0];
  const float* patch_w = (const float*)d_in[1];
  const float* patch_b = (const float*)d_in[2];
  const float* pos     = (const float*)d_in[3];
  const float* bn_g    = (const float*)d_in[4];
  const float* bn_b    = (const float*)d_in[5];
  const float* in_w    = (const float*)d_in[6];
  const float* conv_w  = (const float*)d_in[7];
  const float* conv_b  = (const float*)d_in[8];
  const float* xp_w    = (const float*)d_in[9];
  const float* dtp_w   = (const float*)d_in[10];
  const float* dtp_b   = (const float*)d_in[11];
  const float* A_log   = (const float*)d_in[12];
  const float* D_skip  = (const float*)d_in[13];
  const float* out_w   = (const float*)d_in[14];
  const float* norm_g  = (const float*)d_in[15];
  const float* norm_b  = (const float*)d_in[16];
  const float* head_w  = (const float*)d_in[17];
  const float* head_b  = (const float*)d_in[18];
  float* out = (float*)d_out;

  char* ws = (char*)d_ws;
  size_t off = 0;
  auto alloc = [&](size_t bytes) { size_t o = off; off += (bytes + 255) & ~(size_t)255; return o; };

  float* xbuf   = (float*)(ws + alloc((size_t)M_ * D_ * 4));
  u16*   hbuf   = (u16*)  (ws + alloc((size_t)M_ * D_ * 2));
  u16*   xzb    = (u16*)  (ws + alloc((size_t)M_ * 1536 * 2));
  u16*   xcbb   = (u16*)  (ws + alloc((size_t)M_ * DI_ * 2));
  float* pbuf   = (float*)(ws + alloc((size_t)4 * M_ * 56 * 4));
  u16*   im2col = (u16*)  (ws + alloc((size_t)M_ * 768 * 2));
  u16*   ybuf   = (u16*)  (ws + alloc((size_t)M_ * DI_ * 2));
  float* ysbuf  = (float*)(ws + alloc((size_t)M_ * DI_ * 2 * 4));
  float* hend   = (float*)(ws + alloc((size_t)NSEG * B_ * DI_ * NST * 4));
  float* send   = (float*)(ws + alloc((size_t)NSEG * B_ * DI_ * 4));
  float* Abuf   = (float*)(ws + alloc((size_t)DEPTH * DI_ * NST * 4));
  float* partial= (float*)(ws + alloc((size_t)B_ * 7 * D_ * 4));
  u16*   in_wT  = (u16*)  (ws + alloc((size_t)DEPTH * 1536 * D_ * 2));
  u16*   xp_wT  = (u16*)  (ws + alloc((size_t)DEPTH * 56 * DI_ * 2));
  u16*   out_wT = (u16*)  (ws + alloc((size_t)DEPTH * D_ * DI_ * 2));
  u16*   pw_b   = (u16*)  (ws + alloc((size_t)D_ * 768 * 2));

  dim3 tb(32, 8);
  k_transpose_bf16<<<dim3(48, 12, DEPTH), tb, 0, stream>>>(in_w,  in_wT,  D_, 1536);
  k_transpose_bf16<<<dim3(2, 24, DEPTH),  tb, 0, stream>>>(xp_w,  xp_wT,  DI_, 56);
  k_transpose_bf16<<<dim3(12, 24, DEPTH), tb, 0, stream>>>(out_w, out_wT, DI_, D_);
  k_convert_bf16<<<(D_ * 768 + 255) / 256, 256, 0, stream>>>(patch_w, pw_b, D_ * 768);
  k_prepA<<<(DEPTH * DI_ * NST + 255) / 256, 256, 0, stream>>>(A_log, Abuf, DEPTH * DI_ * NST);

  k_im2col<<<(M_ * 768 + 255) / 256, 256, 0, stream>>>(x_in, im2col);
  k_gemm<64,64,2,0><<<dim3(M_ / 64, 6), 256, 0, stream>>>(im2col, pw_b, xbuf, D_, 768, patch_b, pos);

  for (int dp = 0; dp < DEPTH; ++dp) {
    const u16* iwt = in_wT  + (size_t)dp * 1536 * D_;
    const u16* xwt = xp_wT  + (size_t)dp * 56 * DI_;
    const u16* owt = out_wT + (size_t)dp * D_ * DI_;
    const float* Al = Abuf + (size_t)dp * DI_ * NST;
    k_ln<<<M_, 384, 0, stream>>>(xbuf, bn_g + dp * D_, bn_b + dp * D_, hbuf);
    k_gemm<64,128,0,1><<<dim3(M_ / 64, 12), 256, 0, stream>>>(hbuf, iwt, (float*)xzb, 1536, D_, nullptr, nullptr);
    k_conv<<<(M_ * (DI_ / 4) + 255) / 256, 256, 0, stream>>>(xzb, conv_w + (size_t)dp * DI_ * 4,
                                                             conv_b + dp * DI_, xcbb);
    k_xp_split<<<dim3(M_ / 32, 4), 256, 0, stream>>>(xcbb, xwt, pbuf);
    k_scan_part<<<dim3(B_, DI_ / 64, NSEG), 256, 0, stream>>>(pbuf, xcbb,
                                                              dtp_w + (size_t)dp * R_ * DI_,
                                                              dtp_b + dp * DI_, Al,
                                                              D_skip + dp * DI_, ysbuf, hend, send);
    k_scan_apply<<<dim3(B_, DI_ / 64, NSEG), 256, 0, stream>>>(pbuf, ysbuf, xzb, Al,
                                                               hend, send, ybuf);
    k_gemm<64,64,1,0><<<dim3(M_ / 64, 6), 256, 0, stream>>>(ybuf, owt, xbuf, D_, DI_, nullptr, nullptr);
  }

  k_feat_part<<<dim3(B_, 7), 384, 0, stream>>>(xbuf, partial);
  k_head<<<dim3((NC_ + 255) / 256, B_), 256, 0, stream>>>(partial, norm_g, norm_b, head_w, head_b, out);
}

// Round 12
// 1371.261 us; speedup vs baseline: 1.4518x; 1.0731x over previous
//
#include <hip/hip_runtime.h>
#include <math.h>

typedef short bf16x8 __attribute__((ext_vector_type(8)));
typedef float f32x4 __attribute__((ext_vector_type(4)));
typedef float f32x2 __attribute__((ext_vector_type(2)));
typedef unsigned short u16;
typedef unsigned int u32;
typedef unsigned short u16x4 __attribute__((ext_vector_type(4)));

#define B_    32
#define D_    384
#define DEPTH 12
#define NST   16
#define DI_   768
#define R_    24
#define L_    196
#define NC_   1000
#define M_    (B_*L_)   // 6272
#define SEG   28
#define NSEG  7

__device__ __forceinline__ u16 f2bf(float f) {
  union { float f; unsigned u; } v; v.f = f;
  unsigned r = v.u + 0x7fffu + ((v.u >> 16) & 1u);
  return (u16)(r >> 16);
}
__device__ __forceinline__ float bf2f(u16 x) {
  union { unsigned u; float f; } v; v.u = ((unsigned)x) << 16;
  return v.f;
}
__device__ __forceinline__ float quad_sum(float y) {
  y += __int_as_float(__builtin_amdgcn_update_dpp(0, __float_as_int(y), 0xB1, 0xf, 0xf, true));
  y += __int_as_float(__builtin_amdgcn_update_dpp(0, __float_as_int(y), 0x4E, 0xf, 0xf, true));
  return y;
}

// ---------------- weight prep ----------------
__global__ void k_transpose_bf16(const float* __restrict__ in, u16* __restrict__ out,
                                 int R, int C) {
  __shared__ float tile[32][33];
  const size_t zoff = (size_t)blockIdx.z * R * C;
  in  += zoff; out += zoff;
  int c0 = blockIdx.x * 32, r0 = blockIdx.y * 32;
  int tx = threadIdx.x, ty = threadIdx.y;
  for (int i = ty; i < 32; i += 8) {
    int r = r0 + i, c = c0 + tx;
    tile[i][tx] = (r < R && c < C) ? in[(size_t)r * C + c] : 0.f;
  }
  __syncthreads();
  for (int i = ty; i < 32; i += 8) {
    int c = c0 + i, r = r0 + tx;
    if (c < C && r < R) out[(size_t)c * R + r] = f2bf(tile[tx][i]);
  }
}

__global__ void k_convert_bf16(const float* __restrict__ in, u16* __restrict__ out, int n) {
  int i = blockIdx.x * 256 + threadIdx.x;
  if (i < n) out[i] = f2bf(in[i]);
}

__global__ void k_prepA(const float* __restrict__ alog, float* __restrict__ A, int n) {
  int i = blockIdx.x * 256 + threadIdx.x;
  if (i < n) A[i] = -__expf(alog[i]);
}

// ---------------- im2col ----------------
__global__ void k_im2col(const float* __restrict__ x, u16* __restrict__ xcol) {
  int idx = blockIdx.x * 256 + threadIdx.x;
  if (idx >= M_ * 768) return;
  int k = idx % 768, m = idx / 768;
  int b = m / L_, l = m % L_;
  int li = l / 14, lj = l % 14;
  int c = k / 256, r = k % 256;
  int i = r / 16, j = r % 16;
  int hh = li * 16 + i, ww = lj * 16 + j;
  xcol[idx] = f2bf(x[(((size_t)b * 3 + c) * 224 + hh) * 224 + ww]);
}

// ---------------- GEMM (software-pipelined) ----------------
template<int BM, int BN, int EPI, int OB>
__global__ __launch_bounds__(256)
void k_gemm(const u16* __restrict__ A, const u16* __restrict__ BT,
            float* __restrict__ Cout, int Nn, int Kk,
            const float* __restrict__ bias, const float* __restrict__ pos) {
  const int m0 = blockIdx.x * BM;
  const int n0 = blockIdx.y * BN;
  __shared__ u16 lA[BM * 72];
  __shared__ u16 lB[BN * 72];
  const int tid  = threadIdx.x;
  const int wave = tid >> 6, lane = tid & 63;
  const int wm = (wave >> 1) * (BM / 2), wn = (wave & 1) * (BN / 2);
  constexpr int MI = BM / 32, NJ = BN / 32;
  constexpr int NV = (BM + BN) / 32;
  f32x4 acc[MI][NJ] = {};
  const int fr = lane & 15, kg = (lane >> 4) * 8;

  bf16x8 v[NV];
  auto load = [&](int k0) {
    #pragma unroll
    for (int q = 0; q < NV; ++q) {
      int id = tid + q * 256;
      int row = id >> 3, vv = id & 7;
      bf16x8 t = {};
      if (row < BM) {
        t = *(const bf16x8*)(A + (size_t)(m0 + row) * Kk + k0 + vv * 8);
      } else {
        int br = n0 + row - BM;
        if (br < Nn) t = *(const bf16x8*)(BT + (size_t)br * Kk + k0 + vv * 8);
      }
      v[q] = t;
    }
  };
  load(0);
  for (int k0 = 0; k0 < Kk; k0 += 64) {
    __syncthreads();
    #pragma unroll
    for (int q = 0; q < NV; ++q) {
      int id = tid + q * 256;
      int row = id >> 3, vv = id & 7;
      u16* dst = (row < BM) ? (lA + row * 72 + vv * 8) : (lB + (size_t)(row - BM) * 72 + vv * 8);
      *(bf16x8*)dst = v[q];
    }
    __syncthreads();
    if (k0 + 64 < Kk) load(k0 + 64);
    #pragma unroll
    for (int kk = 0; kk < 64; kk += 32) {
      bf16x8 af[MI], bfr[NJ];
      #pragma unroll
      for (int i = 0; i < MI; ++i)
        af[i] = *(const bf16x8*)(lA + (wm + i * 16 + fr) * 72 + kk + kg);
      #pragma unroll
      for (int j = 0; j < NJ; ++j)
        bfr[j] = *(const bf16x8*)(lB + (wn + j * 16 + fr) * 72 + kk + kg);
      #pragma unroll
      for (int i = 0; i < MI; ++i)
        #pragma unroll
        for (int j = 0; j < NJ; ++j)
          acc[i][j] = __builtin_amdgcn_mfma_f32_16x16x32_bf16(af[i], bfr[j], acc[i][j], 0, 0, 0);
    }
  }

  const int rg = (lane >> 4) * 4;
  #pragma unroll
  for (int i = 0; i < MI; ++i) {
    int row = m0 + wm + i * 16 + rg;
    #pragma unroll
    for (int j = 0; j < NJ; ++j) {
      int col = n0 + wn + j * 16 + fr;
      if (col >= Nn) continue;
      #pragma unroll
      for (int r = 0; r < 4; ++r) {
        float vv = acc[i][j][r];
        size_t idx = (size_t)(row + r) * Nn + col;
        if (EPI == 0) {
          if (OB) ((u16*)Cout)[idx] = f2bf(vv);
          else    Cout[idx] = vv;
        }
        else if (EPI == 1) Cout[idx] += vv;
        else               Cout[idx] = vv + bias[col] + pos[(size_t)((row + r) % L_) * Nn + col];
      }
    }
  }
}

// ---------------- xp skinny GEMM, K-split x4 ----------------
__global__ __launch_bounds__(256)
void k_xp_split(const u16* __restrict__ A, const u16* __restrict__ BT,
                float* __restrict__ pbuf) {
  const int m0 = blockIdx.x * 32;
  const int ks = blockIdx.y;
  __shared__ u16 lA[32 * 72];
  __shared__ u16 lB[64 * 72];
  const int tid  = threadIdx.x;
  const int wave = tid >> 6, lane = tid & 63;
  const int wm = (wave >> 1) * 16, wn = (wave & 1) * 32;
  const int fr = lane & 15, kg = (lane >> 4) * 8;
  f32x4 acc[2] = {};

  bf16x8 v[3];
  auto load = [&](int k0) {
    #pragma unroll
    for (int q = 0; q < 3; ++q) {
      int id = tid + q * 256;
      int row = id >> 3, vv = id & 7;
      bf16x8 t = {};
      if (row < 32) {
        t = *(const bf16x8*)(A + (size_t)(m0 + row) * DI_ + k0 + vv * 8);
      } else {
        int br = row - 32;
        if (br < 56) t = *(const bf16x8*)(BT + (size_t)br * DI_ + k0 + vv * 8);
      }
      v[q] = t;
    }
  };
  const int kbase = ks * 192;
  load(kbase);
  for (int k0 = kbase; k0 < kbase + 192; k0 += 64) {
    __syncthreads();
    #pragma unroll
    for (int q = 0; q < 3; ++q) {
      int id = tid + q * 256;
      int row = id >> 3, vv = id & 7;
      u16* dst = (row < 32) ? (lA + row * 72 + vv * 8) : (lB + (size_t)(row - 32) * 72 + vv * 8);
      *(bf16x8*)dst = v[q];
    }
    __syncthreads();
    if (k0 + 64 < kbase + 192) load(k0 + 64);
    #pragma unroll
    for (int kk = 0; kk < 64; kk += 32) {
      bf16x8 af = *(const bf16x8*)(lA + (wm + fr) * 72 + kk + kg);
      bf16x8 b0 = *(const bf16x8*)(lB + (wn + fr) * 72 + kk + kg);
      bf16x8 b1 = *(const bf16x8*)(lB + (wn + 16 + fr) * 72 + kk + kg);
      acc[0] = __builtin_amdgcn_mfma_f32_16x16x32_bf16(af, b0, acc[0], 0, 0, 0);
      acc[1] = __builtin_amdgcn_mfma_f32_16x16x32_bf16(af, b1, acc[1], 0, 0, 0);
    }
  }
  const int rg = (lane >> 4) * 4;
  #pragma unroll
  for (int j = 0; j < 2; ++j) {
    int col = wn + j * 16 + fr;
    if (col >= 56) continue;
    #pragma unroll
    for (int r = 0; r < 4; ++r) {
      int row = wm + rg + r;
      pbuf[((size_t)ks * M_ + m0 + row) * 56 + col] = acc[j][r];
    }
  }
}

// ---------------- LayerNorm ----------------
__global__ __launch_bounds__(384)
void k_ln(const float* __restrict__ x, const float* __restrict__ g,
          const float* __restrict__ bt, u16* __restrict__ h) {
  const int m = blockIdx.x, d = threadIdx.x;
  __shared__ float red[12];
  float v = x[(size_t)m * D_ + d];
  float s = v, s2 = v * v;
  #pragma unroll
  for (int o = 32; o > 0; o >>= 1) { s += __shfl_xor(s, o); s2 += __shfl_xor(s2, o); }
  int wid = d >> 6;
  if ((d & 63) == 0) { red[wid] = s; red[6 + wid] = s2; }
  __syncthreads();
  float ts = 0.f, ts2 = 0.f;
  #pragma unroll
  for (int w = 0; w < 6; ++w) { ts += red[w]; ts2 += red[6 + w]; }
  float mu = ts / (float)D_;
  float var = ts2 / (float)D_ - mu * mu;
  float rs = rsqrtf(var + 1e-5f);
  h[(size_t)m * D_ + d] = f2bf((v - mu) * rs * g[d] + bt[d]);
}

// ---------------- conv + SiLU ----------------
__global__ __launch_bounds__(256)
void k_conv(const u16* __restrict__ xzb, const float* __restrict__ cw,
            const float* __restrict__ cb, u16* __restrict__ xcb) {
  int idx = blockIdx.x * 256 + threadIdx.x;
  if (idx >= M_ * (DI_ / 4)) return;
  int dq = idx % (DI_ / 4), m = idx / (DI_ / 4), l = m % L_;
  int di4 = dq * 4;
  const u16* base = xzb + (size_t)m * 1536 + di4;
  float xv[4][4];
  #pragma unroll
  for (int t = 0; t < 4; ++t) {
    int back = 3 - t;
    u16x4 v = {};
    if (l >= back) v = *(const u16x4*)(base - (size_t)back * 1536);
    #pragma unroll
    for (int c = 0; c < 4; ++c) xv[t][c] = bf2f(v[c]);
  }
  f32x4 bv = *(const f32x4*)(cb + di4);
  u16x4 outv;
  #pragma unroll
  for (int c = 0; c < 4; ++c) {
    f32x4 w = *(const f32x4*)(cw + (size_t)(di4 + c) * 4);
    float acc = bv[c] + w[0] * xv[0][c] + w[1] * xv[1][c] + w[2] * xv[2][c] + w[3] * xv[3][c];
    float s = acc / (1.f + __expf(-acc));
    outv[c] = f2bf(s);
  }
  *(u16x4*)(xcb + (size_t)m * DI_ + di4) = outv;
}

// ---------------- pass 1: per-segment state only (h_end, scum_end) ----------------
// grid (B_, DI_/64, NSEG-1). No y computation, no ys materialization.
__global__ __launch_bounds__(256)
void k_scan_state(const float* __restrict__ pbuf, const u16* __restrict__ xcb,
                  const float* __restrict__ dtw, const float* __restrict__ dtb,
                  const float* __restrict__ Abuf, float* __restrict__ hend,
                  float* __restrict__ send) {
  const int b   = blockIdx.x;
  const int di0 = blockIdx.y * 64;
  const int s   = blockIdx.z;
  const int tid = threadIdx.x;
  const int dil = tid >> 2, nq = tid & 3;
  const int di  = di0 + dil;
  __shared__ float sDT[SEG][64];
  __shared__ float sXC[SEG][64];
  __shared__ float sB [SEG][16];
  __shared__ float sdb[SEG][28];

  const f32x4 Arow = *(const f32x4*)(Abuf + (size_t)di * NST + nq * 4);
  const size_t mb = (size_t)b * L_ + (size_t)s * SEG;
  const int chd = tid & 63;

  {
    int r = tid >> 4, cc = (tid & 15) * 4;
    #pragma unroll
    for (int j = 0; j < 2; ++j) {
      int row = r + j * 16;
      if (row < SEG) {
        u16x4 xv = *(const u16x4*)(xcb + (mb + row) * DI_ + di0 + cc);
        f32x4 xf;
        #pragma unroll
        for (int q = 0; q < 4; ++q) xf[q] = bf2f(xv[q]);
        *(f32x4*)&sXC[row][cc] = xf;
      }
    }
    if (tid < SEG * 6) {
      int row = tid / 6, c4 = (tid % 6) * 4;
      f32x4 ssum = {};
      #pragma unroll
      for (int ks = 0; ks < 4; ++ks)
        ssum += *(const f32x4*)(pbuf + ((size_t)ks * M_ + mb + row) * 56 + c4);
      *(f32x4*)&sdb[row][c4] = ssum;
    }
    if (tid < SEG * 4) {
      int row = tid >> 2, c4 = (tid & 3) * 4;
      f32x4 ssum = {};
      #pragma unroll
      for (int ks = 0; ks < 4; ++ks)
        ssum += *(const f32x4*)(pbuf + ((size_t)ks * M_ + mb + row) * 56 + 24 + c4);
      *(f32x4*)&sB[row][c4] = ssum;
    }
  }
  float w[24];
  #pragma unroll
  for (int r = 0; r < 24; ++r) w[r] = dtw[r * DI_ + di0 + chd];
  const float bvd = dtb[di0 + chd];
  __syncthreads();

  {
    const int rg = tid >> 6;
    #pragma unroll
    for (int rr = 0; rr < 7; ++rr) {
      int row = rg * 7 + rr;
      float acc = bvd;
      #pragma unroll
      for (int r4 = 0; r4 < 6; ++r4) {
        f32x4 sv = *(const f32x4*)&sdb[row][r4 * 4];
        acc += sv[0] * w[r4 * 4] + sv[1] * w[r4 * 4 + 1]
             + sv[2] * w[r4 * 4 + 2] + sv[3] * w[r4 * 4 + 3];
      }
      float e  = __expf(-fabsf(acc));
      sDT[row][chd] = fmaxf(acc, 0.f) + __logf(1.f + e);
    }
  }
  __syncthreads();

  float h[4] = {0.f, 0.f, 0.f, 0.f};
  float scum = 0.f;
  float dtc = sDT[0][dil], xcc = sXC[0][dil];
  f32x4 Bv = *(const f32x4*)&sB[0][nq * 4];
  #pragma unroll 4
  for (int t = 0; t < SEG; ++t) {
    float dtn = 0.f, xcn = 0.f; f32x4 Bn = {};
    if (t + 1 < SEG) {
      dtn = sDT[t + 1][dil]; xcn = sXC[t + 1][dil];
      Bn = *(const f32x4*)&sB[t + 1][nq * 4];
    }
    scum += dtc;
    float dxv = dtc * xcc;
    #pragma unroll
    for (int n = 0; n < 4; ++n) {
      float e = __expf(dtc * Arow[n]);
      h[n] = e * h[n] + dxv * Bv[n];
    }
    dtc = dtn; xcc = xcn; Bv = Bn;
  }

  size_t sb = ((size_t)s * B_ + b) * DI_ + di;
  *(f32x4*)(hend + sb * 16 + nq * 4) = f32x4{h[0], h[1], h[2], h[3]};
  if (nq == 0) send[sb] = scum;
}

// ---------------- pass 2: full scan with carry-in + gate -> ybuf ----------------
// grid (B_, DI_/64, NSEG). h initialized from combined hend/send of segments < s.
__global__ __launch_bounds__(256)
void k_scan_full(const float* __restrict__ pbuf, const u16* __restrict__ xcb,
                 const u16* __restrict__ xzb, const float* __restrict__ dtw,
                 const float* __restrict__ dtb, const float* __restrict__ Abuf,
                 const float* __restrict__ Dsk, const float* __restrict__ hend,
                 const float* __restrict__ send, u16* __restrict__ yb) {
  const int b   = blockIdx.x;
  const int di0 = blockIdx.y * 64;
  const int s   = blockIdx.z;
  const int tid = threadIdx.x;
  const int dil = tid >> 2, nq = tid & 3;
  const int di  = di0 + dil;
  __shared__ float sDT[SEG][64];
  __shared__ float sXC[SEG][64];
  __shared__ float sBC[SEG][32];
  __shared__ float sdb[SEG][28];
  __shared__ float sYO[SEG][64];

  const f32x4 Arow = *(const f32x4*)(Abuf + (size_t)di * NST + nq * 4);
  const float Dv = Dsk[di];
  const size_t mb = (size_t)b * L_ + (size_t)s * SEG;
  const int chd = tid & 63;

  // staging (LDS writes) — issued first so they overlap the carry combine
  {
    int r = tid >> 4, cc = (tid & 15) * 4;
    #pragma unroll
    for (int j = 0; j < 2; ++j) {
      int row = r + j * 16;
      if (row < SEG) {
        u16x4 xv = *(const u16x4*)(xcb + (mb + row) * DI_ + di0 + cc);
        f32x4 xf;
        #pragma unroll
        for (int q = 0; q < 4; ++q) xf[q] = bf2f(xv[q]);
        *(f32x4*)&sXC[row][cc] = xf;
      }
    }
    if (tid < SEG * 6) {
      int row = tid / 6, c4 = (tid % 6) * 4;
      f32x4 ssum = {};
      #pragma unroll
      for (int ks = 0; ks < 4; ++ks)
        ssum += *(const f32x4*)(pbuf + ((size_t)ks * M_ + mb + row) * 56 + c4);
      *(f32x4*)&sdb[row][c4] = ssum;
    }
    if (tid < SEG * 8) {
      int row = tid >> 3, c4 = (tid & 7) * 4;
      f32x4 ssum = {};
      #pragma unroll
      for (int ks = 0; ks < 4; ++ks)
        ssum += *(const f32x4*)(pbuf + ((size_t)ks * M_ + mb + row) * 56 + 24 + c4);
      *(f32x4*)&sBC[row][c4] = ssum;
    }
  }

  // carry-in combine (registers + global reads only)
  float h[4] = {0.f, 0.f, 0.f, 0.f};
  for (int r = 0; r < s; ++r) {
    size_t sb = ((size_t)r * B_ + b) * DI_ + di;
    f32x4 he = *(const f32x4*)(hend + sb * 16 + nq * 4);
    float se = send[sb];
    #pragma unroll
    for (int q = 0; q < 4; ++q) h[q] = __expf(Arow[q] * se) * h[q] + he[q];
  }

  float w[24];
  #pragma unroll
  for (int r = 0; r < 24; ++r) w[r] = dtw[r * DI_ + di0 + chd];
  const float bvd = dtb[di0 + chd];
  __syncthreads();

  {
    const int rg = tid >> 6;
    #pragma unroll
    for (int rr = 0; rr < 7; ++rr) {
      int row = rg * 7 + rr;
      float acc = bvd;
      #pragma unroll
      for (int r4 = 0; r4 < 6; ++r4) {
        f32x4 sv = *(const f32x4*)&sdb[row][r4 * 4];
        acc += sv[0] * w[r4 * 4] + sv[1] * w[r4 * 4 + 1]
             + sv[2] * w[r4 * 4 + 2] + sv[3] * w[r4 * 4 + 3];
      }
      float e  = __expf(-fabsf(acc));
      sDT[row][chd] = fmaxf(acc, 0.f) + __logf(1.f + e);
    }
  }
  __syncthreads();

  float dtc = sDT[0][dil], xcc = sXC[0][dil];
  f32x4 Bv = *(const f32x4*)&sBC[0][nq * 4];
  f32x4 Cv = *(const f32x4*)&sBC[0][16 + nq * 4];
  #pragma unroll 4
  for (int t = 0; t < SEG; ++t) {
    float dtn = 0.f, xcn = 0.f; f32x4 Bn = {}, Cn = {};
    if (t + 1 < SEG) {
      dtn = sDT[t + 1][dil]; xcn = sXC[t + 1][dil];
      Bn = *(const f32x4*)&sBC[t + 1][nq * 4];
      Cn = *(const f32x4*)&sBC[t + 1][16 + nq * 4];
    }
    float dxv = dtc * xcc;
    float y = (nq == 0) ? Dv * xcc : 0.f;
    #pragma unroll
    for (int n = 0; n < 4; ++n) {
      float e = __expf(dtc * Arow[n]);
      h[n] = e * h[n] + dxv * Bv[n];
      y += h[n] * Cv[n];
    }
    y = quad_sum(y);
    if (nq == 0) sYO[t][dil] = y;
    dtc = dtn; xcc = xcn; Bv = Bn; Cv = Cn;
  }
  __syncthreads();

  // gate + pack (coalesced u32 writes)
  #pragma unroll
  for (int j = 0; j < 4; ++j) {
    int id = tid + j * 256;
    if (id < SEG * 32) {
      int row = id >> 5, c2 = id & 31;
      int ch0 = c2 * 2;
      float y0 = sYO[row][ch0], y1 = sYO[row][ch0 + 1];
      u32 zz = *(const u32*)(xzb + (mb + row) * 1536 + DI_ + di0 + ch0);
      float z0 = bf2f((u16)(zz & 0xffff)), z1 = bf2f((u16)(zz >> 16));
      u32 o = (u32)f2bf(y0 * z0 / (1.f + __expf(-z0)))
            | ((u32)f2bf(y1 * z1 / (1.f + __expf(-z1))) << 16);
      *((u32*)yb + ((mb + row) * DI_ + di0) / 2 + c2) = o;
    }
  }
}

// ---------------- final LN partial sums ----------------
__global__ __launch_bounds__(384)
void k_feat_part(const float* __restrict__ x, float* __restrict__ partial) {
  const int b = blockIdx.x, j = blockIdx.y, d = threadIdx.x;
  __shared__ float red[12];
  const int l0 = j * 28;
  float acc = 0.f;
  float v = x[((size_t)b * L_ + l0) * D_ + d];
  for (int l = l0; l < l0 + 28; ++l) {
    float vn = (l + 1 < l0 + 28) ? x[((size_t)b * L_ + l + 1) * D_ + d] : 0.f;
    float s = v, s2 = v * v;
    #pragma unroll
    for (int o = 32; o > 0; o >>= 1) { s += __shfl_xor(s, o); s2 += __shfl_xor(s2, o); }
    int wid = d >> 6;
    if ((d & 63) == 0) { red[wid] = s; red[6 + wid] = s2; }
    __syncthreads();
    float ts = 0.f, ts2 = 0.f;
    #pragma unroll
    for (int w = 0; w < 6; ++w) { ts += red[w]; ts2 += red[6 + w]; }
    float mu = ts * (1.f / (float)D_);
    float var = ts2 * (1.f / (float)D_) - mu * mu;
    acc += (v - mu) * rsqrtf(var + 1e-5f);
    __syncthreads();
    v = vn;
  }
  partial[((size_t)(b * 7 + j)) * D_ + d] = acc;
}

// ---------------- head ----------------
__global__ __launch_bounds__(256)
void k_head(const float* __restrict__ partial, const float* __restrict__ g,
            const float* __restrict__ bt, const float* __restrict__ hw,
            const float* __restrict__ hb, float* __restrict__ out) {
  const int b = blockIdx.y;
  const int c = blockIdx.x * 256 + threadIdx.x;
  __shared__ float sf[D_];
  for (int i = threadIdx.x; i < D_; i += 256) {
    float s = 0.f;
    #pragma unroll
    for (int j = 0; j < 7; ++j) s += partial[((size_t)(b * 7 + j)) * D_ + i];
    sf[i] = g[i] * (s * (1.f / (float)L_)) + bt[i];
  }
  __syncthreads();
  if (c >= NC_) return;
  float acc = hb[c];
  for (int d = 0; d < D_; ++d) acc += sf[d] * hw[(size_t)d * NC_ + c];
  out[(size_t)b * NC_ + c] = acc;
}

// =====================================================================
extern "C" void kernel_launch(void* const* d_in, const int* in_sizes, int n_in,
                              void* d_out, int out_size, void* d_ws, size_t ws_size,
                              hipStream_t stream) {
  const float* x_in    = (const float*)d_in[0];
  const float* patch_w = (const float*)d_in[1];
  const float* patch_b = (const float*)d_in[2];
  const float* pos     = (const float*)d_in[3];
  const float* bn_g    = (const float*)d_in[4];
  const float* bn_b    = (const float*)d_in[5];
  const float* in_w    = (const float*)d_in[6];
  const float* conv_w  = (const float*)d_in[7];
  const float* conv_b  = (const float*)d_in[8];
  const float* xp_w    = (const float*)d_in[9];
  const float* dtp_w   = (const float*)d_in[10];
  const float* dtp_b   = (const float*)d_in[11];
  const float* A_log   = (const float*)d_in[12];
  const float* D_skip  = (const float*)d_in[13];
  const float* out_w   = (const float*)d_in[14];
  const float* norm_g  = (const float*)d_in[15];
  const float* norm_b  = (const float*)d_in[16];
  const float* head_w  = (const float*)d_in[17];
  const float* head_b  = (const float*)d_in[18];
  float* out = (float*)d_out;

  char* ws = (char*)d_ws;
  size_t off = 0;
  auto alloc = [&](size_t bytes) { size_t o = off; off += (bytes + 255) & ~(size_t)255; return o; };

  float* xbuf   = (float*)(ws + alloc((size_t)M_ * D_ * 4));
  u16*   hbuf   = (u16*)  (ws + alloc((size_t)M_ * D_ * 2));
  u16*   xzb    = (u16*)  (ws + alloc((size_t)M_ * 1536 * 2));
  u16*   xcbb   = (u16*)  (ws + alloc((size_t)M_ * DI_ * 2));
  float* pbuf   = (float*)(ws + alloc((size_t)4 * M_ * 56 * 4));
  u16*   im2col = (u16*)  (ws + alloc((size_t)M_ * 768 * 2));
  u16*   ybuf   = (u16*)  (ws + alloc((size_t)M_ * DI_ * 2));
  float* hend   = (float*)(ws + alloc((size_t)NSEG * B_ * DI_ * NST * 4));
  float* send   = (float*)(ws + alloc((size_t)NSEG * B_ * DI_ * 4));
  float* Abuf   = (float*)(ws + alloc((size_t)DEPTH * DI_ * NST * 4));
  float* partial= (float*)(ws + alloc((size_t)B_ * 7 * D_ * 4));
  u16*   in_wT  = (u16*)  (ws + alloc((size_t)DEPTH * 1536 * D_ * 2));
  u16*   xp_wT  = (u16*)  (ws + alloc((size_t)DEPTH * 56 * DI_ * 2));
  u16*   out_wT = (u16*)  (ws + alloc((size_t)DEPTH * D_ * DI_ * 2));
  u16*   pw_b   = (u16*)  (ws + alloc((size_t)D_ * 768 * 2));

  dim3 tb(32, 8);
  k_transpose_bf16<<<dim3(48, 12, DEPTH), tb, 0, stream>>>(in_w,  in_wT,  D_, 1536);
  k_transpose_bf16<<<dim3(2, 24, DEPTH),  tb, 0, stream>>>(xp_w,  xp_wT,  DI_, 56);
  k_transpose_bf16<<<dim3(12, 24, DEPTH), tb, 0, stream>>>(out_w, out_wT, DI_, D_);
  k_convert_bf16<<<(D_ * 768 + 255) / 256, 256, 0, stream>>>(patch_w, pw_b, D_ * 768);
  k_prepA<<<(DEPTH * DI_ * NST + 255) / 256, 256, 0, stream>>>(A_log, Abuf, DEPTH * DI_ * NST);

  k_im2col<<<(M_ * 768 + 255) / 256, 256, 0, stream>>>(x_in, im2col);
  k_gemm<64,64,2,0><<<dim3(M_ / 64, 6), 256, 0, stream>>>(im2col, pw_b, xbuf, D_, 768, patch_b, pos);

  for (int dp = 0; dp < DEPTH; ++dp) {
    const u16* iwt = in_wT  + (size_t)dp * 1536 * D_;
    const u16* xwt = xp_wT  + (size_t)dp * 56 * DI_;
    const u16* owt = out_wT + (size_t)dp * D_ * DI_;
    const float* Al = Abuf + (size_t)dp * DI_ * NST;
    const float* dw = dtp_w + (size_t)dp * R_ * DI_;
    const float* db = dtp_b + dp * DI_;
    k_ln<<<M_, 384, 0, stream>>>(xbuf, bn_g + dp * D_, bn_b + dp * D_, hbuf);
    k_gemm<64,128,0,1><<<dim3(M_ / 64, 12), 256, 0, stream>>>(hbuf, iwt, (float*)xzb, 1536, D_, nullptr, nullptr);
    k_conv<<<(M_ * (DI_ / 4) + 255) / 256, 256, 0, stream>>>(xzb, conv_w + (size_t)dp * DI_ * 4,
                                                             conv_b + dp * DI_, xcbb);
    k_xp_split<<<dim3(M_ / 32, 4), 256, 0, stream>>>(xcbb, xwt, pbuf);
    k_scan_state<<<dim3(B_, DI_ / 64, NSEG - 1), 256, 0, stream>>>(pbuf, xcbb, dw, db, Al,
                                                                   hend, send);
    k_scan_full<<<dim3(B_, DI_ / 64, NSEG), 256, 0, stream>>>(pbuf, xcbb, xzb, dw, db, Al,
                                                              D_skip + dp * DI_, hend, send, ybuf);
    k_gemm<64,64,1,0><<<dim3(M_ / 64, 6), 256, 0, stream>>>(ybuf, owt, xbuf, D_, DI_, nullptr, nullptr);
  }

  k_feat_part<<<dim3(B_, 7), 384, 0, stream>>>(xbuf, partial);
  k_head<<<dim3((NC_ + 255) / 256, B_), 256, 0, stream>>>(partial, norm_g, norm_b, head_w, head_b, out);
}

// Round 13
// 1337.623 us; speedup vs baseline: 1.4883x; 1.0251x over previous
//
#include <hip/hip_runtime.h>
#include <math.h>

typedef short bf16x8 __attribute__((ext_vector_type(8)));
typedef float f32x4 __attribute__((ext_vector_type(4)));
typedef float f32x2 __attribute__((ext_vector_type(2)));
typedef unsigned short u16;
typedef unsigned int u32;
typedef unsigned short u16x4 __attribute__((ext_vector_type(4)));

#define B_    32
#define D_    384
#define DEPTH 12
#define NST   16
#define DI_   768
#define R_    24
#define L_    196
#define NC_   1000
#define M_    (B_*L_)   // 6272
#define SEG   28
#define NSEG  7

__device__ __forceinline__ u16 f2bf(float f) {
  union { float f; unsigned u; } v; v.f = f;
  unsigned r = v.u + 0x7fffu + ((v.u >> 16) & 1u);
  return (u16)(r >> 16);
}
__device__ __forceinline__ float bf2f(u16 x) {
  union { unsigned u; float f; } v; v.u = ((unsigned)x) << 16;
  return v.f;
}
__device__ __forceinline__ float quad_sum(float y) {
  y += __int_as_float(__builtin_amdgcn_update_dpp(0, __float_as_int(y), 0xB1, 0xf, 0xf, true));
  y += __int_as_float(__builtin_amdgcn_update_dpp(0, __float_as_int(y), 0x4E, 0xf, 0xf, true));
  return y;
}
__device__ __forceinline__ float exp2fast(float x) {
  return __builtin_amdgcn_exp2f(x);     // v_exp_f32 (2^x) directly
}

// ---------------- weight prep ----------------
__global__ void k_transpose_bf16(const float* __restrict__ in, u16* __restrict__ out,
                                 int R, int C) {
  __shared__ float tile[32][33];
  const size_t zoff = (size_t)blockIdx.z * R * C;
  in  += zoff; out += zoff;
  int c0 = blockIdx.x * 32, r0 = blockIdx.y * 32;
  int tx = threadIdx.x, ty = threadIdx.y;
  for (int i = ty; i < 32; i += 8) {
    int r = r0 + i, c = c0 + tx;
    tile[i][tx] = (r < R && c < C) ? in[(size_t)r * C + c] : 0.f;
  }
  __syncthreads();
  for (int i = ty; i < 32; i += 8) {
    int c = c0 + i, r = r0 + tx;
    if (c < C && r < R) out[(size_t)c * R + r] = f2bf(tile[tx][i]);
  }
}

__global__ void k_convert_bf16(const float* __restrict__ in, u16* __restrict__ out, int n) {
  int i = blockIdx.x * 256 + threadIdx.x;
  if (i < n) out[i] = f2bf(in[i]);
}

// A2 = -exp(A_log) * log2(e)  (fold the exp->exp2 conversion once)
__global__ void k_prepA(const float* __restrict__ alog, float* __restrict__ A, int n) {
  int i = blockIdx.x * 256 + threadIdx.x;
  if (i < n) A[i] = -__expf(alog[i]) * 1.44269504088896340736f;
}

// ---------------- im2col ----------------
__global__ void k_im2col(const float* __restrict__ x, u16* __restrict__ xcol) {
  int idx = blockIdx.x * 256 + threadIdx.x;
  if (idx >= M_ * 768) return;
  int k = idx % 768, m = idx / 768;
  int b = m / L_, l = m % L_;
  int li = l / 14, lj = l % 14;
  int c = k / 256, r = k % 256;
  int i = r / 16, j = r % 16;
  int hh = li * 16 + i, ww = lj * 16 + j;
  xcol[idx] = f2bf(x[(((size_t)b * 3 + c) * 224 + hh) * 224 + ww]);
}

// ---------------- GEMM (software-pipelined) ----------------
template<int BM, int BN, int EPI, int OB>
__global__ __launch_bounds__(256)
void k_gemm(const u16* __restrict__ A, const u16* __restrict__ BT,
            float* __restrict__ Cout, int Nn, int Kk,
            const float* __restrict__ bias, const float* __restrict__ pos) {
  const int m0 = blockIdx.x * BM;
  const int n0 = blockIdx.y * BN;
  __shared__ u16 lA[BM * 72];
  __shared__ u16 lB[BN * 72];
  const int tid  = threadIdx.x;
  const int wave = tid >> 6, lane = tid & 63;
  const int wm = (wave >> 1) * (BM / 2), wn = (wave & 1) * (BN / 2);
  constexpr int MI = BM / 32, NJ = BN / 32;
  constexpr int NV = (BM + BN) / 32;
  f32x4 acc[MI][NJ] = {};
  const int fr = lane & 15, kg = (lane >> 4) * 8;

  bf16x8 v[NV];
  auto load = [&](int k0) {
    #pragma unroll
    for (int q = 0; q < NV; ++q) {
      int id = tid + q * 256;
      int row = id >> 3, vv = id & 7;
      bf16x8 t = {};
      if (row < BM) {
        t = *(const bf16x8*)(A + (size_t)(m0 + row) * Kk + k0 + vv * 8);
      } else {
        int br = n0 + row - BM;
        if (br < Nn) t = *(const bf16x8*)(BT + (size_t)br * Kk + k0 + vv * 8);
      }
      v[q] = t;
    }
  };
  load(0);
  for (int k0 = 0; k0 < Kk; k0 += 64) {
    __syncthreads();
    #pragma unroll
    for (int q = 0; q < NV; ++q) {
      int id = tid + q * 256;
      int row = id >> 3, vv = id & 7;
      u16* dst = (row < BM) ? (lA + row * 72 + vv * 8) : (lB + (size_t)(row - BM) * 72 + vv * 8);
      *(bf16x8*)dst = v[q];
    }
    __syncthreads();
    if (k0 + 64 < Kk) load(k0 + 64);
    #pragma unroll
    for (int kk = 0; kk < 64; kk += 32) {
      bf16x8 af[MI], bfr[NJ];
      #pragma unroll
      for (int i = 0; i < MI; ++i)
        af[i] = *(const bf16x8*)(lA + (wm + i * 16 + fr) * 72 + kk + kg);
      #pragma unroll
      for (int j = 0; j < NJ; ++j)
        bfr[j] = *(const bf16x8*)(lB + (wn + j * 16 + fr) * 72 + kk + kg);
      #pragma unroll
      for (int i = 0; i < MI; ++i)
        #pragma unroll
        for (int j = 0; j < NJ; ++j)
          acc[i][j] = __builtin_amdgcn_mfma_f32_16x16x32_bf16(af[i], bfr[j], acc[i][j], 0, 0, 0);
    }
  }

  const int rg = (lane >> 4) * 4;
  #pragma unroll
  for (int i = 0; i < MI; ++i) {
    int row = m0 + wm + i * 16 + rg;
    #pragma unroll
    for (int j = 0; j < NJ; ++j) {
      int col = n0 + wn + j * 16 + fr;
      if (col >= Nn) continue;
      #pragma unroll
      for (int r = 0; r < 4; ++r) {
        float vv = acc[i][j][r];
        size_t idx = (size_t)(row + r) * Nn + col;
        if (EPI == 0) {
          if (OB) ((u16*)Cout)[idx] = f2bf(vv);
          else    Cout[idx] = vv;
        }
        else if (EPI == 1) Cout[idx] += vv;
        else               Cout[idx] = vv + bias[col] + pos[(size_t)((row + r) % L_) * Nn + col];
      }
    }
  }
}

// ---------------- xp skinny GEMM, K-split x4 ----------------
__global__ __launch_bounds__(256)
void k_xp_split(const u16* __restrict__ A, const u16* __restrict__ BT,
                float* __restrict__ pbuf) {
  const int m0 = blockIdx.x * 32;
  const int ks = blockIdx.y;
  __shared__ u16 lA[32 * 72];
  __shared__ u16 lB[64 * 72];
  const int tid  = threadIdx.x;
  const int wave = tid >> 6, lane = tid & 63;
  const int wm = (wave >> 1) * 16, wn = (wave & 1) * 32;
  const int fr = lane & 15, kg = (lane >> 4) * 8;
  f32x4 acc[2] = {};

  bf16x8 v[3];
  auto load = [&](int k0) {
    #pragma unroll
    for (int q = 0; q < 3; ++q) {
      int id = tid + q * 256;
      int row = id >> 3, vv = id & 7;
      bf16x8 t = {};
      if (row < 32) {
        t = *(const bf16x8*)(A + (size_t)(m0 + row) * DI_ + k0 + vv * 8);
      } else {
        int br = row - 32;
        if (br < 56) t = *(const bf16x8*)(BT + (size_t)br * DI_ + k0 + vv * 8);
      }
      v[q] = t;
    }
  };
  const int kbase = ks * 192;
  load(kbase);
  for (int k0 = kbase; k0 < kbase + 192; k0 += 64) {
    __syncthreads();
    #pragma unroll
    for (int q = 0; q < 3; ++q) {
      int id = tid + q * 256;
      int row = id >> 3, vv = id & 7;
      u16* dst = (row < 32) ? (lA + row * 72 + vv * 8) : (lB + (size_t)(row - 32) * 72 + vv * 8);
      *(bf16x8*)dst = v[q];
    }
    __syncthreads();
    if (k0 + 64 < kbase + 192) load(k0 + 64);
    #pragma unroll
    for (int kk = 0; kk < 64; kk += 32) {
      bf16x8 af = *(const bf16x8*)(lA + (wm + fr) * 72 + kk + kg);
      bf16x8 b0 = *(const bf16x8*)(lB + (wn + fr) * 72 + kk + kg);
      bf16x8 b1 = *(const bf16x8*)(lB + (wn + 16 + fr) * 72 + kk + kg);
      acc[0] = __builtin_amdgcn_mfma_f32_16x16x32_bf16(af, b0, acc[0], 0, 0, 0);
      acc[1] = __builtin_amdgcn_mfma_f32_16x16x32_bf16(af, b1, acc[1], 0, 0, 0);
    }
  }
  const int rg = (lane >> 4) * 4;
  #pragma unroll
  for (int j = 0; j < 2; ++j) {
    int col = wn + j * 16 + fr;
    if (col >= 56) continue;
    #pragma unroll
    for (int r = 0; r < 4; ++r) {
      int row = wm + rg + r;
      pbuf[((size_t)ks * M_ + m0 + row) * 56 + col] = acc[j][r];
    }
  }
}

// ---------------- LayerNorm ----------------
__global__ __launch_bounds__(384)
void k_ln(const float* __restrict__ x, const float* __restrict__ g,
          const float* __restrict__ bt, u16* __restrict__ h) {
  const int m = blockIdx.x, d = threadIdx.x;
  __shared__ float red[12];
  float v = x[(size_t)m * D_ + d];
  float s = v, s2 = v * v;
  #pragma unroll
  for (int o = 32; o > 0; o >>= 1) { s += __shfl_xor(s, o); s2 += __shfl_xor(s2, o); }
  int wid = d >> 6;
  if ((d & 63) == 0) { red[wid] = s; red[6 + wid] = s2; }
  __syncthreads();
  float ts = 0.f, ts2 = 0.f;
  #pragma unroll
  for (int w = 0; w < 6; ++w) { ts += red[w]; ts2 += red[6 + w]; }
  float mu = ts / (float)D_;
  float var = ts2 / (float)D_ - mu * mu;
  float rs = rsqrtf(var + 1e-5f);
  h[(size_t)m * D_ + d] = f2bf((v - mu) * rs * g[d] + bt[d]);
}

// ---------------- conv + SiLU ----------------
__global__ __launch_bounds__(256)
void k_conv(const u16* __restrict__ xzb, const float* __restrict__ cw,
            const float* __restrict__ cb, u16* __restrict__ xcb) {
  int idx = blockIdx.x * 256 + threadIdx.x;
  if (idx >= M_ * (DI_ / 4)) return;
  int dq = idx % (DI_ / 4), m = idx / (DI_ / 4), l = m % L_;
  int di4 = dq * 4;
  const u16* base = xzb + (size_t)m * 1536 + di4;
  float xv[4][4];
  #pragma unroll
  for (int t = 0; t < 4; ++t) {
    int back = 3 - t;
    u16x4 v = {};
    if (l >= back) v = *(const u16x4*)(base - (size_t)back * 1536);
    #pragma unroll
    for (int c = 0; c < 4; ++c) xv[t][c] = bf2f(v[c]);
  }
  f32x4 bv = *(const f32x4*)(cb + di4);
  u16x4 outv;
  #pragma unroll
  for (int c = 0; c < 4; ++c) {
    f32x4 w = *(const f32x4*)(cw + (size_t)(di4 + c) * 4);
    float acc = bv[c] + w[0] * xv[0][c] + w[1] * xv[1][c] + w[2] * xv[2][c] + w[3] * xv[3][c];
    float s = acc / (1.f + __expf(-acc));
    outv[c] = f2bf(s);
  }
  *(u16x4*)(xcb + (size_t)m * DI_ + di4) = outv;
}

// ---------------- pass 1: per-segment state only (h_end, scum_end) ----------------
// grid (B_, DI_/64, NSEG-1). xc staged as bf16; exp via exp2 (A prescaled).
__global__ __launch_bounds__(256)
void k_scan_state(const float* __restrict__ pbuf, const u16* __restrict__ xcb,
                  const float* __restrict__ dtw, const float* __restrict__ dtb,
                  const float* __restrict__ Abuf, float* __restrict__ hend,
                  float* __restrict__ send) {
  const int b   = blockIdx.x;
  const int di0 = blockIdx.y * 64;
  const int s   = blockIdx.z;
  const int tid = threadIdx.x;
  const int dil = tid >> 2, nq = tid & 3;
  const int di  = di0 + dil;
  __shared__ float sDT[SEG][64];
  __shared__ u16   sXC[SEG][64];
  __shared__ float sB [SEG][16];
  __shared__ float sdb[SEG][28];

  const f32x4 Arow = *(const f32x4*)(Abuf + (size_t)di * NST + nq * 4);
  const size_t mb = (size_t)b * L_ + (size_t)s * SEG;
  const int chd = tid & 63;

  {
    int r = tid >> 4, cc = (tid & 15) * 4;
    #pragma unroll
    for (int j = 0; j < 2; ++j) {
      int row = r + j * 16;
      if (row < SEG)
        *(u16x4*)&sXC[row][cc] = *(const u16x4*)(xcb + (mb + row) * DI_ + di0 + cc);
    }
    if (tid < SEG * 6) {
      int row = tid / 6, c4 = (tid % 6) * 4;
      f32x4 ssum = {};
      #pragma unroll
      for (int ks = 0; ks < 4; ++ks)
        ssum += *(const f32x4*)(pbuf + ((size_t)ks * M_ + mb + row) * 56 + c4);
      *(f32x4*)&sdb[row][c4] = ssum;
    }
    if (tid < SEG * 4) {
      int row = tid >> 2, c4 = (tid & 3) * 4;
      f32x4 ssum = {};
      #pragma unroll
      for (int ks = 0; ks < 4; ++ks)
        ssum += *(const f32x4*)(pbuf + ((size_t)ks * M_ + mb + row) * 56 + 24 + c4);
      *(f32x4*)&sB[row][c4] = ssum;
    }
  }
  float w[24];
  #pragma unroll
  for (int r = 0; r < 24; ++r) w[r] = dtw[r * DI_ + di0 + chd];
  const float bvd = dtb[di0 + chd];
  __syncthreads();

  {
    const int rg = tid >> 6;
    #pragma unroll
    for (int rr = 0; rr < 7; ++rr) {
      int row = rg * 7 + rr;
      float acc = bvd;
      #pragma unroll
      for (int r4 = 0; r4 < 6; ++r4) {
        f32x4 sv = *(const f32x4*)&sdb[row][r4 * 4];
        acc += sv[0] * w[r4 * 4] + sv[1] * w[r4 * 4 + 1]
             + sv[2] * w[r4 * 4 + 2] + sv[3] * w[r4 * 4 + 3];
      }
      float e  = __expf(-fabsf(acc));
      sDT[row][chd] = fmaxf(acc, 0.f) + __logf(1.f + e);
    }
  }
  __syncthreads();

  float h[4] = {0.f, 0.f, 0.f, 0.f};
  float scum = 0.f;
  float dtc = sDT[0][dil], xcc = bf2f(sXC[0][dil]);
  f32x4 Bv = *(const f32x4*)&sB[0][nq * 4];
  #pragma unroll 4
  for (int t = 0; t < SEG; ++t) {
    float dtn = 0.f, xcn = 0.f; f32x4 Bn = {};
    if (t + 1 < SEG) {
      dtn = sDT[t + 1][dil]; xcn = bf2f(sXC[t + 1][dil]);
      Bn = *(const f32x4*)&sB[t + 1][nq * 4];
    }
    scum += dtc;
    float dxv = dtc * xcc;
    #pragma unroll
    for (int n = 0; n < 4; ++n) {
      float e = exp2fast(dtc * Arow[n]);
      h[n] = e * h[n] + dxv * Bv[n];
    }
    dtc = dtn; xcc = xcn; Bv = Bn;
  }

  size_t sb = ((size_t)s * B_ + b) * DI_ + di;
  *(f32x4*)(hend + sb * 16 + nq * 4) = f32x4{h[0], h[1], h[2], h[3]};
  if (nq == 0) send[sb] = scum;
}

// ---------------- pass 2: full scan with carry-in + gate -> ybuf ----------------
// grid (B_, DI_/64, NSEG). xc bf16; sdb aliased onto sYO (disjoint lifetimes);
// LDS 21.5 KB -> 7 blocks/CU.
__global__ __launch_bounds__(256)
void k_scan_full(const float* __restrict__ pbuf, const u16* __restrict__ xcb,
                 const u16* __restrict__ xzb, const float* __restrict__ dtw,
                 const float* __restrict__ dtb, const float* __restrict__ Abuf,
                 const float* __restrict__ Dsk, const float* __restrict__ hend,
                 const float* __restrict__ send, u16* __restrict__ yb) {
  const int b   = blockIdx.x;
  const int di0 = blockIdx.y * 64;
  const int s   = blockIdx.z;
  const int tid = threadIdx.x;
  const int dil = tid >> 2, nq = tid & 3;
  const int di  = di0 + dil;
  __shared__ float sDT[SEG][64];
  __shared__ u16   sXC[SEG][64];
  __shared__ float sBC[SEG][32];
  __shared__ float sYO[SEG][64];             // scan-phase output; pre-scan: aliased as sdb
  float (*sdb)[28] = (float(*)[28])&sYO[0][0];  // dt-input scratch (dead before sYO writes)

  const f32x4 Arow = *(const f32x4*)(Abuf + (size_t)di * NST + nq * 4);
  const float Dv = Dsk[di];
  const size_t mb = (size_t)b * L_ + (size_t)s * SEG;
  const int chd = tid & 63;

  // staging (LDS writes) — issued first so they overlap the carry combine
  {
    int r = tid >> 4, cc = (tid & 15) * 4;
    #pragma unroll
    for (int j = 0; j < 2; ++j) {
      int row = r + j * 16;
      if (row < SEG)
        *(u16x4*)&sXC[row][cc] = *(const u16x4*)(xcb + (mb + row) * DI_ + di0 + cc);
    }
    if (tid < SEG * 6) {
      int row = tid / 6, c4 = (tid % 6) * 4;
      f32x4 ssum = {};
      #pragma unroll
      for (int ks = 0; ks < 4; ++ks)
        ssum += *(const f32x4*)(pbuf + ((size_t)ks * M_ + mb + row) * 56 + c4);
      *(f32x4*)&sdb[row][c4] = ssum;
    }
    if (tid < SEG * 8) {
      int row = tid >> 3, c4 = (tid & 7) * 4;
      f32x4 ssum = {};
      #pragma unroll
      for (int ks = 0; ks < 4; ++ks)
        ssum += *(const f32x4*)(pbuf + ((size_t)ks * M_ + mb + row) * 56 + 24 + c4);
      *(f32x4*)&sBC[row][c4] = ssum;
    }
  }

  // carry-in combine (registers + global reads only)
  float h[4] = {0.f, 0.f, 0.f, 0.f};
  for (int r = 0; r < s; ++r) {
    size_t sb = ((size_t)r * B_ + b) * DI_ + di;
    f32x4 he = *(const f32x4*)(hend + sb * 16 + nq * 4);
    float se = send[sb];
    #pragma unroll
    for (int q = 0; q < 4; ++q) h[q] = exp2fast(Arow[q] * se) * h[q] + he[q];
  }

  float w[24];
  #pragma unroll
  for (int r = 0; r < 24; ++r) w[r] = dtw[r * DI_ + di0 + chd];
  const float bvd = dtb[di0 + chd];
  __syncthreads();

  {
    const int rg = tid >> 6;
    #pragma unroll
    for (int rr = 0; rr < 7; ++rr) {
      int row = rg * 7 + rr;
      float acc = bvd;
      #pragma unroll
      for (int r4 = 0; r4 < 6; ++r4) {
        f32x4 sv = *(const f32x4*)&sdb[row][r4 * 4];
        acc += sv[0] * w[r4 * 4] + sv[1] * w[r4 * 4 + 1]
             + sv[2] * w[r4 * 4 + 2] + sv[3] * w[r4 * 4 + 3];
      }
      float e  = __expf(-fabsf(acc));
      sDT[row][chd] = fmaxf(acc, 0.f) + __logf(1.f + e);
    }
  }
  __syncthreads();   // after this barrier sdb is dead; sYO writes may begin

  float dtc = sDT[0][dil], xcc = bf2f(sXC[0][dil]);
  f32x4 Bv = *(const f32x4*)&sBC[0][nq * 4];
  f32x4 Cv = *(const f32x4*)&sBC[0][16 + nq * 4];
  #pragma unroll 4
  for (int t = 0; t < SEG; ++t) {
    float dtn = 0.f, xcn = 0.f; f32x4 Bn = {}, Cn = {};
    if (t + 1 < SEG) {
      dtn = sDT[t + 1][dil]; xcn = bf2f(sXC[t + 1][dil]);
      Bn = *(const f32x4*)&sBC[t + 1][nq * 4];
      Cn = *(const f32x4*)&sBC[t + 1][16 + nq * 4];
    }
    float dxv = dtc * xcc;
    float y = (nq == 0) ? Dv * xcc : 0.f;
    #pragma unroll
    for (int n = 0; n < 4; ++n) {
      float e = exp2fast(dtc * Arow[n]);
      h[n] = e * h[n] + dxv * Bv[n];
      y += h[n] * Cv[n];
    }
    y = quad_sum(y);
    if (nq == 0) sYO[t][dil] = y;
    dtc = dtn; xcc = xcn; Bv = Bn; Cv = Cn;
  }
  __syncthreads();

  // gate + pack (coalesced u32 writes)
  #pragma unroll
  for (int j = 0; j < 4; ++j) {
    int id = tid + j * 256;
    if (id < SEG * 32) {
      int row = id >> 5, c2 = id & 31;
      int ch0 = c2 * 2;
      float y0 = sYO[row][ch0], y1 = sYO[row][ch0 + 1];
      u32 zz = *(const u32*)(xzb + (mb + row) * 1536 + DI_ + di0 + ch0);
      float z0 = bf2f((u16)(zz & 0xffff)), z1 = bf2f((u16)(zz >> 16));
      u32 o = (u32)f2bf(y0 * z0 / (1.f + __expf(-z0)))
            | ((u32)f2bf(y1 * z1 / (1.f + __expf(-z1))) << 16);
      *((u32*)yb + ((mb + row) * DI_ + di0) / 2 + c2) = o;
    }
  }
}

// ---------------- final LN partial sums ----------------
__global__ __launch_bounds__(384)
void k_feat_part(const float* __restrict__ x, float* __restrict__ partial) {
  const int b = blockIdx.x, j = blockIdx.y, d = threadIdx.x;
  __shared__ float red[12];
  const int l0 = j * 28;
  float acc = 0.f;
  float v = x[((size_t)b * L_ + l0) * D_ + d];
  for (int l = l0; l < l0 + 28; ++l) {
    float vn = (l + 1 < l0 + 28) ? x[((size_t)b * L_ + l + 1) * D_ + d] : 0.f;
    float s = v, s2 = v * v;
    #pragma unroll
    for (int o = 32; o > 0; o >>= 1) { s += __shfl_xor(s, o); s2 += __shfl_xor(s2, o); }
    int wid = d >> 6;
    if ((d & 63) == 0) { red[wid] = s; red[6 + wid] = s2; }
    __syncthreads();
    float ts = 0.f, ts2 = 0.f;
    #pragma unroll
    for (int w = 0; w < 6; ++w) { ts += red[w]; ts2 += red[6 + w]; }
    float mu = ts * (1.f / (float)D_);
    float var = ts2 * (1.f / (float)D_) - mu * mu;
    acc += (v - mu) * rsqrtf(var + 1e-5f);
    __syncthreads();
    v = vn;
  }
  partial[((size_t)(b * 7 + j)) * D_ + d] = acc;
}

// ---------------- head ----------------
__global__ __launch_bounds__(256)
void k_head(const float* __restrict__ partial, const float* __restrict__ g,
            const float* __restrict__ bt, const float* __restrict__ hw,
            const float* __restrict__ hb, float* __restrict__ out) {
  const int b = blockIdx.y;
  const int c = blockIdx.x * 256 + threadIdx.x;
  __shared__ float sf[D_];
  for (int i = threadIdx.x; i < D_; i += 256) {
    float s = 0.f;
    #pragma unroll
    for (int j = 0; j < 7; ++j) s += partial[((size_t)(b * 7 + j)) * D_ + i];
    sf[i] = g[i] * (s * (1.f / (float)L_)) + bt[i];
  }
  __syncthreads();
  if (c >= NC_) return;
  float acc = hb[c];
  for (int d = 0; d < D_; ++d) acc += sf[d] * hw[(size_t)d * NC_ + c];
  out[(size_t)b * NC_ + c] = acc;
}

// =====================================================================
extern "C" void kernel_launch(void* const* d_in, const int* in_sizes, int n_in,
                              void* d_out, int out_size, void* d_ws, size_t ws_size,
                              hipStream_t stream) {
  const float* x_in    = (const float*)d_in[0];
  const float* patch_w = (const float*)d_in[1];
  const float* patch_b = (const float*)d_in[2];
  const float* pos     = (const float*)d_in[3];
  const float* bn_g    = (const float*)d_in[4];
  const float* bn_b    = (const float*)d_in[5];
  const float* in_w    = (const float*)d_in[6];
  const float* conv_w  = (const float*)d_in[7];
  const float* conv_b  = (const float*)d_in[8];
  const float* xp_w    = (const float*)d_in[9];
  const float* dtp_w   = (const float*)d_in[10];
  const float* dtp_b   = (const float*)d_in[11];
  const float* A_log   = (const float*)d_in[12];
  const float* D_skip  = (const float*)d_in[13];
  const float* out_w   = (const float*)d_in[14];
  const float* norm_g  = (const float*)d_in[15];
  const float* norm_b  = (const float*)d_in[16];
  const float* head_w  = (const float*)d_in[17];
  const float* head_b  = (const float*)d_in[18];
  float* out = (float*)d_out;

  char* ws = (char*)d_ws;
  size_t off = 0;
  auto alloc = [&](size_t bytes) { size_t o = off; off += (bytes + 255) & ~(size_t)255; return o; };

  float* xbuf   = (float*)(ws + alloc((size_t)M_ * D_ * 4));
  u16*   hbuf   = (u16*)  (ws + alloc((size_t)M_ * D_ * 2));
  u16*   xzb    = (u16*)  (ws + alloc((size_t)M_ * 1536 * 2));
  u16*   xcbb   = (u16*)  (ws + alloc((size_t)M_ * DI_ * 2));
  float* pbuf   = (float*)(ws + alloc((size_t)4 * M_ * 56 * 4));
  u16*   im2col = (u16*)  (ws + alloc((size_t)M_ * 768 * 2));
  u16*   ybuf   = (u16*)  (ws + alloc((size_t)M_ * DI_ * 2));
  float* hend   = (float*)(ws + alloc((size_t)NSEG * B_ * DI_ * NST * 4));
  float* send   = (float*)(ws + alloc((size_t)NSEG * B_ * DI_ * 4));
  float* Abuf   = (float*)(ws + alloc((size_t)DEPTH * DI_ * NST * 4));
  float* partial= (float*)(ws + alloc((size_t)B_ * 7 * D_ * 4));
  u16*   in_wT  = (u16*)  (ws + alloc((size_t)DEPTH * 1536 * D_ * 2));
  u16*   xp_wT  = (u16*)  (ws + alloc((size_t)DEPTH * 56 * DI_ * 2));
  u16*   out_wT = (u16*)  (ws + alloc((size_t)DEPTH * D_ * DI_ * 2));
  u16*   pw_b   = (u16*)  (ws + alloc((size_t)D_ * 768 * 2));

  dim3 tb(32, 8);
  k_transpose_bf16<<<dim3(48, 12, DEPTH), tb, 0, stream>>>(in_w,  in_wT,  D_, 1536);
  k_transpose_bf16<<<dim3(2, 24, DEPTH),  tb, 0, stream>>>(xp_w,  xp_wT,  DI_, 56);
  k_transpose_bf16<<<dim3(12, 24, DEPTH), tb, 0, stream>>>(out_w, out_wT, DI_, D_);
  k_convert_bf16<<<(D_ * 768 + 255) / 256, 256, 0, stream>>>(patch_w, pw_b, D_ * 768);
  k_prepA<<<(DEPTH * DI_ * NST + 255) / 256, 256, 0, stream>>>(A_log, Abuf, DEPTH * DI_ * NST);

  k_im2col<<<(M_ * 768 + 255) / 256, 256, 0, stream>>>(x_in, im2col);
  k_gemm<64,64,2,0><<<dim3(M_ / 64, 6), 256, 0, stream>>>(im2col, pw_b, xbuf, D_, 768, patch_b, pos);

  for (int dp = 0; dp < DEPTH; ++dp) {
    const u16* iwt = in_wT  + (size_t)dp * 1536 * D_;
    const u16* xwt = xp_wT  + (size_t)dp * 56 * DI_;
    const u16* owt = out_wT + (size_t)dp * D_ * DI_;
    const float* Al = Abuf + (size_t)dp * DI_ * NST;
    const float* dw = dtp_w + (size_t)dp * R_ * DI_;
    const float* db = dtp_b + dp * DI_;
    k_ln<<<M_, 384, 0, stream>>>(xbuf, bn_g + dp * D_, bn_b + dp * D_, hbuf);
    k_gemm<64,128,0,1><<<dim3(M_ / 64, 12), 256, 0, stream>>>(hbuf, iwt, (float*)xzb, 1536, D_, nullptr, nullptr);
    k_conv<<<(M_ * (DI_ / 4) + 255) / 256, 256, 0, stream>>>(xzb, conv_w + (size_t)dp * DI_ * 4,
                                                             conv_b + dp * DI_, xcbb);
    k_xp_split<<<dim3(M_ / 32, 4), 256, 0, stream>>>(xcbb, xwt, pbuf);
    k_scan_state<<<dim3(B_, DI_ / 64, NSEG - 1), 256, 0, stream>>>(pbuf, xcbb, dw, db, Al,
                                                                   hend, send);
    k_scan_full<<<dim3(B_, DI_ / 64, NSEG), 256, 0, stream>>>(pbuf, xcbb, xzb, dw, db, Al,
                                                              D_skip + dp * DI_, hend, send, ybuf);
    k_gemm<64,64,1,0><<<dim3(M_ / 64, 6), 256, 0, stream>>>(ybuf, owt, xbuf, D_, DI_, nullptr, nullptr);
  }

  k_feat_part<<<dim3(B_, 7), 384, 0, stream>>>(xbuf, partial);
  k_head<<<dim3((NC_ + 255) / 256, B_), 256, 0, stream>>>(partial, norm_g, norm_b, head_w, head_b, out);
}

// Round 14
// 1325.765 us; speedup vs baseline: 1.5017x; 1.0089x over previous
//
#include <hip/hip_runtime.h>
#include <math.h>

typedef short bf16x8 __attribute__((ext_vector_type(8)));
typedef float f32x4 __attribute__((ext_vector_type(4)));
typedef float f32x2 __attribute__((ext_vector_type(2)));
typedef unsigned short u16;
typedef unsigned int u32;
typedef unsigned short u16x4 __attribute__((ext_vector_type(4)));

#define B_    32
#define D_    384
#define DEPTH 12
#define NST   16
#define DI_   768
#define R_    24
#define L_    196
#define NC_   1000
#define M_    (B_*L_)   // 6272
#define SEG   28
#define NSEG  7

__device__ __forceinline__ u16 f2bf(float f) {
  union { float f; unsigned u; } v; v.f = f;
  unsigned r = v.u + 0x7fffu + ((v.u >> 16) & 1u);
  return (u16)(r >> 16);
}
__device__ __forceinline__ float bf2f(u16 x) {
  union { unsigned u; float f; } v; v.u = ((unsigned)x) << 16;
  return v.f;
}
__device__ __forceinline__ float quad_sum(float y) {
  y += __int_as_float(__builtin_amdgcn_update_dpp(0, __float_as_int(y), 0xB1, 0xf, 0xf, true));
  y += __int_as_float(__builtin_amdgcn_update_dpp(0, __float_as_int(y), 0x4E, 0xf, 0xf, true));
  return y;
}
__device__ __forceinline__ float exp2fast(float x) {
  return __builtin_amdgcn_exp2f(x);
}

// ---------------- weight prep ----------------
__global__ void k_transpose_bf16(const float* __restrict__ in, u16* __restrict__ out,
                                 int R, int C) {
  __shared__ float tile[32][33];
  const size_t zoff = (size_t)blockIdx.z * R * C;
  in  += zoff; out += zoff;
  int c0 = blockIdx.x * 32, r0 = blockIdx.y * 32;
  int tx = threadIdx.x, ty = threadIdx.y;
  for (int i = ty; i < 32; i += 8) {
    int r = r0 + i, c = c0 + tx;
    tile[i][tx] = (r < R && c < C) ? in[(size_t)r * C + c] : 0.f;
  }
  __syncthreads();
  for (int i = ty; i < 32; i += 8) {
    int c = c0 + i, r = r0 + tx;
    if (c < C && r < R) out[(size_t)c * R + r] = f2bf(tile[tx][i]);
  }
}

__global__ void k_convert_bf16(const float* __restrict__ in, u16* __restrict__ out, int n) {
  int i = blockIdx.x * 256 + threadIdx.x;
  if (i < n) out[i] = f2bf(in[i]);
}

// A2 = -exp(A_log) * log2(e)
__global__ void k_prepA(const float* __restrict__ alog, float* __restrict__ A, int n) {
  int i = blockIdx.x * 256 + threadIdx.x;
  if (i < n) A[i] = -__expf(alog[i]) * 1.44269504088896340736f;
}

// ---------------- im2col ----------------
__global__ void k_im2col(const float* __restrict__ x, u16* __restrict__ xcol) {
  int idx = blockIdx.x * 256 + threadIdx.x;
  if (idx >= M_ * 768) return;
  int k = idx % 768, m = idx / 768;
  int b = m / L_, l = m % L_;
  int li = l / 14, lj = l % 14;
  int c = k / 256, r = k % 256;
  int i = r / 16, j = r % 16;
  int hh = li * 16 + i, ww = lj * 16 + j;
  xcol[idx] = f2bf(x[(((size_t)b * 3 + c) * 224 + hh) * 224 + ww]);
}

// ---------------- GEMM (software-pipelined) ----------------
template<int BM, int BN, int EPI, int OB>
__global__ __launch_bounds__(256)
void k_gemm(const u16* __restrict__ A, const u16* __restrict__ BT,
            float* __restrict__ Cout, int Nn, int Kk,
            const float* __restrict__ bias, const float* __restrict__ pos) {
  const int m0 = blockIdx.x * BM;
  const int n0 = blockIdx.y * BN;
  __shared__ u16 lA[BM * 72];
  __shared__ u16 lB[BN * 72];
  const int tid  = threadIdx.x;
  const int wave = tid >> 6, lane = tid & 63;
  const int wm = (wave >> 1) * (BM / 2), wn = (wave & 1) * (BN / 2);
  constexpr int MI = BM / 32, NJ = BN / 32;
  constexpr int NV = (BM + BN) / 32;
  f32x4 acc[MI][NJ] = {};
  const int fr = lane & 15, kg = (lane >> 4) * 8;

  bf16x8 v[NV];
  auto load = [&](int k0) {
    #pragma unroll
    for (int q = 0; q < NV; ++q) {
      int id = tid + q * 256;
      int row = id >> 3, vv = id & 7;
      bf16x8 t = {};
      if (row < BM) {
        t = *(const bf16x8*)(A + (size_t)(m0 + row) * Kk + k0 + vv * 8);
      } else {
        int br = n0 + row - BM;
        if (br < Nn) t = *(const bf16x8*)(BT + (size_t)br * Kk + k0 + vv * 8);
      }
      v[q] = t;
    }
  };
  load(0);
  for (int k0 = 0; k0 < Kk; k0 += 64) {
    __syncthreads();
    #pragma unroll
    for (int q = 0; q < NV; ++q) {
      int id = tid + q * 256;
      int row = id >> 3, vv = id & 7;
      u16* dst = (row < BM) ? (lA + row * 72 + vv * 8) : (lB + (size_t)(row - BM) * 72 + vv * 8);
      *(bf16x8*)dst = v[q];
    }
    __syncthreads();
    if (k0 + 64 < Kk) load(k0 + 64);
    #pragma unroll
    for (int kk = 0; kk < 64; kk += 32) {
      bf16x8 af[MI], bfr[NJ];
      #pragma unroll
      for (int i = 0; i < MI; ++i)
        af[i] = *(const bf16x8*)(lA + (wm + i * 16 + fr) * 72 + kk + kg);
      #pragma unroll
      for (int j = 0; j < NJ; ++j)
        bfr[j] = *(const bf16x8*)(lB + (wn + j * 16 + fr) * 72 + kk + kg);
      #pragma unroll
      for (int i = 0; i < MI; ++i)
        #pragma unroll
        for (int j = 0; j < NJ; ++j)
          acc[i][j] = __builtin_amdgcn_mfma_f32_16x16x32_bf16(af[i], bfr[j], acc[i][j], 0, 0, 0);
    }
  }

  const int rg = (lane >> 4) * 4;
  #pragma unroll
  for (int i = 0; i < MI; ++i) {
    int row = m0 + wm + i * 16 + rg;
    #pragma unroll
    for (int j = 0; j < NJ; ++j) {
      int col = n0 + wn + j * 16 + fr;
      if (col >= Nn) continue;
      #pragma unroll
      for (int r = 0; r < 4; ++r) {
        float vv = acc[i][j][r];
        size_t idx = (size_t)(row + r) * Nn + col;
        if (EPI == 0) {
          if (OB) ((u16*)Cout)[idx] = f2bf(vv);
          else    Cout[idx] = vv;
        }
        else if (EPI == 1) Cout[idx] += vv;
        else               Cout[idx] = vv + bias[col] + pos[(size_t)((row + r) % L_) * Nn + col];
      }
    }
  }
}

// ---------------- fused conv+SiLU + xp skinny GEMM (K-split x4) ----------------
// grid (M_/32, 4). Block computes xc = silu(conv(xz)) for its 32-row x 192-ch
// slice (writes xcb), and the 32x56 partial dbc over that K slice (writes pbuf).
__global__ __launch_bounds__(256)
void k_xp_conv(const u16* __restrict__ xzb, const float* __restrict__ cw,
               const float* __restrict__ cb, const u16* __restrict__ BT,
               u16* __restrict__ xcb, float* __restrict__ pbuf) {
  const int m0  = blockIdx.x * 32;
  const int ks  = blockIdx.y;
  const int ch0 = ks * 192;
  __shared__ u16 sXZ[35][64];
  __shared__ u16 lA[32 * 72];
  __shared__ u16 lB[64 * 72];
  const int tid  = threadIdx.x;
  const int wave = tid >> 6, lane = tid & 63;
  const int wm = (wave >> 1) * 16, wn = (wave & 1) * 32;
  const int fr = lane & 15, kg = (lane >> 4) * 8;
  f32x4 acc[2] = {};

  for (int kc = 0; kc < 3; ++kc) {
    const int c0 = ch0 + kc * 64;
    __syncthreads();                 // protect previous chunk's LDS reads
    // stage B-tile (56 rows x 64 cols of xp_wT slice)
    #pragma unroll
    for (int j = 0; j < 2; ++j) {
      int u = tid + j * 256;
      if (u < 448) {
        int row = u >> 3, vv = u & 7;
        *(bf16x8*)(lB + row * 72 + vv * 8) =
            *(const bf16x8*)(BT + (size_t)row * DI_ + c0 + vv * 8);
      }
    }
    // stage xz taps: rows m0-3..m0+31, cols c0..c0+63
    #pragma unroll
    for (int j = 0; j < 3; ++j) {
      int u = tid + j * 256;
      if (u < 560) {
        int row = u >> 4, c4 = (u & 15) * 4;
        int gm = m0 - 3 + row; if (gm < 0) gm = 0;
        *(u16x4*)&sXZ[row][c4] = *(const u16x4*)(xzb + (size_t)gm * 1536 + c0 + c4);
      }
    }
    __syncthreads();
    // conv + SiLU: 32 rows x 16 groups of 4 channels
    #pragma unroll
    for (int j = 0; j < 2; ++j) {
      int g = tid + j * 256;         // < 512
      int r = g >> 4, c4 = (g & 15) * 4;
      int l = (m0 + r) % L_;
      u16x4 t0 = *(const u16x4*)&sXZ[r + 3][c4];
      u16x4 t1 = (l >= 1) ? *(const u16x4*)&sXZ[r + 2][c4] : u16x4{};
      u16x4 t2 = (l >= 2) ? *(const u16x4*)&sXZ[r + 1][c4] : u16x4{};
      u16x4 t3 = (l >= 3) ? *(const u16x4*)&sXZ[r    ][c4] : u16x4{};
      f32x4 bv = *(const f32x4*)(cb + c0 + c4);
      u16x4 outv;
      #pragma unroll
      for (int c = 0; c < 4; ++c) {
        f32x4 w = *(const f32x4*)(cw + (size_t)(c0 + c4 + c) * 4);
        float a = bv[c] + w[3] * bf2f(t0[c]) + w[2] * bf2f(t1[c])
                        + w[1] * bf2f(t2[c]) + w[0] * bf2f(t3[c]);
        float s = a / (1.f + __expf(-a));
        outv[c] = f2bf(s);
      }
      *(u16x4*)(xcb + (size_t)(m0 + r) * DI_ + c0 + c4) = outv;
      *(u16x4*)(lA + r * 72 + c4) = outv;
    }
    __syncthreads();
    #pragma unroll
    for (int kk = 0; kk < 64; kk += 32) {
      bf16x8 af = *(const bf16x8*)(lA + (wm + fr) * 72 + kk + kg);
      bf16x8 b0 = *(const bf16x8*)(lB + (wn + fr) * 72 + kk + kg);
      bf16x8 b1 = *(const bf16x8*)(lB + (wn + 16 + fr) * 72 + kk + kg);
      acc[0] = __builtin_amdgcn_mfma_f32_16x16x32_bf16(af, b0, acc[0], 0, 0, 0);
      acc[1] = __builtin_amdgcn_mfma_f32_16x16x32_bf16(af, b1, acc[1], 0, 0, 0);
    }
  }
  const int rg = (lane >> 4) * 4;
  #pragma unroll
  for (int j = 0; j < 2; ++j) {
    int col = wn + j * 16 + fr;
    if (col >= 56) continue;
    #pragma unroll
    for (int r = 0; r < 4; ++r) {
      int row = wm + rg + r;
      pbuf[((size_t)ks * M_ + m0 + row) * 56 + col] = acc[j][r];
    }
  }
}

// ---------------- LayerNorm ----------------
__global__ __launch_bounds__(384)
void k_ln(const float* __restrict__ x, const float* __restrict__ g,
          const float* __restrict__ bt, u16* __restrict__ h) {
  const int m = blockIdx.x, d = threadIdx.x;
  __shared__ float red[12];
  float v = x[(size_t)m * D_ + d];
  float s = v, s2 = v * v;
  #pragma unroll
  for (int o = 32; o > 0; o >>= 1) { s += __shfl_xor(s, o); s2 += __shfl_xor(s2, o); }
  int wid = d >> 6;
  if ((d & 63) == 0) { red[wid] = s; red[6 + wid] = s2; }
  __syncthreads();
  float ts = 0.f, ts2 = 0.f;
  #pragma unroll
  for (int w = 0; w < 6; ++w) { ts += red[w]; ts2 += red[6 + w]; }
  float mu = ts / (float)D_;
  float var = ts2 / (float)D_ - mu * mu;
  float rs = rsqrtf(var + 1e-5f);
  h[(size_t)m * D_ + d] = f2bf((v - mu) * rs * g[d] + bt[d]);
}

// ---------------- pass 1: per-segment state only (h_end, scum_end) ----------------
__global__ __launch_bounds__(256)
void k_scan_state(const float* __restrict__ pbuf, const u16* __restrict__ xcb,
                  const float* __restrict__ dtw, const float* __restrict__ dtb,
                  const float* __restrict__ Abuf, float* __restrict__ hend,
                  float* __restrict__ send) {
  const int b   = blockIdx.x;
  const int di0 = blockIdx.y * 64;
  const int s   = blockIdx.z;
  const int tid = threadIdx.x;
  const int dil = tid >> 2, nq = tid & 3;
  const int di  = di0 + dil;
  __shared__ float sDT[SEG][64];
  __shared__ u16   sXC[SEG][64];
  __shared__ float sB [SEG][16];
  __shared__ float sdb[SEG][28];

  const f32x4 Arow = *(const f32x4*)(Abuf + (size_t)di * NST + nq * 4);
  const size_t mb = (size_t)b * L_ + (size_t)s * SEG;
  const int chd = tid & 63;

  {
    int r = tid >> 4, cc = (tid & 15) * 4;
    #pragma unroll
    for (int j = 0; j < 2; ++j) {
      int row = r + j * 16;
      if (row < SEG)
        *(u16x4*)&sXC[row][cc] = *(const u16x4*)(xcb + (mb + row) * DI_ + di0 + cc);
    }
    if (tid < SEG * 6) {
      int row = tid / 6, c4 = (tid % 6) * 4;
      f32x4 ssum = {};
      #pragma unroll
      for (int ks = 0; ks < 4; ++ks)
        ssum += *(const f32x4*)(pbuf + ((size_t)ks * M_ + mb + row) * 56 + c4);
      *(f32x4*)&sdb[row][c4] = ssum;
    }
    if (tid < SEG * 4) {
      int row = tid >> 2, c4 = (tid & 3) * 4;
      f32x4 ssum = {};
      #pragma unroll
      for (int ks = 0; ks < 4; ++ks)
        ssum += *(const f32x4*)(pbuf + ((size_t)ks * M_ + mb + row) * 56 + 24 + c4);
      *(f32x4*)&sB[row][c4] = ssum;
    }
  }
  float w[24];
  #pragma unroll
  for (int r = 0; r < 24; ++r) w[r] = dtw[r * DI_ + di0 + chd];
  const float bvd = dtb[di0 + chd];
  __syncthreads();

  {
    const int rg = tid >> 6;
    #pragma unroll
    for (int rr = 0; rr < 7; ++rr) {
      int row = rg * 7 + rr;
      float acc = bvd;
      #pragma unroll
      for (int r4 = 0; r4 < 6; ++r4) {
        f32x4 sv = *(const f32x4*)&sdb[row][r4 * 4];
        acc += sv[0] * w[r4 * 4] + sv[1] * w[r4 * 4 + 1]
             + sv[2] * w[r4 * 4 + 2] + sv[3] * w[r4 * 4 + 3];
      }
      float e  = __expf(-fabsf(acc));
      sDT[row][chd] = fmaxf(acc, 0.f) + __logf(1.f + e);
    }
  }
  __syncthreads();

  float h[4] = {0.f, 0.f, 0.f, 0.f};
  float scum = 0.f;
  float dtc = sDT[0][dil], xcc = bf2f(sXC[0][dil]);
  f32x4 Bv = *(const f32x4*)&sB[0][nq * 4];
  #pragma unroll 4
  for (int t = 0; t < SEG; ++t) {
    float dtn = 0.f, xcn = 0.f; f32x4 Bn = {};
    if (t + 1 < SEG) {
      dtn = sDT[t + 1][dil]; xcn = bf2f(sXC[t + 1][dil]);
      Bn = *(const f32x4*)&sB[t + 1][nq * 4];
    }
    scum += dtc;
    float dxv = dtc * xcc;
    #pragma unroll
    for (int n = 0; n < 4; ++n) {
      float e = exp2fast(dtc * Arow[n]);
      h[n] = e * h[n] + dxv * Bv[n];
    }
    dtc = dtn; xcc = xcn; Bv = Bn;
  }

  size_t sb = ((size_t)s * B_ + b) * DI_ + di;
  *(f32x4*)(hend + sb * 16 + nq * 4) = f32x4{h[0], h[1], h[2], h[3]};
  if (nq == 0) send[sb] = scum;
}

// ---------------- pass 2: full scan with carry-in + gate -> ybuf ----------------
__global__ __launch_bounds__(256)
void k_scan_full(const float* __restrict__ pbuf, const u16* __restrict__ xcb,
                 const u16* __restrict__ xzb, const float* __restrict__ dtw,
                 const float* __restrict__ dtb, const float* __restrict__ Abuf,
                 const float* __restrict__ Dsk, const float* __restrict__ hend,
                 const float* __restrict__ send, u16* __restrict__ yb) {
  const int b   = blockIdx.x;
  const int di0 = blockIdx.y * 64;
  const int s   = blockIdx.z;
  const int tid = threadIdx.x;
  const int dil = tid >> 2, nq = tid & 3;
  const int di  = di0 + dil;
  __shared__ float sDT[SEG][64];
  __shared__ u16   sXC[SEG][64];
  __shared__ float sBC[SEG][32];
  __shared__ float sYO[SEG][64];
  float (*sdb)[28] = (float(*)[28])&sYO[0][0];

  const f32x4 Arow = *(const f32x4*)(Abuf + (size_t)di * NST + nq * 4);
  const float Dv = Dsk[di];
  const size_t mb = (size_t)b * L_ + (size_t)s * SEG;
  const int chd = tid & 63;

  {
    int r = tid >> 4, cc = (tid & 15) * 4;
    #pragma unroll
    for (int j = 0; j < 2; ++j) {
      int row = r + j * 16;
      if (row < SEG)
        *(u16x4*)&sXC[row][cc] = *(const u16x4*)(xcb + (mb + row) * DI_ + di0 + cc);
    }
    if (tid < SEG * 6) {
      int row = tid / 6, c4 = (tid % 6) * 4;
      f32x4 ssum = {};
      #pragma unroll
      for (int ks = 0; ks < 4; ++ks)
        ssum += *(const f32x4*)(pbuf + ((size_t)ks * M_ + mb + row) * 56 + c4);
      *(f32x4*)&sdb[row][c4] = ssum;
    }
    if (tid < SEG * 8) {
      int row = tid >> 3, c4 = (tid & 7) * 4;
      f32x4 ssum = {};
      #pragma unroll
      for (int ks = 0; ks < 4; ++ks)
        ssum += *(const f32x4*)(pbuf + ((size_t)ks * M_ + mb + row) * 56 + 24 + c4);
      *(f32x4*)&sBC[row][c4] = ssum;
    }
  }

  float h[4] = {0.f, 0.f, 0.f, 0.f};
  for (int r = 0; r < s; ++r) {
    size_t sb = ((size_t)r * B_ + b) * DI_ + di;
    f32x4 he = *(const f32x4*)(hend + sb * 16 + nq * 4);
    float se = send[sb];
    #pragma unroll
    for (int q = 0; q < 4; ++q) h[q] = exp2fast(Arow[q] * se) * h[q] + he[q];
  }

  float w[24];
  #pragma unroll
  for (int r = 0; r < 24; ++r) w[r] = dtw[r * DI_ + di0 + chd];
  const float bvd = dtb[di0 + chd];
  __syncthreads();

  {
    const int rg = tid >> 6;
    #pragma unroll
    for (int rr = 0; rr < 7; ++rr) {
      int row = rg * 7 + rr;
      float acc = bvd;
      #pragma unroll
      for (int r4 = 0; r4 < 6; ++r4) {
        f32x4 sv = *(const f32x4*)&sdb[row][r4 * 4];
        acc += sv[0] * w[r4 * 4] + sv[1] * w[r4 * 4 + 1]
             + sv[2] * w[r4 * 4 + 2] + sv[3] * w[r4 * 4 + 3];
      }
      float e  = __expf(-fabsf(acc));
      sDT[row][chd] = fmaxf(acc, 0.f) + __logf(1.f + e);
    }
  }
  __syncthreads();   // sdb dead; sYO writes may begin

  float dtc = sDT[0][dil], xcc = bf2f(sXC[0][dil]);
  f32x4 Bv = *(const f32x4*)&sBC[0][nq * 4];
  f32x4 Cv = *(const f32x4*)&sBC[0][16 + nq * 4];
  #pragma unroll 4
  for (int t = 0; t < SEG; ++t) {
    float dtn = 0.f, xcn = 0.f; f32x4 Bn = {}, Cn = {};
    if (t + 1 < SEG) {
      dtn = sDT[t + 1][dil]; xcn = bf2f(sXC[t + 1][dil]);
      Bn = *(const f32x4*)&sBC[t + 1][nq * 4];
      Cn = *(const f32x4*)&sBC[t + 1][16 + nq * 4];
    }
    float dxv = dtc * xcc;
    float y = 0.f;
    #pragma unroll
    for (int n = 0; n < 4; ++n) {
      float e = exp2fast(dtc * Arow[n]);
      h[n] = e * h[n] + dxv * Bv[n];
      y += h[n] * Cv[n];
    }
    y = quad_sum(y);
    if (nq == 0) sYO[t][dil] = y + Dv * xcc;
    dtc = dtn; xcc = xcn; Bv = Bn; Cv = Cn;
  }
  __syncthreads();

  #pragma unroll
  for (int j = 0; j < 4; ++j) {
    int id = tid + j * 256;
    if (id < SEG * 32) {
      int row = id >> 5, c2 = id & 31;
      int ch0 = c2 * 2;
      float y0 = sYO[row][ch0], y1 = sYO[row][ch0 + 1];
      u32 zz = *(const u32*)(xzb + (mb + row) * 1536 + DI_ + di0 + ch0);
      float z0 = bf2f((u16)(zz & 0xffff)), z1 = bf2f((u16)(zz >> 16));
      u32 o = (u32)f2bf(y0 * z0 / (1.f + __expf(-z0)))
            | ((u32)f2bf(y1 * z1 / (1.f + __expf(-z1))) << 16);
      *((u32*)yb + ((mb + row) * DI_ + di0) / 2 + c2) = o;
    }
  }
}

// ---------------- final LN partial sums ----------------
__global__ __launch_bounds__(384)
void k_feat_part(const float* __restrict__ x, float* __restrict__ partial) {
  const int b = blockIdx.x, j = blockIdx.y, d = threadIdx.x;
  __shared__ float red[12];
  const int l0 = j * 28;
  float acc = 0.f;
  float v = x[((size_t)b * L_ + l0) * D_ + d];
  for (int l = l0; l < l0 + 28; ++l) {
    float vn = (l + 1 < l0 + 28) ? x[((size_t)b * L_ + l + 1) * D_ + d] : 0.f;
    float s = v, s2 = v * v;
    #pragma unroll
    for (int o = 32; o > 0; o >>= 1) { s += __shfl_xor(s, o); s2 += __shfl_xor(s2, o); }
    int wid = d >> 6;
    if ((d & 63) == 0) { red[wid] = s; red[6 + wid] = s2; }
    __syncthreads();
    float ts = 0.f, ts2 = 0.f;
    #pragma unroll
    for (int w = 0; w < 6; ++w) { ts += red[w]; ts2 += red[6 + w]; }
    float mu = ts * (1.f / (float)D_);
    float var = ts2 * (1.f / (float)D_) - mu * mu;
    acc += (v - mu) * rsqrtf(var + 1e-5f);
    __syncthreads();
    v = vn;
  }
  partial[((size_t)(b * 7 + j)) * D_ + d] = acc;
}

// ---------------- head ----------------
__global__ __launch_bounds__(256)
void k_head(const float* __restrict__ partial, const float* __restrict__ g,
            const float* __restrict__ bt, const float* __restrict__ hw,
            const float* __restrict__ hb, float* __restrict__ out) {
  const int b = blockIdx.y;
  const int c = blockIdx.x * 256 + threadIdx.x;
  __shared__ float sf[D_];
  for (int i = threadIdx.x; i < D_; i += 256) {
    float s = 0.f;
    #pragma unroll
    for (int j = 0; j < 7; ++j) s += partial[((size_t)(b * 7 + j)) * D_ + i];
    sf[i] = g[i] * (s * (1.f / (float)L_)) + bt[i];
  }
  __syncthreads();
  if (c >= NC_) return;
  float acc = hb[c];
  for (int d = 0; d < D_; ++d) acc += sf[d] * hw[(size_t)d * NC_ + c];
  out[(size_t)b * NC_ + c] = acc;
}

// =====================================================================
extern "C" void kernel_launch(void* const* d_in, const int* in_sizes, int n_in,
                              void* d_out, int out_size, void* d_ws, size_t ws_size,
                              hipStream_t stream) {
  const float* x_in    = (const float*)d_in[0];
  const float* patch_w = (const float*)d_in[1];
  const float* patch_b = (const float*)d_in[2];
  const float* pos     = (const float*)d_in[3];
  const float* bn_g    = (const float*)d_in[4];
  const float* bn_b    = (const float*)d_in[5];
  const float* in_w    = (const float*)d_in[6];
  const float* conv_w  = (const float*)d_in[7];
  const float* conv_b  = (const float*)d_in[8];
  const float* xp_w    = (const float*)d_in[9];
  const float* dtp_w   = (const float*)d_in[10];
  const float* dtp_b   = (const float*)d_in[11];
  const float* A_log   = (const float*)d_in[12];
  const float* D_skip  = (const float*)d_in[13];
  const float* out_w   = (const float*)d_in[14];
  const float* norm_g  = (const float*)d_in[15];
  const float* norm_b  = (const float*)d_in[16];
  const float* head_w  = (const float*)d_in[17];
  const float* head_b  = (const float*)d_in[18];
  float* out = (float*)d_out;

  char* ws = (char*)d_ws;
  size_t off = 0;
  auto alloc = [&](size_t bytes) { size_t o = off; off += (bytes + 255) & ~(size_t)255; return o; };

  float* xbuf   = (float*)(ws + alloc((size_t)M_ * D_ * 4));
  u16*   hbuf   = (u16*)  (ws + alloc((size_t)M_ * D_ * 2));
  u16*   xzb    = (u16*)  (ws + alloc((size_t)M_ * 1536 * 2));
  u16*   xcbb   = (u16*)  (ws + alloc((size_t)M_ * DI_ * 2));
  float* pbuf   = (float*)(ws + alloc((size_t)4 * M_ * 56 * 4));
  u16*   im2col = (u16*)  (ws + alloc((size_t)M_ * 768 * 2));
  u16*   ybuf   = (u16*)  (ws + alloc((size_t)M_ * DI_ * 2));
  float* hend   = (float*)(ws + alloc((size_t)NSEG * B_ * DI_ * NST * 4));
  float* send   = (float*)(ws + alloc((size_t)NSEG * B_ * DI_ * 4));
  float* Abuf   = (float*)(ws + alloc((size_t)DEPTH * DI_ * NST * 4));
  float* partial= (float*)(ws + alloc((size_t)B_ * 7 * D_ * 4));
  u16*   in_wT  = (u16*)  (ws + alloc((size_t)DEPTH * 1536 * D_ * 2));
  u16*   xp_wT  = (u16*)  (ws + alloc((size_t)DEPTH * 56 * DI_ * 2));
  u16*   out_wT = (u16*)  (ws + alloc((size_t)DEPTH * D_ * DI_ * 2));
  u16*   pw_b   = (u16*)  (ws + alloc((size_t)D_ * 768 * 2));

  dim3 tb(32, 8);
  k_transpose_bf16<<<dim3(48, 12, DEPTH), tb, 0, stream>>>(in_w,  in_wT,  D_, 1536);
  k_transpose_bf16<<<dim3(2, 24, DEPTH),  tb, 0, stream>>>(xp_w,  xp_wT,  DI_, 56);
  k_transpose_bf16<<<dim3(12, 24, DEPTH), tb, 0, stream>>>(out_w, out_wT, DI_, D_);
  k_convert_bf16<<<(D_ * 768 + 255) / 256, 256, 0, stream>>>(patch_w, pw_b, D_ * 768);
  k_prepA<<<(DEPTH * DI_ * NST + 255) / 256, 256, 0, stream>>>(A_log, Abuf, DEPTH * DI_ * NST);

  k_im2col<<<(M_ * 768 + 255) / 256, 256, 0, stream>>>(x_in, im2col);
  k_gemm<64,64,2,0><<<dim3(M_ / 64, 6), 256, 0, stream>>>(im2col, pw_b, xbuf, D_, 768, patch_b, pos);

  for (int dp = 0; dp < DEPTH; ++dp) {
    const u16* iwt = in_wT  + (size_t)dp * 1536 * D_;
    const u16* xwt = xp_wT  + (size_t)dp * 56 * DI_;
    const u16* owt = out_wT + (size_t)dp * D_ * DI_;
    const float* Al = Abuf + (size_t)dp * DI_ * NST;
    const float* dw = dtp_w + (size_t)dp * R_ * DI_;
    const float* db = dtp_b + dp * DI_;
    k_ln<<<M_, 384, 0, stream>>>(xbuf, bn_g + dp * D_, bn_b + dp * D_, hbuf);
    k_gemm<64,128,0,1><<<dim3(M_ / 64, 12), 256, 0, stream>>>(hbuf, iwt, (float*)xzb, 1536, D_, nullptr, nullptr);
    k_xp_conv<<<dim3(M_ / 32, 4), 256, 0, stream>>>(xzb, conv_w + (size_t)dp * DI_ * 4,
                                                    conv_b + dp * DI_, xwt, xcbb, pbuf);
    k_scan_state<<<dim3(B_, DI_ / 64, NSEG - 1), 256, 0, stream>>>(pbuf, xcbb, dw, db, Al,
                                                                   hend, send);
    k_scan_full<<<dim3(B_, DI_ / 64, NSEG), 256, 0, stream>>>(pbuf, xcbb, xzb, dw, db, Al,
                                                              D_skip + dp * DI_, hend, send, ybuf);
    k_gemm<64,64,1,0><<<dim3(M_ / 64, 6), 256, 0, stream>>>(ybuf, owt, xbuf, D_, DI_, nullptr, nullptr);
  }

  k_feat_part<<<dim3(B_, 7), 384, 0, stream>>>(xbuf, partial);
  k_head<<<dim3((NC_ + 255) / 256, B_), 256, 0, stream>>>(partial, norm_g, norm_b, head_w, head_b, out);
}